// Round 3
// baseline (15715.163 us; speedup 1.0000x reference)
//
#include <hip/hip_runtime.h>
#include <hip/hip_bf16.h>
#include <math.h>

typedef unsigned short ushortT;

// Problem constants
#define Bc   2
#define Tc   512
#define Cc   768
#define Hc   12
#define HDc  64
#define Vc   50304
#define BTc  (Bc*Tc)          // 1024
#define NHc  (Bc*Hc)          // 24
#define C3   (3*Cc)           // 2304
#define C4   (4*Cc)           // 3072
#define EPS_LN 1e-5f
#define H_STEP 0.05f
#define INVN (1.0f/512.0f)
#define NBLK_SINK 384
#define BARS_PER_STEP 13

typedef float f32x4 __attribute__((ext_vector_type(4)));
typedef __bf16 bf16x8 __attribute__((ext_vector_type(8)));
typedef ushortT us8 __attribute__((ext_vector_type(8)));

// ---------------- bf16 helpers --------------------------------------------
__device__ __forceinline__ ushortT f2bf(float f) {
    union { float f; unsigned u; } x; x.f = f;
    unsigned r = (x.u + 0x7fffu + ((x.u >> 16) & 1u)) >> 16;
    return (ushortT)r;
}
__device__ __forceinline__ float bf2f(ushortT b) {
    union { unsigned u; float f; } x; x.u = ((unsigned)b) << 16;
    return x.f;
}

// async global->LDS, 16 bytes per lane
__device__ __forceinline__ void gll16(const ushortT* g, ushortT* l) {
    __builtin_amdgcn_global_load_lds(
        (const __attribute__((address_space(1))) unsigned int*)g,
        (__attribute__((address_space(3))) unsigned int*)l,
        16, 0, 0);
}

// ---------------- block reductions ----------------------------------------
__device__ __forceinline__ float waveReduceMaxX(float v) {
    for (int o = 32; o; o >>= 1) v = fmaxf(v, __shfl_xor(v, o));
    return v;
}
__device__ __forceinline__ float waveReduceSumX(float v) {
    for (int o = 32; o; o >>= 1) v += __shfl_xor(v, o);
    return v;
}
__device__ __forceinline__ float blockReduceSum(float v) {
    __shared__ float sm[4];
    for (int o = 32; o; o >>= 1) v += __shfl_down(v, o);
    __syncthreads();
    if ((threadIdx.x & 63) == 0) sm[threadIdx.x >> 6] = v;
    __syncthreads();
    return sm[0] + sm[1] + sm[2] + sm[3];
}

// ---------------- grid barrier (monotonic counter) ------------------------
__device__ __forceinline__ void gridbar(unsigned* ctr, unsigned target) {
    __syncthreads();
    if (threadIdx.x == 0) {
        __threadfence();
        atomicAdd(ctr, 1u);
        while (__hip_atomic_load(ctr, __ATOMIC_ACQUIRE, __HIP_MEMORY_SCOPE_AGENT) < target)
            __builtin_amdgcn_s_sleep(2);
    }
    __syncthreads();
}

// ---------------- embedding: z = wte[idx] + wpe[t] ------------------------
__global__ __launch_bounds__(256)
void embed_kernel(const int* __restrict__ idx, const float* __restrict__ wte,
                  const float* __restrict__ wpe, float* __restrict__ z)
{
    int i = blockIdx.x * 256 + threadIdx.x;
    if (i >= BTc * Cc) return;
    int r = i / Cc, c = i - r * Cc;
    int tok = idx[r];
    z[i] = wte[(size_t)tok * Cc + c] + wpe[(size_t)(r & (Tc - 1)) * Cc + c];
}

// ---------------- weight fp32 [K][N] -> bf16 [N][K] transpose -------------
__global__ __launch_bounds__(256)
void wtrans_kernel(const float* __restrict__ W, ushortT* __restrict__ out,
                   int K, int N)
{
    __shared__ float t[32][33];
    int k0 = blockIdx.x * 32, n0 = blockIdx.y * 32;
    int tx = threadIdx.x & 31, ty = threadIdx.x >> 5;
    for (int r = ty; r < 32; r += 8)
        t[r][tx] = W[(size_t)(k0 + r) * N + n0 + tx];
    __syncthreads();
    for (int r = ty; r < 32; r += 8)
        out[(size_t)(n0 + r) * K + k0 + tx] = f2bf(t[tx][r]);
}

// ---------------- v-part of qkv (bf16) -> vT [NH][64][512] ----------------
__global__ __launch_bounds__(256)
void vtrans_kernel(const ushortT* __restrict__ qkv, ushortT* __restrict__ vT)
{
    __shared__ ushortT t[32][33];
    int n = blockIdx.z; int b = n / Hc, h = n - b * Hc;
    int t0 = blockIdx.x * 32, d0 = blockIdx.y * 32;
    int tx = threadIdx.x & 31, ty = threadIdx.x >> 5;
    const ushortT* src = qkv + (size_t)(b * Tc) * C3 + 2 * Cc + h * HDc;
    for (int r = ty; r < 32; r += 8)
        t[r][tx] = src[(size_t)(t0 + r) * C3 + d0 + tx];
    __syncthreads();
    ushortT* dst = vT + (size_t)n * HDc * Tc;
    for (int r = ty; r < 32; r += 8)
        dst[(size_t)(d0 + r) * Tc + t0 + tx] = t[tx][r];
}

// ---------------- LayerNorm over 768 dims (+optional time column) ---------
__global__ __launch_bounds__(256)
void ln_kernel(const float* __restrict__ X, const float* __restrict__ w,
               const float* __restrict__ bb, void* __restrict__ Y,
               float* __restrict__ yt, int hasT, float tval,
               int rowMul, int rowAdd, int obf16)
{
    int orow = blockIdx.x;
    int r = orow * rowMul + rowAdd;
    const float* x = X + (size_t)r * Cc;
    int tid = threadIdx.x;
    float xv[3];
#pragma unroll
    for (int q = 0; q < 3; ++q) xv[q] = x[tid + 256 * q];
    float s = xv[0] + xv[1] + xv[2];
    s = blockReduceSum(s);
    float cnt = hasT ? (float)(Cc + 1) : (float)Cc;
    float mu = (s + (hasT ? tval : 0.f)) / cnt;
    float d0 = xv[0] - mu, d1 = xv[1] - mu, d2 = xv[2] - mu;
    float ss = d0 * d0 + d1 * d1 + d2 * d2;
    __syncthreads();
    ss = blockReduceSum(ss);
    float dt = tval - mu;
    float var = (ss + (hasT ? dt * dt : 0.f)) / cnt;
    float rs = rsqrtf(var + EPS_LN);
#pragma unroll
    for (int q = 0; q < 3; ++q) {
        int c = tid + 256 * q;
        float v = (xv[q] - mu) * rs * w[c] + bb[c];
        if (obf16) ((ushortT*)Y)[(size_t)orow * Cc + c] = f2bf(v);
        else       ((float*)Y)[(size_t)orow * Cc + c] = v;
    }
    if (hasT && tid == 0) yt[orow] = dt * rs * w[Cc] + bb[Cc];
}

// ---------------- MFMA GEMM: C = A[M,K](bf16) @ Bt[N,K](bf16)^T -----------
// EPI: 0 = bias(+rank1) -> bf16 ; 1 = gelu(bias+rank1) -> bf16 ;
//      3 = bias -> fp32 ; 4 = split-K partial fp32 (blockIdx.z chunks)
template <int EPI>
__global__ __launch_bounds__(256)
void gemm_bt(const ushortT* __restrict__ A, int lda,
             const ushortT* __restrict__ Bt, int ldb,
             void* __restrict__ Cm, int ldc, int K,
             const float* __restrict__ bias,
             const float* __restrict__ extraA,
             const float* __restrict__ extraB)
{
    __shared__ __align__(16) ushortT Als[128][32];
    __shared__ __align__(16) ushortT Bls[128][32];
    if (EPI == 4) {
        int koff = blockIdx.z * K;
        A += koff; Bt += koff;
    }
    int tid = threadIdx.x;
    int lane = tid & 63, wid = tid >> 6;
    int wm = wid >> 1, wn = wid & 1;
    int m0 = blockIdx.y * 128, n0 = blockIdx.x * 128;
    f32x4 acc[4][4];
    const f32x4 fz = {0.f, 0.f, 0.f, 0.f};
#pragma unroll
    for (int i = 0; i < 4; ++i)
#pragma unroll
        for (int j = 0; j < 4; ++j) acc[i][j] = fz;

    for (int k0 = 0; k0 < K; k0 += 32) {
#pragma unroll
        for (int is = 0; is < 2; ++is) {
            int ch = is * 256 + tid;
            int m = ch >> 2, kc = ch & 3;
            gll16(A + (size_t)(m0 + m) * lda + k0 + kc * 8, &Als[0][0] + ch * 8);
            gll16(Bt + (size_t)(n0 + m) * ldb + k0 + kc * 8, &Bls[0][0] + ch * 8);
        }
        __syncthreads();
        bf16x8 af[4], bfv[4];
#pragma unroll
        for (int i = 0; i < 4; ++i) {
            int row = wm * 64 + i * 16 + (lane & 15);
            af[i] = *(const bf16x8*)&Als[row][(lane >> 4) * 8];
            int col = wn * 64 + i * 16 + (lane & 15);
            bfv[i] = *(const bf16x8*)&Bls[col][(lane >> 4) * 8];
        }
#pragma unroll
        for (int i = 0; i < 4; ++i)
#pragma unroll
            for (int j = 0; j < 4; ++j)
                acc[i][j] = __builtin_amdgcn_mfma_f32_16x16x32_bf16(af[i], bfv[j], acc[i][j], 0, 0, 0);
        __syncthreads();
    }
#pragma unroll
    for (int i = 0; i < 4; ++i) {
#pragma unroll
        for (int j = 0; j < 4; ++j) {
#pragma unroll
            for (int r = 0; r < 4; ++r) {
                int row = m0 + wm * 64 + i * 16 + (lane >> 4) * 4 + r;
                int col = n0 + wn * 64 + j * 16 + (lane & 15);
                float v = acc[i][j][r];
                if (extraA) v += extraA[row] * extraB[col];
                if (bias) v += bias[col];
                size_t oi = (size_t)row * ldc + col;
                if (EPI == 0) {
                    ((ushortT*)Cm)[oi] = f2bf(v);
                } else if (EPI == 1) {
                    v = 0.5f * v * (1.f + erff(v * 0.70710678118654752440f));
                    ((ushortT*)Cm)[oi] = f2bf(v);
                } else if (EPI == 3) {
                    ((float*)Cm)[oi] = v;
                } else if (EPI == 4) {
                    ((float*)Cm)[(size_t)blockIdx.z * ((size_t)BTc * Cc) + oi] = v;
                }
            }
        }
    }
}

// ---------------- QK^T via MFMA: S = q@k^T / 8 (fp32 out), causal skip ----
__global__ __launch_bounds__(256)
void qk_mfma(const ushortT* __restrict__ qkv, float* __restrict__ S)
{
    int n = blockIdx.z; int b = n / Hc, h = n - b * Hc;
    int m0 = blockIdx.y * 128, n0 = blockIdx.x * 128;
    if (n0 > m0 + 127) return;
    const ushortT* Aq = qkv + (size_t)(b * Tc) * C3 + h * HDc;
    const ushortT* Bk = Aq + Cc;
    __shared__ __align__(16) ushortT Als[128][32];
    __shared__ __align__(16) ushortT Bls[128][32];
    int tid = threadIdx.x;
    int lane = tid & 63, wid = tid >> 6;
    int wm = wid >> 1, wn = wid & 1;
    f32x4 acc[4][4];
    const f32x4 fz = {0.f, 0.f, 0.f, 0.f};
#pragma unroll
    for (int i = 0; i < 4; ++i)
#pragma unroll
        for (int j = 0; j < 4; ++j) acc[i][j] = fz;

    for (int k0 = 0; k0 < HDc; k0 += 32) {
#pragma unroll
        for (int is = 0; is < 2; ++is) {
            int ch = is * 256 + tid;
            int m = ch >> 2, kc = ch & 3;
            gll16(Aq + (size_t)(m0 + m) * C3 + k0 + kc * 8, &Als[0][0] + ch * 8);
            gll16(Bk + (size_t)(n0 + m) * C3 + k0 + kc * 8, &Bls[0][0] + ch * 8);
        }
        __syncthreads();
        bf16x8 af[4], bfv[4];
#pragma unroll
        for (int i = 0; i < 4; ++i) {
            int row = wm * 64 + i * 16 + (lane & 15);
            af[i] = *(const bf16x8*)&Als[row][(lane >> 4) * 8];
            int col = wn * 64 + i * 16 + (lane & 15);
            bfv[i] = *(const bf16x8*)&Bls[col][(lane >> 4) * 8];
        }
#pragma unroll
        for (int i = 0; i < 4; ++i)
#pragma unroll
            for (int j = 0; j < 4; ++j)
                acc[i][j] = __builtin_amdgcn_mfma_f32_16x16x32_bf16(af[i], bfv[j], acc[i][j], 0, 0, 0);
        __syncthreads();
    }
    float* Sb = S + (size_t)n * Tc * Tc;
#pragma unroll
    for (int i = 0; i < 4; ++i)
#pragma unroll
        for (int j = 0; j < 4; ++j)
#pragma unroll
            for (int r = 0; r < 4; ++r) {
                int row = m0 + wm * 64 + i * 16 + (lane >> 4) * 4 + r;
                int col = n0 + wn * 64 + j * 16 + (lane & 15);
                Sb[(size_t)row * Tc + col] = acc[i][j][r] * 0.125f;
            }
}

// ===================== fused softmax+E + Sinkhorn + vscale =================
// grid = 384 blocks x 256 threads (all co-resident: 1536 waves << capacity).
// Phases: P_E (softmax -> E bf16, rowsum -> a) | bar | P_T (E -> ET) | bar |
//         11 alternating passes (col,row,...,col) each followed by bar |
//         vscale (vTs = vT * n*b).
__device__ __forceinline__ void sink_half(const ushortT* __restrict__ M,
                                          const float* __restrict__ xin,
                                          float* __restrict__ xout, int bI)
{
    int tid = threadIdx.x;
    int lane = tid & 63, w = tid >> 6;
    int head = bI >> 4;
    const ushortT* Mb = M + (size_t)head * Tc * Tc;
    const float* xi = xin + head * Tc;
    f32x4 x0 = *(const f32x4*)(xi + lane * 8);
    f32x4 x1 = *(const f32x4*)(xi + lane * 8 + 4);
#pragma unroll
    for (int it = 0; it < 8; ++it) {
        int row = (bI & 15) * 32 + w * 8 + it;
        us8 ev = *(const us8*)(Mb + (size_t)row * Tc + lane * 8);
        float s = bf2f(ev[0]) * x0[0] + bf2f(ev[1]) * x0[1]
                + bf2f(ev[2]) * x0[2] + bf2f(ev[3]) * x0[3]
                + bf2f(ev[4]) * x1[0] + bf2f(ev[5]) * x1[1]
                + bf2f(ev[6]) * x1[2] + bf2f(ev[7]) * x1[3];
        s = waveReduceSumX(s);
        if (lane == 0) xout[head * Tc + row] = INVN / s;
    }
}

__global__ __launch_bounds__(256)
void sinkfull(const float* __restrict__ S, ushortT* __restrict__ E,
              ushortT* __restrict__ ET, float* __restrict__ avec,
              float* __restrict__ bvec, const ushortT* __restrict__ vT,
              ushortT* __restrict__ vTs, unsigned* __restrict__ ctr,
              unsigned barBase)
{
    __shared__ ushortT ttile[32][33];
    int bI = blockIdx.x;
    int tid = threadIdx.x;
    int lane = tid & 63, w = tid >> 6;

    // ---- P_E: softmax rows -> E = exp(-p) bf16, rowsum -> a ----
#pragma unroll
    for (int it = 0; it < 8; ++it) {
        int g = bI * 32 + w * 8 + it;       // global row (head*512 + i)
        int i = g & (Tc - 1);
        const float* srow = S + (size_t)g * Tc;
        f32x4 v0 = *(const f32x4*)(srow + lane * 8);
        f32x4 v1 = *(const f32x4*)(srow + lane * 8 + 4);
        float x[8] = {v0[0], v0[1], v0[2], v0[3], v1[0], v1[1], v1[2], v1[3]};
        float mx = -INFINITY;
#pragma unroll
        for (int e = 0; e < 8; ++e)
            if (lane * 8 + e <= i) mx = fmaxf(mx, x[e]);
        mx = waveReduceMaxX(mx);
        float ex[8]; float se = 0.f;
#pragma unroll
        for (int e = 0; e < 8; ++e) {
            ex[e] = (lane * 8 + e <= i) ? __expf(x[e] - mx) : 0.f;
            se += ex[e];
        }
        se = waveReduceSumX(se);
        float inv = 1.f / se;
        us8 pack; float rs = 0.f;
#pragma unroll
        for (int e = 0; e < 8; ++e) {
            float Ee = __expf(-(ex[e] * inv));
            rs += Ee;
            pack[e] = f2bf(Ee);
        }
        rs = waveReduceSumX(rs);
        *(us8*)(E + (size_t)g * Tc + lane * 8) = pack;
        if (lane == 0) avec[g] = INVN / rs;
    }
    gridbar(ctr, barBase + 1 * NBLK_SINK);

    // ---- P_T: transpose E -> ET (16 32x32 tiles per block) ----
    {
        int tx = tid & 31, ty = tid >> 5;
#pragma unroll
        for (int tt = 0; tt < 16; ++tt) {
            int tileId = bI * 16 + tt;              // 0..6143
            int head = tileId >> 8;
            int rem = tileId & 255;
            int i0 = (rem >> 4) * 32, j0 = (rem & 15) * 32;
            const ushortT* Eb = E + (size_t)head * Tc * Tc;
            ushortT* Tb = ET + (size_t)head * Tc * Tc;
            for (int r = ty; r < 32; r += 8)
                ttile[r][tx] = Eb[(size_t)(i0 + r) * Tc + j0 + tx];
            __syncthreads();
            for (int r = ty; r < 32; r += 8)
                Tb[(size_t)(j0 + r) * Tc + i0 + tx] = ttile[tx][r];
            __syncthreads();
        }
    }
    gridbar(ctr, barBase + 2 * NBLK_SINK);

    // ---- 11 alternating passes: col (ET,a->b), row (E,b->a), ... ----
#pragma unroll 1
    for (int p = 0; p < 11; ++p) {
        if ((p & 1) == 0) sink_half(ET, avec, bvec, bI);
        else              sink_half(E, bvec, avec, bI);
        gridbar(ctr, barBase + (3 + p) * NBLK_SINK);
    }

    // ---- vscale: vTs = vT * (n * b_j) ----
    {
        int flat = bI * 2048 + tid * 8;             // over NH*64*512
        int n = flat >> 15;
        int j = flat & (Tc - 1);
        us8 vv = *(const us8*)(vT + flat);
        f32x4 b0 = *(const f32x4*)(bvec + n * Tc + j);
        f32x4 b1 = *(const f32x4*)(bvec + n * Tc + j + 4);
        float bs[8] = {b0[0], b0[1], b0[2], b0[3], b1[0], b1[1], b1[2], b1[3]};
        us8 o;
#pragma unroll
        for (int e = 0; e < 8; ++e)
            o[e] = f2bf(bf2f(vv[e]) * 512.f * bs[e]);
        *(us8*)(vTs + flat) = o;
    }
}

// ---------------- y = a_i * (E @ vTs) via MFMA (bf16 out) -----------------
__global__ __launch_bounds__(256)
void piv_mfma(const ushortT* __restrict__ E, const ushortT* __restrict__ vTs,
              const float* __restrict__ avec, ushortT* __restrict__ y)
{
    int n = blockIdx.y; int b = n / Hc, h = n - b * Hc;
    int m0 = blockIdx.x * 128;
    const ushortT* Ap = E + (size_t)n * Tc * Tc;
    const ushortT* Bv = vTs + (size_t)n * HDc * Tc;
    __shared__ __align__(16) ushortT Als[128][32];
    __shared__ __align__(16) ushortT Bls[64][32];
    int tid = threadIdx.x;
    int lane = tid & 63, wid = tid >> 6;
    int wm = wid >> 1, wn = wid & 1;
    f32x4 acc[4][2];
    const f32x4 fz = {0.f, 0.f, 0.f, 0.f};
#pragma unroll
    for (int i = 0; i < 4; ++i)
#pragma unroll
        for (int j = 0; j < 2; ++j) acc[i][j] = fz;

    for (int k0 = 0; k0 < Tc; k0 += 32) {
#pragma unroll
        for (int is = 0; is < 2; ++is) {
            int ch = is * 256 + tid;
            int m = ch >> 2, kc = ch & 3;
            gll16(Ap + (size_t)(m0 + m) * Tc + k0 + kc * 8, &Als[0][0] + ch * 8);
        }
        {
            int ch = tid;
            int d = ch >> 2, kc = ch & 3;
            gll16(Bv + (size_t)d * Tc + k0 + kc * 8, &Bls[0][0] + ch * 8);
        }
        __syncthreads();
        bf16x8 af[4], bfv[2];
#pragma unroll
        for (int i = 0; i < 4; ++i) {
            int row = wm * 64 + i * 16 + (lane & 15);
            af[i] = *(const bf16x8*)&Als[row][(lane >> 4) * 8];
        }
#pragma unroll
        for (int j = 0; j < 2; ++j) {
            int col = wn * 32 + j * 16 + (lane & 15);
            bfv[j] = *(const bf16x8*)&Bls[col][(lane >> 4) * 8];
        }
#pragma unroll
        for (int i = 0; i < 4; ++i)
#pragma unroll
            for (int j = 0; j < 2; ++j)
                acc[i][j] = __builtin_amdgcn_mfma_f32_16x16x32_bf16(af[i], bfv[j], acc[i][j], 0, 0, 0);
        __syncthreads();
    }
#pragma unroll
    for (int i = 0; i < 4; ++i)
#pragma unroll
        for (int j = 0; j < 2; ++j)
#pragma unroll
            for (int r = 0; r < 4; ++r) {
                int rIn = m0 + wm * 64 + i * 16 + (lane >> 4) * 4 + r;
                float a_r = avec[n * Tc + rIn];
                int row = b * Tc + rIn;
                int col = h * HDc + wn * 32 + j * 16 + (lane & 15);
                y[(size_t)row * Cc + col] = f2bf(acc[i][j][r] * a_r);
            }
}

// ---------------- split-K reduce + Euler: z += h*(sum parts + bias) -------
__global__ __launch_bounds__(256)
void mlp_reduce(const float* __restrict__ parts, const float* __restrict__ bias,
                float* __restrict__ z)
{
    int i4 = (blockIdx.x * 256 + threadIdx.x) * 4;
    const size_t CS = (size_t)BTc * Cc;
    f32x4 a = *(const f32x4*)(parts + i4);
    f32x4 b = *(const f32x4*)(parts + CS + i4);
    f32x4 c = *(const f32x4*)(parts + 2 * CS + i4);
    f32x4 d = *(const f32x4*)(parts + 3 * CS + i4);
    int col = i4 - (i4 / Cc) * Cc;
    f32x4 bb = *(const f32x4*)(bias + col);
    f32x4 zz = *(const f32x4*)(z + i4);
#pragma unroll
    for (int e = 0; e < 4; ++e)
        zz[e] += H_STEP * (a[e] + b[e] + c[e] + d[e] + bb[e]);
    *(f32x4*)(z + i4) = zz;
}

// ---------------- logits: out[b,v] = xf[b,:] . wte[v,:] (fp32) ------------
__global__ __launch_bounds__(256)
void logits_kernel(const float* __restrict__ xf, const float* __restrict__ wte,
                   float* __restrict__ out)
{
    __shared__ float xs[2 * Cc];
    int tid = threadIdx.x;
    for (int l = tid; l < 2 * Cc; l += 256) xs[l] = xf[l];
    __syncthreads();
    int w = tid >> 6, lane = tid & 63;
    int vrow = blockIdx.x * 4 + w;
    const float* wr = wte + (size_t)vrow * Cc;
    float a0 = 0.f, a1 = 0.f;
    for (int k = lane; k < Cc; k += 64) {
        float wv = wr[k];
        a0 += wv * xs[k];
        a1 += wv * xs[Cc + k];
    }
    for (int o = 32; o; o >>= 1) {
        a0 += __shfl_down(a0, o);
        a1 += __shfl_down(a1, o);
    }
    if (lane == 0) {
        out[vrow] = a0;
        out[Vc + vrow] = a1;
    }
}

// ==========================================================================
extern "C" void kernel_launch(void* const* d_in, const int* in_sizes, int n_in,
                              void* d_out, int out_size, void* d_ws, size_t ws_size,
                              hipStream_t stream)
{
    const int*   idx        = (const int*)  d_in[0];
    const float* wte        = (const float*)d_in[1];
    const float* wpe        = (const float*)d_in[2];
    const float* attn_ln_w  = (const float*)d_in[3];
    const float* attn_ln_b  = (const float*)d_in[4];
    const float* c_attn_w   = (const float*)d_in[5];
    const float* c_attn_b   = (const float*)d_in[6];
    const float* c_proj_w   = (const float*)d_in[7];
    const float* c_proj_b   = (const float*)d_in[8];
    const float* mlp_ln_w   = (const float*)d_in[9];
    const float* mlp_ln_b   = (const float*)d_in[10];
    const float* c_fc_w     = (const float*)d_in[11];
    const float* c_fc_b     = (const float*)d_in[12];
    const float* mlp_proj_w = (const float*)d_in[13];
    const float* mlp_proj_b = (const float*)d_in[14];
    const float* lnf_w      = (const float*)d_in[15];
    const float* lnf_b      = (const float*)d_in[16];
    float* out = (float*)d_out;

    // -------- workspace carving (256B aligned) --------
    char* base = (char*)d_ws;
    size_t off = 0;
    auto alloc = [&](size_t bytes) -> void* {
        void* p = base + off;
        off = (off + bytes + 255) & ~(size_t)255;
        return p;
    };
    float*   z     = (float*)  alloc((size_t)BTc * Cc * 4);
    float*   ao    = (float*)  alloc((size_t)BTc * Cc * 4);
    float*   Sbuf  = (float*)  alloc((size_t)NHc * Tc * Tc * 4);  // 25MB; h1/parts alias
    ushortT* E     = (ushortT*)alloc((size_t)NHc * Tc * Tc * 2);
    ushortT* ET    = (ushortT*)alloc((size_t)NHc * Tc * Tc * 2);
    ushortT* qkvb  = (ushortT*)alloc((size_t)BTc * C3 * 2);
    ushortT* xlnb  = (ushortT*)alloc((size_t)BTc * Cc * 2);
    ushortT* y     = (ushortT*)alloc((size_t)BTc * Cc * 2);
    ushortT* vT    = (ushortT*)alloc((size_t)NHc * HDc * Tc * 2);
    ushortT* vTs   = (ushortT*)alloc((size_t)NHc * HDc * Tc * 2);
    float*   xt    = (float*)  alloc(BTc * 4);
    float*   avec  = (float*)  alloc(NHc * Tc * 4);
    float*   bvec  = (float*)  alloc(NHc * Tc * 4);
    float*   xf    = (float*)  alloc(2 * Cc * 4);
    unsigned* ctr  = (unsigned*)alloc(256);
    ushortT* WqkvT = (ushortT*)alloc((size_t)C3 * Cc * 2);
    ushortT* WprojT= (ushortT*)alloc((size_t)Cc * Cc * 2);
    ushortT* WfcT  = (ushortT*)alloc((size_t)C4 * Cc * 2);
    ushortT* WmlpT = (ushortT*)alloc((size_t)Cc * C4 * 2);
    // aliases inside Sbuf (dead after sinkfull each step)
    ushortT* h1    = (ushortT*)Sbuf;                      // 6.3MB bf16
    float*   parts = (float*)((char*)Sbuf + (8u << 20));  // 12.6MB fp32

    hipMemsetAsync(ctr, 0, 4, stream);
    embed_kernel<<<(BTc * Cc + 255) / 256, 256, 0, stream>>>(idx, wte, wpe, z);
    wtrans_kernel<<<dim3(Cc / 32, C3 / 32), 256, 0, stream>>>(c_attn_w,   WqkvT,  Cc, C3);
    wtrans_kernel<<<dim3(Cc / 32, Cc / 32), 256, 0, stream>>>(c_proj_w,   WprojT, Cc, Cc);
    wtrans_kernel<<<dim3(Cc / 32, C4 / 32), 256, 0, stream>>>(c_fc_w,     WfcT,   Cc, C4);
    wtrans_kernel<<<dim3(C4 / 32, Cc / 32), 256, 0, stream>>>(mlp_proj_w, WmlpT,  C4, Cc);

    float t = 0.f;
    for (int step = 0; step < 20; ++step) {
        ln_kernel<<<BTc, 256, 0, stream>>>(z, attn_ln_w, attn_ln_b, xlnb, xt, 1, t, 1, 0, 1);
        gemm_bt<0><<<dim3(C3 / 128, BTc / 128), 256, 0, stream>>>(
            xlnb, Cc, WqkvT, Cc, qkvb, C3, Cc,
            c_attn_b, xt, c_attn_w + (size_t)Cc * C3);
        vtrans_kernel<<<dim3(Tc / 32, HDc / 32, NHc), 256, 0, stream>>>(qkvb, vT);
        qk_mfma<<<dim3(Tc / 128, Tc / 128, NHc), 256, 0, stream>>>(qkvb, Sbuf);
        sinkfull<<<NBLK_SINK, 256, 0, stream>>>(
            Sbuf, E, ET, avec, bvec, vT, vTs, ctr,
            (unsigned)(step * BARS_PER_STEP * NBLK_SINK));
        piv_mfma<<<dim3(Tc / 128, NHc), 256, 0, stream>>>(E, vTs, avec, y);
        gemm_bt<3><<<dim3(Cc / 128, BTc / 128), 256, 0, stream>>>(
            y, Cc, WprojT, Cc, ao, Cc, Cc,
            c_proj_b, nullptr, nullptr);
        ln_kernel<<<BTc, 256, 0, stream>>>(ao, mlp_ln_w, mlp_ln_b, xlnb, xt, 1, t, 1, 0, 1);
        gemm_bt<1><<<dim3(C4 / 128, BTc / 128), 256, 0, stream>>>(
            xlnb, Cc, WfcT, Cc, h1, C4, Cc,
            c_fc_b, xt, c_fc_w + (size_t)Cc * C4);
        gemm_bt<4><<<dim3(Cc / 128, BTc / 128, 4), 256, 0, stream>>>(
            h1, C4, WmlpT, C4, parts, Cc, C4 / 4,
            nullptr, nullptr, nullptr);
        mlp_reduce<<<(BTc * Cc) / 1024, 256, 0, stream>>>(parts, mlp_proj_b, z);
        t += H_STEP;
    }

    ln_kernel<<<2, 256, 0, stream>>>(z, lnf_w, lnf_b, xf, nullptr, 0, 0.f, Tc, Tc - 1, 0);
    logits_kernel<<<Vc / 4, 256, 0, stream>>>(xf, wte, out);
}

// Round 4
// 7284.317 us; speedup vs baseline: 2.1574x; 2.1574x over previous
//
#include <hip/hip_runtime.h>
#include <hip/hip_bf16.h>
#include <math.h>

typedef unsigned short ushortT;
typedef unsigned int uintT;

// Problem constants
#define Bc   2
#define Tc   512
#define Cc   768
#define Hc   12
#define HDc  64
#define Vc   50304
#define BTc  (Bc*Tc)          // 1024
#define NHc  (Bc*Hc)          // 24
#define C3   (3*Cc)           // 2304
#define C4   (4*Cc)           // 3072
#define EPS_LN 1e-5f
#define H_STEP 0.05f
#define INVN (1.0f/512.0f)

typedef float f32x4 __attribute__((ext_vector_type(4)));
typedef __bf16 bf16x8 __attribute__((ext_vector_type(8)));
typedef ushortT us8 __attribute__((ext_vector_type(8)));
typedef uintT u32x4 __attribute__((ext_vector_type(4)));

// ---------------- bf16 helpers --------------------------------------------
__device__ __forceinline__ ushortT f2bf(float f) {
    union { float f; unsigned u; } x; x.f = f;
    unsigned r = (x.u + 0x7fffu + ((x.u >> 16) & 1u)) >> 16;
    return (ushortT)r;
}
__device__ __forceinline__ float bf2f(ushortT b) {
    union { unsigned u; float f; } x; x.u = ((unsigned)b) << 16;
    return x.f;
}
__device__ __forceinline__ float bflo(uintT w) {
    union { unsigned u; float f; } x; x.u = w << 16;
    return x.f;
}
__device__ __forceinline__ float bfhi(uintT w) {
    union { unsigned u; float f; } x; x.u = w & 0xffff0000u;
    return x.f;
}

// async global->LDS, 16 bytes per lane
__device__ __forceinline__ void gll16(const ushortT* g, ushortT* l) {
    __builtin_amdgcn_global_load_lds(
        (const __attribute__((address_space(1))) unsigned int*)g,
        (__attribute__((address_space(3))) unsigned int*)l,
        16, 0, 0);
}

// ---------------- wave reductions -----------------------------------------
__device__ __forceinline__ float waveReduceMaxX(float v) {
    for (int o = 32; o; o >>= 1) v = fmaxf(v, __shfl_xor(v, o));
    return v;
}
__device__ __forceinline__ float waveReduceSumX(float v) {
    for (int o = 32; o; o >>= 1) v += __shfl_xor(v, o);
    return v;
}
__device__ __forceinline__ float blockReduceSum(float v) {
    __shared__ float sm[4];
    for (int o = 32; o; o >>= 1) v += __shfl_down(v, o);
    __syncthreads();
    if ((threadIdx.x & 63) == 0) sm[threadIdx.x >> 6] = v;
    __syncthreads();
    return sm[0] + sm[1] + sm[2] + sm[3];
}

// ---------------- embedding: z = wte[idx] + wpe[t] ------------------------
__global__ __launch_bounds__(256)
void embed_kernel(const int* __restrict__ idx, const float* __restrict__ wte,
                  const float* __restrict__ wpe, float* __restrict__ z)
{
    int i = blockIdx.x * 256 + threadIdx.x;
    if (i >= BTc * Cc) return;
    int r = i / Cc, c = i - r * Cc;
    int tok = idx[r];
    z[i] = wte[(size_t)tok * Cc + c] + wpe[(size_t)(r & (Tc - 1)) * Cc + c];
}

// ---------------- weight fp32 [K][N] -> bf16 [N][K] transpose -------------
__global__ __launch_bounds__(256)
void wtrans_kernel(const float* __restrict__ W, ushortT* __restrict__ out,
                   int K, int N)
{
    __shared__ float t[32][33];
    int k0 = blockIdx.x * 32, n0 = blockIdx.y * 32;
    int tx = threadIdx.x & 31, ty = threadIdx.x >> 5;
    for (int r = ty; r < 32; r += 8)
        t[r][tx] = W[(size_t)(k0 + r) * N + n0 + tx];
    __syncthreads();
    for (int r = ty; r < 32; r += 8)
        out[(size_t)(n0 + r) * K + k0 + tx] = f2bf(t[tx][r]);
}

// ---------------- v-part of qkv (bf16) -> vT [NH][64][512] ----------------
__global__ __launch_bounds__(256)
void vtrans_kernel(const ushortT* __restrict__ qkv, ushortT* __restrict__ vT)
{
    __shared__ ushortT t[32][33];
    int n = blockIdx.z; int b = n / Hc, h = n - b * Hc;
    int t0 = blockIdx.x * 32, d0 = blockIdx.y * 32;
    int tx = threadIdx.x & 31, ty = threadIdx.x >> 5;
    const ushortT* src = qkv + (size_t)(b * Tc) * C3 + 2 * Cc + h * HDc;
    for (int r = ty; r < 32; r += 8)
        t[r][tx] = src[(size_t)(t0 + r) * C3 + d0 + tx];
    __syncthreads();
    ushortT* dst = vT + (size_t)n * HDc * Tc;
    for (int r = ty; r < 32; r += 8)
        dst[(size_t)(d0 + r) * Tc + t0 + tx] = t[tx][r];
}

// ---------------- LayerNorm over 768 dims (+optional time column) ---------
__global__ __launch_bounds__(256)
void ln_kernel(const float* __restrict__ X, const float* __restrict__ w,
               const float* __restrict__ bb, void* __restrict__ Y,
               float* __restrict__ yt, int hasT, float tval,
               int rowMul, int rowAdd, int obf16)
{
    int orow = blockIdx.x;
    int r = orow * rowMul + rowAdd;
    const float* x = X + (size_t)r * Cc;
    int tid = threadIdx.x;
    float xv[3];
#pragma unroll
    for (int q = 0; q < 3; ++q) xv[q] = x[tid + 256 * q];
    float s = xv[0] + xv[1] + xv[2];
    s = blockReduceSum(s);
    float cnt = hasT ? (float)(Cc + 1) : (float)Cc;
    float mu = (s + (hasT ? tval : 0.f)) / cnt;
    float d0 = xv[0] - mu, d1 = xv[1] - mu, d2 = xv[2] - mu;
    float ss = d0 * d0 + d1 * d1 + d2 * d2;
    __syncthreads();
    ss = blockReduceSum(ss);
    float dt = tval - mu;
    float var = (ss + (hasT ? dt * dt : 0.f)) / cnt;
    float rs = rsqrtf(var + EPS_LN);
#pragma unroll
    for (int q = 0; q < 3; ++q) {
        int c = tid + 256 * q;
        float v = (xv[q] - mu) * rs * w[c] + bb[c];
        if (obf16) ((ushortT*)Y)[(size_t)orow * Cc + c] = f2bf(v);
        else       ((float*)Y)[(size_t)orow * Cc + c] = v;
    }
    if (hasT && tid == 0) yt[orow] = dt * rs * w[Cc] + bb[Cc];
}

// ---------------- MFMA GEMM: C = A[M,K](bf16) @ Bt[N,K](bf16)^T -----------
// EPI: 0 = bias(+rank1) -> bf16 ; 1 = gelu(bias+rank1) -> bf16 ;
//      3 = bias -> fp32 ; 4 = split-K partial fp32 (blockIdx.z chunks)
template <int EPI>
__global__ __launch_bounds__(256)
void gemm_bt(const ushortT* __restrict__ A, int lda,
             const ushortT* __restrict__ Bt, int ldb,
             void* __restrict__ Cm, int ldc, int K,
             const float* __restrict__ bias,
             const float* __restrict__ extraA,
             const float* __restrict__ extraB)
{
    __shared__ __align__(16) ushortT Als[128][32];
    __shared__ __align__(16) ushortT Bls[128][32];
    if (EPI == 4) {
        int koff = blockIdx.z * K;
        A += koff; Bt += koff;
    }
    int tid = threadIdx.x;
    int lane = tid & 63, wid = tid >> 6;
    int wm = wid >> 1, wn = wid & 1;
    int m0 = blockIdx.y * 128, n0 = blockIdx.x * 128;
    f32x4 acc[4][4];
    const f32x4 fz = {0.f, 0.f, 0.f, 0.f};
#pragma unroll
    for (int i = 0; i < 4; ++i)
#pragma unroll
        for (int j = 0; j < 4; ++j) acc[i][j] = fz;

    for (int k0 = 0; k0 < K; k0 += 32) {
#pragma unroll
        for (int is = 0; is < 2; ++is) {
            int ch = is * 256 + tid;
            int m = ch >> 2, kc = ch & 3;
            gll16(A + (size_t)(m0 + m) * lda + k0 + kc * 8, &Als[0][0] + ch * 8);
            gll16(Bt + (size_t)(n0 + m) * ldb + k0 + kc * 8, &Bls[0][0] + ch * 8);
        }
        __syncthreads();
        bf16x8 af[4], bfv[4];
#pragma unroll
        for (int i = 0; i < 4; ++i) {
            int row = wm * 64 + i * 16 + (lane & 15);
            af[i] = *(const bf16x8*)&Als[row][(lane >> 4) * 8];
            int col = wn * 64 + i * 16 + (lane & 15);
            bfv[i] = *(const bf16x8*)&Bls[col][(lane >> 4) * 8];
        }
#pragma unroll
        for (int i = 0; i < 4; ++i)
#pragma unroll
            for (int j = 0; j < 4; ++j)
                acc[i][j] = __builtin_amdgcn_mfma_f32_16x16x32_bf16(af[i], bfv[j], acc[i][j], 0, 0, 0);
        __syncthreads();
    }
#pragma unroll
    for (int i = 0; i < 4; ++i) {
#pragma unroll
        for (int j = 0; j < 4; ++j) {
#pragma unroll
            for (int r = 0; r < 4; ++r) {
                int row = m0 + wm * 64 + i * 16 + (lane >> 4) * 4 + r;
                int col = n0 + wn * 64 + j * 16 + (lane & 15);
                float v = acc[i][j][r];
                if (extraA) v += extraA[row] * extraB[col];
                if (bias) v += bias[col];
                size_t oi = (size_t)row * ldc + col;
                if (EPI == 0) {
                    ((ushortT*)Cm)[oi] = f2bf(v);
                } else if (EPI == 1) {
                    v = 0.5f * v * (1.f + erff(v * 0.70710678118654752440f));
                    ((ushortT*)Cm)[oi] = f2bf(v);
                } else if (EPI == 3) {
                    ((float*)Cm)[oi] = v;
                } else if (EPI == 4) {
                    ((float*)Cm)[(size_t)blockIdx.z * ((size_t)BTc * Cc) + oi] = v;
                }
            }
        }
    }
}

// ---------------- QK^T via MFMA: S = q@k^T / 8 (fp32 out), causal skip ----
__global__ __launch_bounds__(256)
void qk_mfma(const ushortT* __restrict__ qkv, float* __restrict__ S)
{
    int n = blockIdx.z; int b = n / Hc, h = n - b * Hc;
    int m0 = blockIdx.y * 128, n0 = blockIdx.x * 128;
    if (n0 > m0 + 127) return;
    const ushortT* Aq = qkv + (size_t)(b * Tc) * C3 + h * HDc;
    const ushortT* Bk = Aq + Cc;
    __shared__ __align__(16) ushortT Als[128][32];
    __shared__ __align__(16) ushortT Bls[128][32];
    int tid = threadIdx.x;
    int lane = tid & 63, wid = tid >> 6;
    int wm = wid >> 1, wn = wid & 1;
    f32x4 acc[4][4];
    const f32x4 fz = {0.f, 0.f, 0.f, 0.f};
#pragma unroll
    for (int i = 0; i < 4; ++i)
#pragma unroll
        for (int j = 0; j < 4; ++j) acc[i][j] = fz;

    for (int k0 = 0; k0 < HDc; k0 += 32) {
#pragma unroll
        for (int is = 0; is < 2; ++is) {
            int ch = is * 256 + tid;
            int m = ch >> 2, kc = ch & 3;
            gll16(Aq + (size_t)(m0 + m) * C3 + k0 + kc * 8, &Als[0][0] + ch * 8);
            gll16(Bk + (size_t)(n0 + m) * C3 + k0 + kc * 8, &Bls[0][0] + ch * 8);
        }
        __syncthreads();
        bf16x8 af[4], bfv[4];
#pragma unroll
        for (int i = 0; i < 4; ++i) {
            int row = wm * 64 + i * 16 + (lane & 15);
            af[i] = *(const bf16x8*)&Als[row][(lane >> 4) * 8];
            int col = wn * 64 + i * 16 + (lane & 15);
            bfv[i] = *(const bf16x8*)&Bls[col][(lane >> 4) * 8];
        }
#pragma unroll
        for (int i = 0; i < 4; ++i)
#pragma unroll
            for (int j = 0; j < 4; ++j)
                acc[i][j] = __builtin_amdgcn_mfma_f32_16x16x32_bf16(af[i], bfv[j], acc[i][j], 0, 0, 0);
        __syncthreads();
    }
    float* Sb = S + (size_t)n * Tc * Tc;
#pragma unroll
    for (int i = 0; i < 4; ++i)
#pragma unroll
        for (int j = 0; j < 4; ++j)
#pragma unroll
            for (int r = 0; r < 4; ++r) {
                int row = m0 + wm * 64 + i * 16 + (lane >> 4) * 4 + r;
                int col = n0 + wn * 64 + j * 16 + (lane & 15);
                Sb[(size_t)row * Tc + col] = acc[i][j][r] * 0.125f;
            }
}

// ===================== per-head fused Sinkhorn (block = head) =============
// 24 blocks x 512 threads. Phase 0: causal softmax -> E=exp(-p) bf16,
// rowsum -> a1. Then 11 alternating passes (col,row,...,col) with only
// __syncthreads. b kept in permuted LDS layout bp[e*64 + j/8] so row passes
// read it bank-conflict-free into registers. Finally scale vT by n*b6 and
// write a6 for the piv epilogue. No transpose, no grid barrier, no pi.
__global__ __launch_bounds__(512)
void sinkhead(const float* __restrict__ S, ushortT* __restrict__ E,
              float* __restrict__ avec, const ushortT* __restrict__ vT,
              ushortT* __restrict__ vTs)
{
    int n = blockIdx.x;
    int tid = threadIdx.x;
    int l = tid & 63, w = tid >> 6;          // 8 waves
    __shared__ float a[Tc];
    __shared__ float bp[Tc];
    const float* Sb = S + (size_t)n * Tc * Tc;
    ushortT* Eb = E + (size_t)n * Tc * Tc;

    // ---- phase 0: softmax rows -> E, rowsum -> a1 ----
#pragma unroll 1
    for (int it = 0; it < 64; ++it) {
        int row = it * 8 + w;
        const float* sr = Sb + (size_t)row * Tc + l * 8;
        f32x4 v0 = *(const f32x4*)sr;
        f32x4 v1 = *(const f32x4*)(sr + 4);
        float x[8] = {v0[0], v0[1], v0[2], v0[3], v1[0], v1[1], v1[2], v1[3]};
        float mx = -INFINITY;
#pragma unroll
        for (int e = 0; e < 8; ++e)
            if (l * 8 + e <= row) mx = fmaxf(mx, x[e]);
        mx = waveReduceMaxX(mx);
        float ex[8], se = 0.f;
#pragma unroll
        for (int e = 0; e < 8; ++e) {
            ex[e] = (l * 8 + e <= row) ? __expf(x[e] - mx) : 0.f;
            se += ex[e];
        }
        se = waveReduceSumX(se);
        float inv = 1.f / se;
        us8 pack; float rs = 0.f;
#pragma unroll
        for (int e = 0; e < 8; ++e) {
            float Ee = __expf(-(ex[e] * inv));   // masked: exp(-0)=1 (matches ref)
            rs += Ee;
            pack[e] = f2bf(Ee);
        }
        rs = waveReduceSumX(rs);
        *(us8*)(Eb + (size_t)row * Tc + l * 8) = pack;
        if (l == 0) a[row] = INVN / rs;
    }
    __syncthreads();

    // ---- 11 alternating passes: col (a->b), row (b->a), ..., col ----
#pragma unroll 1
    for (int p = 0; p < 11; ++p) {
        if ((p & 1) == 0) {
            // col pass: b_j = INVN / sum_i E[i][j]*a[i]; thread per column
            int j = tid;
            float acc = 0.f;
#pragma unroll 1
            for (int i = 0; i < Tc; i += 16) {
                float part = 0.f;
#pragma unroll
                for (int k = 0; k < 16; ++k)
                    part += bf2f(Eb[(size_t)(i + k) * Tc + j]) * a[i + k];
                acc += part;
            }
            bp[((j & 7) << 6) + (j >> 3)] = INVN / acc;
        } else {
            // row pass: a_i = INVN / sum_j E[i][j]*b[j]; wave per row, ILP 4
            float breg[8];
#pragma unroll
            for (int e = 0; e < 8; ++e) breg[e] = bp[e * 64 + l];
#pragma unroll 1
            for (int it = 0; it < 16; ++it) {
                int r0 = it * 32 + w * 4;
                u32x4 q0 = *(const u32x4*)(Eb + (size_t)(r0 + 0) * Tc + l * 8);
                u32x4 q1 = *(const u32x4*)(Eb + (size_t)(r0 + 1) * Tc + l * 8);
                u32x4 q2 = *(const u32x4*)(Eb + (size_t)(r0 + 2) * Tc + l * 8);
                u32x4 q3 = *(const u32x4*)(Eb + (size_t)(r0 + 3) * Tc + l * 8);
                float s0 = 0.f, s1 = 0.f, s2 = 0.f, s3 = 0.f;
#pragma unroll
                for (int c = 0; c < 4; ++c) {
                    s0 += bflo(q0[c]) * breg[2 * c] + bfhi(q0[c]) * breg[2 * c + 1];
                    s1 += bflo(q1[c]) * breg[2 * c] + bfhi(q1[c]) * breg[2 * c + 1];
                    s2 += bflo(q2[c]) * breg[2 * c] + bfhi(q2[c]) * breg[2 * c + 1];
                    s3 += bflo(q3[c]) * breg[2 * c] + bfhi(q3[c]) * breg[2 * c + 1];
                }
                s0 = waveReduceSumX(s0);
                s1 = waveReduceSumX(s1);
                s2 = waveReduceSumX(s2);
                s3 = waveReduceSumX(s3);
                if (l == 0) {
                    a[r0 + 0] = INVN / s0;
                    a[r0 + 1] = INVN / s1;
                    a[r0 + 2] = INVN / s2;
                    a[r0 + 3] = INVN / s3;
                }
            }
        }
        __syncthreads();
    }

    // ---- vscale: vTs = vT * (n * b6), and write out a6 ----
    {
        float breg[8];
#pragma unroll
        for (int e = 0; e < 8; ++e) breg[e] = bp[e * 64 + l];
        const ushortT* vb = vT + (size_t)n * HDc * Tc;
        ushortT* ob = vTs + (size_t)n * HDc * Tc;
#pragma unroll 1
        for (int dd = 0; dd < 8; ++dd) {
            int d = dd * 8 + w;
            us8 vv = *(const us8*)(vb + (size_t)d * Tc + l * 8);
            us8 o;
#pragma unroll
            for (int e = 0; e < 8; ++e)
                o[e] = f2bf(bf2f(vv[e]) * 512.f * breg[e]);
            *(us8*)(ob + (size_t)d * Tc + l * 8) = o;
        }
        avec[n * Tc + tid] = a[tid];
    }
}

// ---------------- y = a_i * (E @ vTs) via MFMA (bf16 out) -----------------
__global__ __launch_bounds__(256)
void piv_mfma(const ushortT* __restrict__ E, const ushortT* __restrict__ vTs,
              const float* __restrict__ avec, ushortT* __restrict__ y)
{
    int n = blockIdx.y; int b = n / Hc, h = n - b * Hc;
    int m0 = blockIdx.x * 128;
    const ushortT* Ap = E + (size_t)n * Tc * Tc;
    const ushortT* Bv = vTs + (size_t)n * HDc * Tc;
    __shared__ __align__(16) ushortT Als[128][32];
    __shared__ __align__(16) ushortT Bls[64][32];
    int tid = threadIdx.x;
    int lane = tid & 63, wid = tid >> 6;
    int wm = wid >> 1, wn = wid & 1;
    f32x4 acc[4][2];
    const f32x4 fz = {0.f, 0.f, 0.f, 0.f};
#pragma unroll
    for (int i = 0; i < 4; ++i)
#pragma unroll
        for (int j = 0; j < 2; ++j) acc[i][j] = fz;

    for (int k0 = 0; k0 < Tc; k0 += 32) {
#pragma unroll
        for (int is = 0; is < 2; ++is) {
            int ch = is * 256 + tid;
            int m = ch >> 2, kc = ch & 3;
            gll16(Ap + (size_t)(m0 + m) * Tc + k0 + kc * 8, &Als[0][0] + ch * 8);
        }
        {
            int ch = tid;
            int d = ch >> 2, kc = ch & 3;
            gll16(Bv + (size_t)d * Tc + k0 + kc * 8, &Bls[0][0] + ch * 8);
        }
        __syncthreads();
        bf16x8 af[4], bfv[2];
#pragma unroll
        for (int i = 0; i < 4; ++i) {
            int row = wm * 64 + i * 16 + (lane & 15);
            af[i] = *(const bf16x8*)&Als[row][(lane >> 4) * 8];
        }
#pragma unroll
        for (int j = 0; j < 2; ++j) {
            int col = wn * 32 + j * 16 + (lane & 15);
            bfv[j] = *(const bf16x8*)&Bls[col][(lane >> 4) * 8];
        }
#pragma unroll
        for (int i = 0; i < 4; ++i)
#pragma unroll
            for (int j = 0; j < 2; ++j)
                acc[i][j] = __builtin_amdgcn_mfma_f32_16x16x32_bf16(af[i], bfv[j], acc[i][j], 0, 0, 0);
        __syncthreads();
    }
#pragma unroll
    for (int i = 0; i < 4; ++i)
#pragma unroll
        for (int j = 0; j < 2; ++j)
#pragma unroll
            for (int r = 0; r < 4; ++r) {
                int rIn = m0 + wm * 64 + i * 16 + (lane >> 4) * 4 + r;
                float a_r = avec[n * Tc + rIn];
                int row = b * Tc + rIn;
                int col = h * HDc + wn * 32 + j * 16 + (lane & 15);
                y[(size_t)row * Cc + col] = f2bf(acc[i][j][r] * a_r);
            }
}

// ---------------- split-K reduce + Euler: z += h*(sum parts + bias) -------
__global__ __launch_bounds__(256)
void mlp_reduce(const float* __restrict__ parts, const float* __restrict__ bias,
                float* __restrict__ z)
{
    int i4 = (blockIdx.x * 256 + threadIdx.x) * 4;
    const size_t CS = (size_t)BTc * Cc;
    f32x4 a = *(const f32x4*)(parts + i4);
    f32x4 b = *(const f32x4*)(parts + CS + i4);
    f32x4 c = *(const f32x4*)(parts + 2 * CS + i4);
    f32x4 d = *(const f32x4*)(parts + 3 * CS + i4);
    int col = i4 - (i4 / Cc) * Cc;
    f32x4 bb = *(const f32x4*)(bias + col);
    f32x4 zz = *(const f32x4*)(z + i4);
#pragma unroll
    for (int e = 0; e < 4; ++e)
        zz[e] += H_STEP * (a[e] + b[e] + c[e] + d[e] + bb[e]);
    *(f32x4*)(z + i4) = zz;
}

// ---------------- logits: out[b,v] = xf[b,:] . wte[v,:] (fp32) ------------
__global__ __launch_bounds__(256)
void logits_kernel(const float* __restrict__ xf, const float* __restrict__ wte,
                   float* __restrict__ out)
{
    __shared__ float xs[2 * Cc];
    int tid = threadIdx.x;
    for (int l = tid; l < 2 * Cc; l += 256) xs[l] = xf[l];
    __syncthreads();
    int w = tid >> 6, lane = tid & 63;
    int vrow = blockIdx.x * 4 + w;
    const float* wr = wte + (size_t)vrow * Cc;
    float a0 = 0.f, a1 = 0.f;
    for (int k = lane; k < Cc; k += 64) {
        float wv = wr[k];
        a0 += wv * xs[k];
        a1 += wv * xs[Cc + k];
    }
    for (int o = 32; o; o >>= 1) {
        a0 += __shfl_down(a0, o);
        a1 += __shfl_down(a1, o);
    }
    if (lane == 0) {
        out[vrow] = a0;
        out[Vc + vrow] = a1;
    }
}

// ==========================================================================
extern "C" void kernel_launch(void* const* d_in, const int* in_sizes, int n_in,
                              void* d_out, int out_size, void* d_ws, size_t ws_size,
                              hipStream_t stream)
{
    const int*   idx        = (const int*)  d_in[0];
    const float* wte        = (const float*)d_in[1];
    const float* wpe        = (const float*)d_in[2];
    const float* attn_ln_w  = (const float*)d_in[3];
    const float* attn_ln_b  = (const float*)d_in[4];
    const float* c_attn_w   = (const float*)d_in[5];
    const float* c_attn_b   = (const float*)d_in[6];
    const float* c_proj_w   = (const float*)d_in[7];
    const float* c_proj_b   = (const float*)d_in[8];
    const float* mlp_ln_w   = (const float*)d_in[9];
    const float* mlp_ln_b   = (const float*)d_in[10];
    const float* c_fc_w     = (const float*)d_in[11];
    const float* c_fc_b     = (const float*)d_in[12];
    const float* mlp_proj_w = (const float*)d_in[13];
    const float* mlp_proj_b = (const float*)d_in[14];
    const float* lnf_w      = (const float*)d_in[15];
    const float* lnf_b      = (const float*)d_in[16];
    float* out = (float*)d_out;

    // -------- workspace carving (256B aligned) --------
    char* base = (char*)d_ws;
    size_t off = 0;
    auto alloc = [&](size_t bytes) -> void* {
        void* p = base + off;
        off = (off + bytes + 255) & ~(size_t)255;
        return p;
    };
    float*   z     = (float*)  alloc((size_t)BTc * Cc * 4);
    float*   ao    = (float*)  alloc((size_t)BTc * Cc * 4);
    float*   Sbuf  = (float*)  alloc((size_t)NHc * Tc * Tc * 4);  // 25MB; parts/h1 alias
    ushortT* E     = (ushortT*)alloc((size_t)NHc * Tc * Tc * 2);
    ushortT* qkvb  = (ushortT*)alloc((size_t)BTc * C3 * 2);
    ushortT* xlnb  = (ushortT*)alloc((size_t)BTc * Cc * 2);
    ushortT* y     = (ushortT*)alloc((size_t)BTc * Cc * 2);
    ushortT* vT    = (ushortT*)alloc((size_t)NHc * HDc * Tc * 2);
    ushortT* vTs   = (ushortT*)alloc((size_t)NHc * HDc * Tc * 2);
    float*   xt    = (float*)  alloc(BTc * 4);
    float*   avec  = (float*)  alloc(NHc * Tc * 4);
    float*   xf    = (float*)  alloc(2 * Cc * 4);
    ushortT* WqkvT = (ushortT*)alloc((size_t)C3 * Cc * 2);
    ushortT* WprojT= (ushortT*)alloc((size_t)Cc * Cc * 2);
    ushortT* WfcT  = (ushortT*)alloc((size_t)C4 * Cc * 2);
    ushortT* WmlpT = (ushortT*)alloc((size_t)Cc * C4 * 2);
    // aliases inside Sbuf (S dead once sinkhead is done each step)
    float*   parts = (float*)Sbuf;                          // 4 x 3MB fp32
    ushortT* h1    = (ushortT*)((char*)Sbuf + (13u << 20)); // 6.3MB bf16

    embed_kernel<<<(BTc * Cc + 255) / 256, 256, 0, stream>>>(idx, wte, wpe, z);
    wtrans_kernel<<<dim3(Cc / 32, C3 / 32), 256, 0, stream>>>(c_attn_w,   WqkvT,  Cc, C3);
    wtrans_kernel<<<dim3(Cc / 32, Cc / 32), 256, 0, stream>>>(c_proj_w,   WprojT, Cc, Cc);
    wtrans_kernel<<<dim3(Cc / 32, C4 / 32), 256, 0, stream>>>(c_fc_w,     WfcT,   Cc, C4);
    wtrans_kernel<<<dim3(C4 / 32, Cc / 32), 256, 0, stream>>>(mlp_proj_w, WmlpT,  C4, Cc);

    float t = 0.f;
    for (int step = 0; step < 20; ++step) {
        ln_kernel<<<BTc, 256, 0, stream>>>(z, attn_ln_w, attn_ln_b, xlnb, xt, 1, t, 1, 0, 1);
        gemm_bt<0><<<dim3(C3 / 128, BTc / 128), 256, 0, stream>>>(
            xlnb, Cc, WqkvT, Cc, qkvb, C3, Cc,
            c_attn_b, xt, c_attn_w + (size_t)Cc * C3);
        vtrans_kernel<<<dim3(Tc / 32, HDc / 32, NHc), 256, 0, stream>>>(qkvb, vT);
        qk_mfma<<<dim3(Tc / 128, Tc / 128, NHc), 256, 0, stream>>>(qkvb, Sbuf);
        sinkhead<<<NHc, 512, 0, stream>>>(Sbuf, E, avec, vT, vTs);
        piv_mfma<<<dim3(Tc / 128, NHc), 256, 0, stream>>>(E, vTs, avec, y);
        gemm_bt<3><<<dim3(Cc / 128, BTc / 128), 256, 0, stream>>>(
            y, Cc, WprojT, Cc, ao, Cc, Cc,
            c_proj_b, nullptr, nullptr);
        ln_kernel<<<BTc, 256, 0, stream>>>(ao, mlp_ln_w, mlp_ln_b, xlnb, xt, 1, t, 1, 0, 1);
        gemm_bt<1><<<dim3(C4 / 128, BTc / 128), 256, 0, stream>>>(
            xlnb, Cc, WfcT, Cc, h1, C4, Cc,
            c_fc_b, xt, c_fc_w + (size_t)Cc * C4);
        gemm_bt<4><<<dim3(Cc / 128, BTc / 128, 4), 256, 0, stream>>>(
            h1, C4, WmlpT, C4, parts, Cc, C4 / 4,
            nullptr, nullptr, nullptr);
        mlp_reduce<<<(BTc * Cc) / 1024, 256, 0, stream>>>(parts, mlp_proj_b, z);
        t += H_STEP;
    }

    ln_kernel<<<2, 256, 0, stream>>>(z, lnf_w, lnf_b, xf, nullptr, 0, 0.f, Tc, Tc - 1, 0);
    logits_kernel<<<Vc / 4, 256, 0, stream>>>(xf, wte, out);
}

// Round 5
// 4484.682 us; speedup vs baseline: 3.5042x; 1.6243x over previous
//
#include <hip/hip_runtime.h>
#include <hip/hip_bf16.h>
#include <math.h>

typedef unsigned short ushortT;
typedef unsigned int uintT;

// Problem constants
#define Bc   2
#define Tc   512
#define Cc   768
#define Hc   12
#define HDc  64
#define Vc   50304
#define BTc  (Bc*Tc)          // 1024
#define NHc  (Bc*Hc)          // 24
#define C3   (3*Cc)           // 2304
#define C4   (4*Cc)           // 3072
#define EPS_LN 1e-5f
#define H_STEP 0.05f
#define INVN (1.0f/512.0f)
#define SB   4                // blocks per head in sinkhorn

typedef float f32x4 __attribute__((ext_vector_type(4)));
typedef __bf16 bf16x8 __attribute__((ext_vector_type(8)));
typedef ushortT us8 __attribute__((ext_vector_type(8)));
typedef uintT u32x4 __attribute__((ext_vector_type(4)));

// ---------------- bf16 helpers --------------------------------------------
__device__ __forceinline__ ushortT f2bf(float f) {
    union { float f; unsigned u; } x; x.f = f;
    unsigned r = (x.u + 0x7fffu + ((x.u >> 16) & 1u)) >> 16;
    return (ushortT)r;
}
__device__ __forceinline__ float bf2f(ushortT b) {
    union { unsigned u; float f; } x; x.u = ((unsigned)b) << 16;
    return x.f;
}
__device__ __forceinline__ float bflo(uintT w) {
    union { unsigned u; float f; } x; x.u = w << 16;
    return x.f;
}
__device__ __forceinline__ float bfhi(uintT w) {
    union { unsigned u; float f; } x; x.u = w & 0xffff0000u;
    return x.f;
}

// async global->LDS, 16 bytes per lane
__device__ __forceinline__ void gll16(const ushortT* g, ushortT* l) {
    __builtin_amdgcn_global_load_lds(
        (const __attribute__((address_space(1))) unsigned int*)g,
        (__attribute__((address_space(3))) unsigned int*)l,
        16, 0, 0);
}

// ---------------- wave reductions -----------------------------------------
__device__ __forceinline__ float waveReduceMaxX(float v) {
    for (int o = 32; o; o >>= 1) v = fmaxf(v, __shfl_xor(v, o));
    return v;
}
__device__ __forceinline__ float waveReduceSumX(float v) {
    for (int o = 32; o; o >>= 1) v += __shfl_xor(v, o);
    return v;
}
__device__ __forceinline__ float blockReduceSum(float v) {
    __shared__ float sm[4];
    for (int o = 32; o; o >>= 1) v += __shfl_down(v, o);
    __syncthreads();
    if ((threadIdx.x & 63) == 0) sm[threadIdx.x >> 6] = v;
    __syncthreads();
    return sm[0] + sm[1] + sm[2] + sm[3];
}

// ---------------- embedding: z = wte[idx] + wpe[t] ------------------------
__global__ __launch_bounds__(256)
void embed_kernel(const int* __restrict__ idx, const float* __restrict__ wte,
                  const float* __restrict__ wpe, float* __restrict__ z)
{
    int i = blockIdx.x * 256 + threadIdx.x;
    if (i >= BTc * Cc) return;
    int r = i / Cc, c = i - r * Cc;
    int tok = idx[r];
    z[i] = wte[(size_t)tok * Cc + c] + wpe[(size_t)(r & (Tc - 1)) * Cc + c];
}

// ---------------- weight fp32 [K][N] -> bf16 [N][K] transpose -------------
__global__ __launch_bounds__(256)
void wtrans_kernel(const float* __restrict__ W, ushortT* __restrict__ out,
                   int K, int N)
{
    __shared__ float t[32][33];
    int k0 = blockIdx.x * 32, n0 = blockIdx.y * 32;
    int tx = threadIdx.x & 31, ty = threadIdx.x >> 5;
    for (int r = ty; r < 32; r += 8)
        t[r][tx] = W[(size_t)(k0 + r) * N + n0 + tx];
    __syncthreads();
    for (int r = ty; r < 32; r += 8)
        out[(size_t)(n0 + r) * K + k0 + tx] = f2bf(t[tx][r]);
}

// ---------------- v-part of qkv (bf16) -> vT [NH][64][512] ----------------
__global__ __launch_bounds__(256)
void vtrans_kernel(const ushortT* __restrict__ qkv, ushortT* __restrict__ vT)
{
    __shared__ ushortT t[32][33];
    int n = blockIdx.z; int b = n / Hc, h = n - b * Hc;
    int t0 = blockIdx.x * 32, d0 = blockIdx.y * 32;
    int tx = threadIdx.x & 31, ty = threadIdx.x >> 5;
    const ushortT* src = qkv + (size_t)(b * Tc) * C3 + 2 * Cc + h * HDc;
    for (int r = ty; r < 32; r += 8)
        t[r][tx] = src[(size_t)(t0 + r) * C3 + d0 + tx];
    __syncthreads();
    ushortT* dst = vT + (size_t)n * HDc * Tc;
    for (int r = ty; r < 32; r += 8)
        dst[(size_t)(d0 + r) * Tc + t0 + tx] = t[tx][r];
}

// ---------------- LayerNorm over 768 dims (+optional time column) ---------
__global__ __launch_bounds__(256)
void ln_kernel(const float* __restrict__ X, const float* __restrict__ w,
               const float* __restrict__ bb, void* __restrict__ Y,
               float* __restrict__ yt, int hasT, float tval,
               int rowMul, int rowAdd, int obf16)
{
    int orow = blockIdx.x;
    int r = orow * rowMul + rowAdd;
    const float* x = X + (size_t)r * Cc;
    int tid = threadIdx.x;
    float xv[3];
#pragma unroll
    for (int q = 0; q < 3; ++q) xv[q] = x[tid + 256 * q];
    float s = xv[0] + xv[1] + xv[2];
    s = blockReduceSum(s);
    float cnt = hasT ? (float)(Cc + 1) : (float)Cc;
    float mu = (s + (hasT ? tval : 0.f)) / cnt;
    float d0 = xv[0] - mu, d1 = xv[1] - mu, d2 = xv[2] - mu;
    float ss = d0 * d0 + d1 * d1 + d2 * d2;
    __syncthreads();
    ss = blockReduceSum(ss);
    float dt = tval - mu;
    float var = (ss + (hasT ? dt * dt : 0.f)) / cnt;
    float rs = rsqrtf(var + EPS_LN);
#pragma unroll
    for (int q = 0; q < 3; ++q) {
        int c = tid + 256 * q;
        float v = (xv[q] - mu) * rs * w[c] + bb[c];
        if (obf16) ((ushortT*)Y)[(size_t)orow * Cc + c] = f2bf(v);
        else       ((float*)Y)[(size_t)orow * Cc + c] = v;
    }
    if (hasT && tid == 0) yt[orow] = dt * rs * w[Cc] + bb[Cc];
}

// ---------------- MFMA GEMM: C = A[M,K](bf16) @ Bt[N,K](bf16)^T -----------
// EPI: 0 = bias(+rank1) -> bf16 ; 1 = gelu(bias+rank1) -> bf16 ;
//      3 = bias -> fp32 ; 4 = split-K partial fp32 (blockIdx.z chunks)
template <int EPI>
__global__ __launch_bounds__(256)
void gemm_bt(const ushortT* __restrict__ A, int lda,
             const ushortT* __restrict__ Bt, int ldb,
             void* __restrict__ Cm, int ldc, int K,
             const float* __restrict__ bias,
             const float* __restrict__ extraA,
             const float* __restrict__ extraB)
{
    __shared__ __align__(16) ushortT Als[128][32];
    __shared__ __align__(16) ushortT Bls[128][32];
    if (EPI == 4) {
        int koff = blockIdx.z * K;
        A += koff; Bt += koff;
    }
    int tid = threadIdx.x;
    int lane = tid & 63, wid = tid >> 6;
    int wm = wid >> 1, wn = wid & 1;
    int m0 = blockIdx.y * 128, n0 = blockIdx.x * 128;
    f32x4 acc[4][4];
    const f32x4 fz = {0.f, 0.f, 0.f, 0.f};
#pragma unroll
    for (int i = 0; i < 4; ++i)
#pragma unroll
        for (int j = 0; j < 4; ++j) acc[i][j] = fz;

    for (int k0 = 0; k0 < K; k0 += 32) {
#pragma unroll
        for (int is = 0; is < 2; ++is) {
            int ch = is * 256 + tid;
            int m = ch >> 2, kc = ch & 3;
            gll16(A + (size_t)(m0 + m) * lda + k0 + kc * 8, &Als[0][0] + ch * 8);
            gll16(Bt + (size_t)(n0 + m) * ldb + k0 + kc * 8, &Bls[0][0] + ch * 8);
        }
        __syncthreads();
        bf16x8 af[4], bfv[4];
#pragma unroll
        for (int i = 0; i < 4; ++i) {
            int row = wm * 64 + i * 16 + (lane & 15);
            af[i] = *(const bf16x8*)&Als[row][(lane >> 4) * 8];
            int col = wn * 64 + i * 16 + (lane & 15);
            bfv[i] = *(const bf16x8*)&Bls[col][(lane >> 4) * 8];
        }
#pragma unroll
        for (int i = 0; i < 4; ++i)
#pragma unroll
            for (int j = 0; j < 4; ++j)
                acc[i][j] = __builtin_amdgcn_mfma_f32_16x16x32_bf16(af[i], bfv[j], acc[i][j], 0, 0, 0);
        __syncthreads();
    }
#pragma unroll
    for (int i = 0; i < 4; ++i) {
#pragma unroll
        for (int j = 0; j < 4; ++j) {
#pragma unroll
            for (int r = 0; r < 4; ++r) {
                int row = m0 + wm * 64 + i * 16 + (lane >> 4) * 4 + r;
                int col = n0 + wn * 64 + j * 16 + (lane & 15);
                float v = acc[i][j][r];
                if (extraA) v += extraA[row] * extraB[col];
                if (bias) v += bias[col];
                size_t oi = (size_t)row * ldc + col;
                if (EPI == 0) {
                    ((ushortT*)Cm)[oi] = f2bf(v);
                } else if (EPI == 1) {
                    v = 0.5f * v * (1.f + erff(v * 0.70710678118654752440f));
                    ((ushortT*)Cm)[oi] = f2bf(v);
                } else if (EPI == 3) {
                    ((float*)Cm)[oi] = v;
                } else if (EPI == 4) {
                    ((float*)Cm)[(size_t)blockIdx.z * ((size_t)BTc * Cc) + oi] = v;
                }
            }
        }
    }
}

// ---------------- QK^T via MFMA: S = q@k^T / 8 (fp32 out), causal skip ----
__global__ __launch_bounds__(256)
void qk_mfma(const ushortT* __restrict__ qkv, float* __restrict__ S)
{
    int n = blockIdx.z; int b = n / Hc, h = n - b * Hc;
    int m0 = blockIdx.y * 128, n0 = blockIdx.x * 128;
    if (n0 > m0 + 127) return;
    const ushortT* Aq = qkv + (size_t)(b * Tc) * C3 + h * HDc;
    const ushortT* Bk = Aq + Cc;
    __shared__ __align__(16) ushortT Als[128][32];
    __shared__ __align__(16) ushortT Bls[128][32];
    int tid = threadIdx.x;
    int lane = tid & 63, wid = tid >> 6;
    int wm = wid >> 1, wn = wid & 1;
    f32x4 acc[4][4];
    const f32x4 fz = {0.f, 0.f, 0.f, 0.f};
#pragma unroll
    for (int i = 0; i < 4; ++i)
#pragma unroll
        for (int j = 0; j < 4; ++j) acc[i][j] = fz;

    for (int k0 = 0; k0 < HDc; k0 += 32) {
#pragma unroll
        for (int is = 0; is < 2; ++is) {
            int ch = is * 256 + tid;
            int m = ch >> 2, kc = ch & 3;
            gll16(Aq + (size_t)(m0 + m) * C3 + k0 + kc * 8, &Als[0][0] + ch * 8);
            gll16(Bk + (size_t)(n0 + m) * C3 + k0 + kc * 8, &Bls[0][0] + ch * 8);
        }
        __syncthreads();
        bf16x8 af[4], bfv[4];
#pragma unroll
        for (int i = 0; i < 4; ++i) {
            int row = wm * 64 + i * 16 + (lane & 15);
            af[i] = *(const bf16x8*)&Als[row][(lane >> 4) * 8];
            int col = wn * 64 + i * 16 + (lane & 15);
            bfv[i] = *(const bf16x8*)&Bls[col][(lane >> 4) * 8];
        }
#pragma unroll
        for (int i = 0; i < 4; ++i)
#pragma unroll
            for (int j = 0; j < 4; ++j)
                acc[i][j] = __builtin_amdgcn_mfma_f32_16x16x32_bf16(af[i], bfv[j], acc[i][j], 0, 0, 0);
        __syncthreads();
    }
    float* Sb = S + (size_t)n * Tc * Tc;
#pragma unroll
    for (int i = 0; i < 4; ++i)
#pragma unroll
        for (int j = 0; j < 4; ++j)
#pragma unroll
            for (int r = 0; r < 4; ++r) {
                int row = m0 + wm * 64 + i * 16 + (lane >> 4) * 4 + r;
                int col = n0 + wn * 64 + j * 16 + (lane & 15);
                Sb[(size_t)row * Tc + col] = acc[i][j][r] * 0.125f;
            }
}

// ===================== 4-blocks-per-head LDS-resident Sinkhorn ============
// grid = 96 blocks x 512 threads. Block (n, r) owns rows [r*128, r*128+128)
// of head n, resident in LDS (128KB). Row passes are LDS-local; col passes
// exchange 512 partial sums via global + a 4-block counter barrier (6/step).
__global__ __launch_bounds__(512)
void sinkhead4(const float* __restrict__ S, ushortT* __restrict__ E,
               float* __restrict__ avec, const ushortT* __restrict__ vT,
               ushortT* __restrict__ vTs, float* __restrict__ partials,
               unsigned* __restrict__ ctr, unsigned barBase)
{
    int gb = blockIdx.x;
    int n = gb >> 2, r = gb & 3;
    int row0 = r * 128;
    int tid = threadIdx.x;
    int l = tid & 63, w = tid >> 6;          // 8 waves
    __shared__ __align__(16) ushortT Els[128][Tc];   // 128 KB
    __shared__ float a_s[128];
    __shared__ float b_s[Tc];
    const float* Sb = S + (size_t)n * Tc * Tc;
    ushortT* Eg = E + (size_t)n * Tc * Tc;

    // ---- phase 0: causal softmax rows -> E (LDS + global), rowsum -> a1 ----
#pragma unroll 1
    for (int it = 0; it < 16; ++it) {
        int rr = it * 8 + w;                 // 0..127 local row
        int row = row0 + rr;                 // absolute row
        const float* sr = Sb + (size_t)row * Tc + l * 8;
        f32x4 v0 = *(const f32x4*)sr;
        f32x4 v1 = *(const f32x4*)(sr + 4);
        float x[8] = {v0[0], v0[1], v0[2], v0[3], v1[0], v1[1], v1[2], v1[3]};
        float mx = -INFINITY;
#pragma unroll
        for (int e = 0; e < 8; ++e)
            if (l * 8 + e <= row) mx = fmaxf(mx, x[e]);
        mx = waveReduceMaxX(mx);
        float ex[8], se = 0.f;
#pragma unroll
        for (int e = 0; e < 8; ++e) {
            ex[e] = (l * 8 + e <= row) ? __expf(x[e] - mx) : 0.f;
            se += ex[e];
        }
        se = waveReduceSumX(se);
        float inv = 1.f / se;
        us8 pack; float rs = 0.f;
#pragma unroll
        for (int e = 0; e < 8; ++e) {
            float Ee = __expf(-(ex[e] * inv));   // masked: exp(-0)=1 (matches ref)
            rs += Ee;
            pack[e] = f2bf(Ee);
        }
        rs = waveReduceSumX(rs);
        *(us8*)(&Els[rr][l * 8]) = pack;
        *(us8*)(Eg + (size_t)row * Tc + l * 8) = pack;
        if (l == 0) a_s[rr] = INVN / rs;
    }
    __syncthreads();

    float* mypart = partials + (size_t)(n * SB + r) * Tc;
    const float* hpart = partials + (size_t)n * SB * Tc;
    unsigned* myctr = ctr + n * 16;          // 64B-padded per-head counter

    // ---- 11 alternating passes: col(0),row(1),...,col(10) ----
#pragma unroll 1
    for (int p = 0; p < 11; ++p) {
        if ((p & 1) == 0) {
            // col partial over own 128 rows; thread = column
            int j = tid;
            float acc = 0.f;
#pragma unroll 1
            for (int i = 0; i < 128; i += 8) {
                float part = 0.f;
#pragma unroll
                for (int k = 0; k < 8; ++k)
                    part += bf2f(Els[i + k][j]) * a_s[i + k];
                acc += part;
            }
            __hip_atomic_store(&mypart[j], acc, __ATOMIC_RELAXED, __HIP_MEMORY_SCOPE_AGENT);
            __syncthreads();
            if (tid == 0) {
                __threadfence();
                atomicAdd(myctr, 1u);
                unsigned tgt = barBase + (unsigned)(p / 2 + 1) * SB;
                while (__hip_atomic_load(myctr, __ATOMIC_ACQUIRE, __HIP_MEMORY_SCOPE_AGENT) < tgt)
                    __builtin_amdgcn_s_sleep(2);
            }
            __syncthreads();
            float s0 = __hip_atomic_load(&hpart[j], __ATOMIC_RELAXED, __HIP_MEMORY_SCOPE_AGENT);
            float s1 = __hip_atomic_load(&hpart[Tc + j], __ATOMIC_RELAXED, __HIP_MEMORY_SCOPE_AGENT);
            float s2 = __hip_atomic_load(&hpart[2 * Tc + j], __ATOMIC_RELAXED, __HIP_MEMORY_SCOPE_AGENT);
            float s3 = __hip_atomic_load(&hpart[3 * Tc + j], __ATOMIC_RELAXED, __HIP_MEMORY_SCOPE_AGENT);
            b_s[j] = INVN / (s0 + s1 + s2 + s3);
            __syncthreads();
        } else {
            // row pass on own rows: wave per 16 rows, ILP 4
            f32x4 b0 = *(const f32x4*)&b_s[l * 8];
            f32x4 b1 = *(const f32x4*)&b_s[l * 8 + 4];
            float breg[8] = {b0[0], b0[1], b0[2], b0[3], b1[0], b1[1], b1[2], b1[3]};
#pragma unroll 1
            for (int k = 0; k < 16; k += 4) {
                int r0 = w * 16 + k;
                u32x4 q0 = *(const u32x4*)(&Els[r0 + 0][l * 8]);
                u32x4 q1 = *(const u32x4*)(&Els[r0 + 1][l * 8]);
                u32x4 q2 = *(const u32x4*)(&Els[r0 + 2][l * 8]);
                u32x4 q3 = *(const u32x4*)(&Els[r0 + 3][l * 8]);
                float s0 = 0.f, s1 = 0.f, s2 = 0.f, s3 = 0.f;
#pragma unroll
                for (int c = 0; c < 4; ++c) {
                    s0 += bflo(q0[c]) * breg[2 * c] + bfhi(q0[c]) * breg[2 * c + 1];
                    s1 += bflo(q1[c]) * breg[2 * c] + bfhi(q1[c]) * breg[2 * c + 1];
                    s2 += bflo(q2[c]) * breg[2 * c] + bfhi(q2[c]) * breg[2 * c + 1];
                    s3 += bflo(q3[c]) * breg[2 * c] + bfhi(q3[c]) * breg[2 * c + 1];
                }
                s0 = waveReduceSumX(s0);
                s1 = waveReduceSumX(s1);
                s2 = waveReduceSumX(s2);
                s3 = waveReduceSumX(s3);
                if (l == 0) {
                    a_s[r0 + 0] = INVN / s0;
                    a_s[r0 + 1] = INVN / s1;
                    a_s[r0 + 2] = INVN / s2;
                    a_s[r0 + 3] = INVN / s3;
                }
            }
            __syncthreads();
        }
    }

    // ---- vscale own 16 d-rows: vTs = vT * (n*b6); write avec (a6) ----
    {
        f32x4 b0 = *(const f32x4*)&b_s[l * 8];
        f32x4 b1 = *(const f32x4*)&b_s[l * 8 + 4];
        float breg[8] = {b0[0], b0[1], b0[2], b0[3], b1[0], b1[1], b1[2], b1[3]};
        const ushortT* vb = vT + (size_t)n * HDc * Tc;
        ushortT* ob = vTs + (size_t)n * HDc * Tc;
#pragma unroll
        for (int dd = 0; dd < 2; ++dd) {
            int d = r * 16 + w * 2 + dd;
            us8 vv = *(const us8*)(vb + (size_t)d * Tc + l * 8);
            us8 o;
#pragma unroll
            for (int e = 0; e < 8; ++e)
                o[e] = f2bf(bf2f(vv[e]) * 512.f * breg[e]);
            *(us8*)(ob + (size_t)d * Tc + l * 8) = o;
        }
        if (tid < 128) avec[n * Tc + row0 + tid] = a_s[tid];
    }
}

// ---------------- y = a_i * (E @ vTs) via MFMA (bf16 out) -----------------
__global__ __launch_bounds__(256)
void piv_mfma(const ushortT* __restrict__ E, const ushortT* __restrict__ vTs,
              const float* __restrict__ avec, ushortT* __restrict__ y)
{
    int n = blockIdx.y; int b = n / Hc, h = n - b * Hc;
    int m0 = blockIdx.x * 128;
    const ushortT* Ap = E + (size_t)n * Tc * Tc;
    const ushortT* Bv = vTs + (size_t)n * HDc * Tc;
    __shared__ __align__(16) ushortT Als[128][32];
    __shared__ __align__(16) ushortT Bls[64][32];
    int tid = threadIdx.x;
    int lane = tid & 63, wid = tid >> 6;
    int wm = wid >> 1, wn = wid & 1;
    f32x4 acc[4][2];
    const f32x4 fz = {0.f, 0.f, 0.f, 0.f};
#pragma unroll
    for (int i = 0; i < 4; ++i)
#pragma unroll
        for (int j = 0; j < 2; ++j) acc[i][j] = fz;

    for (int k0 = 0; k0 < Tc; k0 += 32) {
#pragma unroll
        for (int is = 0; is < 2; ++is) {
            int ch = is * 256 + tid;
            int m = ch >> 2, kc = ch & 3;
            gll16(Ap + (size_t)(m0 + m) * Tc + k0 + kc * 8, &Als[0][0] + ch * 8);
        }
        {
            int ch = tid;
            int d = ch >> 2, kc = ch & 3;
            gll16(Bv + (size_t)d * Tc + k0 + kc * 8, &Bls[0][0] + ch * 8);
        }
        __syncthreads();
        bf16x8 af[4], bfv[2];
#pragma unroll
        for (int i = 0; i < 4; ++i) {
            int row = wm * 64 + i * 16 + (lane & 15);
            af[i] = *(const bf16x8*)&Als[row][(lane >> 4) * 8];
        }
#pragma unroll
        for (int j = 0; j < 2; ++j) {
            int col = wn * 32 + j * 16 + (lane & 15);
            bfv[j] = *(const bf16x8*)&Bls[col][(lane >> 4) * 8];
        }
#pragma unroll
        for (int i = 0; i < 4; ++i)
#pragma unroll
            for (int j = 0; j < 2; ++j)
                acc[i][j] = __builtin_amdgcn_mfma_f32_16x16x32_bf16(af[i], bfv[j], acc[i][j], 0, 0, 0);
        __syncthreads();
    }
#pragma unroll
    for (int i = 0; i < 4; ++i)
#pragma unroll
        for (int j = 0; j < 2; ++j)
#pragma unroll
            for (int r = 0; r < 4; ++r) {
                int rIn = m0 + wm * 64 + i * 16 + (lane >> 4) * 4 + r;
                float a_r = avec[n * Tc + rIn];
                int row = b * Tc + rIn;
                int col = h * HDc + wn * 32 + j * 16 + (lane & 15);
                y[(size_t)row * Cc + col] = f2bf(acc[i][j][r] * a_r);
            }
}

// ---------------- split-K reduce + Euler: z += h*(sum parts + bias) -------
__global__ __launch_bounds__(256)
void mlp_reduce(const float* __restrict__ parts, const float* __restrict__ bias,
                float* __restrict__ z)
{
    int i4 = (blockIdx.x * 256 + threadIdx.x) * 4;
    const size_t CS = (size_t)BTc * Cc;
    f32x4 a = *(const f32x4*)(parts + i4);
    f32x4 b = *(const f32x4*)(parts + CS + i4);
    f32x4 c = *(const f32x4*)(parts + 2 * CS + i4);
    f32x4 d = *(const f32x4*)(parts + 3 * CS + i4);
    int col = i4 - (i4 / Cc) * Cc;
    f32x4 bb = *(const f32x4*)(bias + col);
    f32x4 zz = *(const f32x4*)(z + i4);
#pragma unroll
    for (int e = 0; e < 4; ++e)
        zz[e] += H_STEP * (a[e] + b[e] + c[e] + d[e] + bb[e]);
    *(f32x4*)(z + i4) = zz;
}

// ---------------- logits: out[b,v] = xf[b,:] . wte[v,:] (fp32) ------------
__global__ __launch_bounds__(256)
void logits_kernel(const float* __restrict__ xf, const float* __restrict__ wte,
                   float* __restrict__ out)
{
    __shared__ float xs[2 * Cc];
    int tid = threadIdx.x;
    for (int l = tid; l < 2 * Cc; l += 256) xs[l] = xf[l];
    __syncthreads();
    int w = tid >> 6, lane = tid & 63;
    int vrow = blockIdx.x * 4 + w;
    const float* wr = wte + (size_t)vrow * Cc;
    float a0 = 0.f, a1 = 0.f;
    for (int k = lane; k < Cc; k += 64) {
        float wv = wr[k];
        a0 += wv * xs[k];
        a1 += wv * xs[Cc + k];
    }
    for (int o = 32; o; o >>= 1) {
        a0 += __shfl_down(a0, o);
        a1 += __shfl_down(a1, o);
    }
    if (lane == 0) {
        out[vrow] = a0;
        out[Vc + vrow] = a1;
    }
}

// ==========================================================================
extern "C" void kernel_launch(void* const* d_in, const int* in_sizes, int n_in,
                              void* d_out, int out_size, void* d_ws, size_t ws_size,
                              hipStream_t stream)
{
    const int*   idx        = (const int*)  d_in[0];
    const float* wte        = (const float*)d_in[1];
    const float* wpe        = (const float*)d_in[2];
    const float* attn_ln_w  = (const float*)d_in[3];
    const float* attn_ln_b  = (const float*)d_in[4];
    const float* c_attn_w   = (const float*)d_in[5];
    const float* c_attn_b   = (const float*)d_in[6];
    const float* c_proj_w   = (const float*)d_in[7];
    const float* c_proj_b   = (const float*)d_in[8];
    const float* mlp_ln_w   = (const float*)d_in[9];
    const float* mlp_ln_b   = (const float*)d_in[10];
    const float* c_fc_w     = (const float*)d_in[11];
    const float* c_fc_b     = (const float*)d_in[12];
    const float* mlp_proj_w = (const float*)d_in[13];
    const float* mlp_proj_b = (const float*)d_in[14];
    const float* lnf_w      = (const float*)d_in[15];
    const float* lnf_b      = (const float*)d_in[16];
    float* out = (float*)d_out;

    // -------- workspace carving (256B aligned) --------
    char* base = (char*)d_ws;
    size_t off = 0;
    auto alloc = [&](size_t bytes) -> void* {
        void* p = base + off;
        off = (off + bytes + 255) & ~(size_t)255;
        return p;
    };
    float*   z     = (float*)  alloc((size_t)BTc * Cc * 4);
    float*   ao    = (float*)  alloc((size_t)BTc * Cc * 4);
    float*   Sbuf  = (float*)  alloc((size_t)NHc * Tc * Tc * 4);  // 25MB; parts/h1 alias
    ushortT* E     = (ushortT*)alloc((size_t)NHc * Tc * Tc * 2);
    ushortT* qkvb  = (ushortT*)alloc((size_t)BTc * C3 * 2);
    ushortT* xlnb  = (ushortT*)alloc((size_t)BTc * Cc * 2);
    ushortT* y     = (ushortT*)alloc((size_t)BTc * Cc * 2);
    ushortT* vT    = (ushortT*)alloc((size_t)NHc * HDc * Tc * 2);
    ushortT* vTs   = (ushortT*)alloc((size_t)NHc * HDc * Tc * 2);
    float*   xt    = (float*)  alloc(BTc * 4);
    float*   avec  = (float*)  alloc(NHc * Tc * 4);
    float*   part  = (float*)  alloc((size_t)NHc * SB * Tc * 4);
    unsigned* ctr  = (unsigned*)alloc(NHc * 16 * 4);
    float*   xf    = (float*)  alloc(2 * Cc * 4);
    ushortT* WqkvT = (ushortT*)alloc((size_t)C3 * Cc * 2);
    ushortT* WprojT= (ushortT*)alloc((size_t)Cc * Cc * 2);
    ushortT* WfcT  = (ushortT*)alloc((size_t)C4 * Cc * 2);
    ushortT* WmlpT = (ushortT*)alloc((size_t)Cc * C4 * 2);
    // aliases inside Sbuf (S dead once sinkhead4 is done each step)
    float*   parts = (float*)Sbuf;                          // 4 x 3MB fp32
    ushortT* h1    = (ushortT*)((char*)Sbuf + (13u << 20)); // 6.3MB bf16

    hipMemsetAsync(ctr, 0, NHc * 16 * 4, stream);
    embed_kernel<<<(BTc * Cc + 255) / 256, 256, 0, stream>>>(idx, wte, wpe, z);
    wtrans_kernel<<<dim3(Cc / 32, C3 / 32), 256, 0, stream>>>(c_attn_w,   WqkvT,  Cc, C3);
    wtrans_kernel<<<dim3(Cc / 32, Cc / 32), 256, 0, stream>>>(c_proj_w,   WprojT, Cc, Cc);
    wtrans_kernel<<<dim3(Cc / 32, C4 / 32), 256, 0, stream>>>(c_fc_w,     WfcT,   Cc, C4);
    wtrans_kernel<<<dim3(C4 / 32, Cc / 32), 256, 0, stream>>>(mlp_proj_w, WmlpT,  C4, Cc);

    float t = 0.f;
    for (int step = 0; step < 20; ++step) {
        ln_kernel<<<BTc, 256, 0, stream>>>(z, attn_ln_w, attn_ln_b, xlnb, xt, 1, t, 1, 0, 1);
        gemm_bt<0><<<dim3(C3 / 128, BTc / 128), 256, 0, stream>>>(
            xlnb, Cc, WqkvT, Cc, qkvb, C3, Cc,
            c_attn_b, xt, c_attn_w + (size_t)Cc * C3);
        vtrans_kernel<<<dim3(Tc / 32, HDc / 32, NHc), 256, 0, stream>>>(qkvb, vT);
        qk_mfma<<<dim3(Tc / 128, Tc / 128, NHc), 256, 0, stream>>>(qkvb, Sbuf);
        sinkhead4<<<NHc * SB, 512, 0, stream>>>(
            Sbuf, E, avec, vT, vTs, part, ctr,
            (unsigned)(step * 6 * SB));
        piv_mfma<<<dim3(Tc / 128, NHc), 256, 0, stream>>>(E, vTs, avec, y);
        gemm_bt<3><<<dim3(Cc / 128, BTc / 128), 256, 0, stream>>>(
            y, Cc, WprojT, Cc, ao, Cc, Cc,
            c_proj_b, nullptr, nullptr);
        ln_kernel<<<BTc, 256, 0, stream>>>(ao, mlp_ln_w, mlp_ln_b, xlnb, xt, 1, t, 1, 0, 1);
        gemm_bt<1><<<dim3(C4 / 128, BTc / 128), 256, 0, stream>>>(
            xlnb, Cc, WfcT, Cc, h1, C4, Cc,
            c_fc_b, xt, c_fc_w + (size_t)Cc * C4);
        gemm_bt<4><<<dim3(Cc / 128, BTc / 128, 4), 256, 0, stream>>>(
            h1, C4, WmlpT, C4, parts, Cc, C4 / 4,
            nullptr, nullptr, nullptr);
        mlp_reduce<<<(BTc * Cc) / 1024, 256, 0, stream>>>(parts, mlp_proj_b, z);
        t += H_STEP;
    }

    ln_kernel<<<2, 256, 0, stream>>>(z, lnf_w, lnf_b, xf, nullptr, 0, 0.f, Tc, Tc - 1, 0);
    logits_kernel<<<Vc / 4, 256, 0, stream>>>(xf, wte, out);
}

// Round 9
// 4457.117 us; speedup vs baseline: 3.5259x; 1.0062x over previous
//
#include <hip/hip_runtime.h>
#include <hip/hip_bf16.h>
#include <math.h>

typedef unsigned short ushortT;
typedef unsigned int uintT;

// Problem constants
#define Bc   2
#define Tc   512
#define Cc   768
#define Hc   12
#define HDc  64
#define Vc   50304
#define BTc  (Bc*Tc)          // 1024
#define NHc  (Bc*Hc)          // 24
#define C3   (3*Cc)           // 2304
#define C4   (4*Cc)           // 3072
#define EPS_LN 1e-5f
#define H_STEP 0.05f
#define INVN (1.0f/512.0f)
#define SB   4                // blocks per head in sinkhorn

typedef float f32x4 __attribute__((ext_vector_type(4)));
typedef __bf16 bf16x8 __attribute__((ext_vector_type(8)));
typedef ushortT us8 __attribute__((ext_vector_type(8)));
typedef uintT u32x4 __attribute__((ext_vector_type(4)));

// ---------------- bf16 helpers --------------------------------------------
__device__ __forceinline__ ushortT f2bf(float f) {
    union { float f; unsigned u; } x; x.f = f;
    unsigned r = (x.u + 0x7fffu + ((x.u >> 16) & 1u)) >> 16;
    return (ushortT)r;
}
__device__ __forceinline__ float bf2f(ushortT b) {
    union { unsigned u; float f; } x; x.u = ((unsigned)b) << 16;
    return x.f;
}
__device__ __forceinline__ float bflo(uintT w) {
    union { unsigned u; float f; } x; x.u = w << 16;
    return x.f;
}
__device__ __forceinline__ float bfhi(uintT w) {
    union { unsigned u; float f; } x; x.u = w & 0xffff0000u;
    return x.f;
}

// async global->LDS, 16 bytes per lane
__device__ __forceinline__ void gll16(const ushortT* g, ushortT* l) {
    __builtin_amdgcn_global_load_lds(
        (const __attribute__((address_space(1))) unsigned int*)g,
        (__attribute__((address_space(3))) unsigned int*)l,
        16, 0, 0);
}

// ---------------- wave reductions -----------------------------------------
__device__ __forceinline__ float waveReduceMaxX(float v) {
    for (int o = 32; o; o >>= 1) v = fmaxf(v, __shfl_xor(v, o));
    return v;
}
__device__ __forceinline__ float waveReduceSumX(float v) {
    for (int o = 32; o; o >>= 1) v += __shfl_xor(v, o);
    return v;
}
__device__ __forceinline__ float blockReduceSum(float v) {
    __shared__ float sm[4];
    for (int o = 32; o; o >>= 1) v += __shfl_down(v, o);
    __syncthreads();
    if ((threadIdx.x & 63) == 0) sm[threadIdx.x >> 6] = v;
    __syncthreads();
    return sm[0] + sm[1] + sm[2] + sm[3];
}

// ---------------- embedding: z = wte[idx] + wpe[t] ------------------------
__global__ __launch_bounds__(256)
void embed_kernel(const int* __restrict__ idx, const float* __restrict__ wte,
                  const float* __restrict__ wpe, float* __restrict__ z)
{
    int i = blockIdx.x * 256 + threadIdx.x;
    if (i >= BTc * Cc) return;
    int r = i / Cc, c = i - r * Cc;
    int tok = idx[r];
    z[i] = wte[(size_t)tok * Cc + c] + wpe[(size_t)(r & (Tc - 1)) * Cc + c];
}

// ---------------- weight fp32 [K][N] -> bf16 [N][K] transpose -------------
__global__ __launch_bounds__(256)
void wtrans_kernel(const float* __restrict__ W, ushortT* __restrict__ out,
                   int K, int N)
{
    __shared__ float t[32][33];
    int k0 = blockIdx.x * 32, n0 = blockIdx.y * 32;
    int tx = threadIdx.x & 31, ty = threadIdx.x >> 5;
    for (int r = ty; r < 32; r += 8)
        t[r][tx] = W[(size_t)(k0 + r) * N + n0 + tx];
    __syncthreads();
    for (int r = ty; r < 32; r += 8)
        out[(size_t)(n0 + r) * K + k0 + tx] = f2bf(t[tx][r]);
}

// ---------------- LayerNorm over 768 dims (+optional time column) ---------
__global__ __launch_bounds__(256)
void ln_kernel(const float* __restrict__ X, const float* __restrict__ w,
               const float* __restrict__ bb, void* __restrict__ Y,
               float* __restrict__ yt, int hasT, float tval,
               int rowMul, int rowAdd, int obf16)
{
    int orow = blockIdx.x;
    int r = orow * rowMul + rowAdd;
    const float* x = X + (size_t)r * Cc;
    int tid = threadIdx.x;
    float xv[3];
#pragma unroll
    for (int q = 0; q < 3; ++q) xv[q] = x[tid + 256 * q];
    float s = xv[0] + xv[1] + xv[2];
    s = blockReduceSum(s);
    float cnt = hasT ? 769.f : 768.f;
    float mu = (s + (hasT ? tval : 0.f)) / cnt;
    float d0 = xv[0] - mu, d1 = xv[1] - mu, d2 = xv[2] - mu;
    float ss = d0 * d0 + d1 * d1 + d2 * d2;
    __syncthreads();
    ss = blockReduceSum(ss);
    float dt = tval - mu;
    float var = (ss + (hasT ? dt * dt : 0.f)) / cnt;
    float rs = rsqrtf(var + EPS_LN);
#pragma unroll
    for (int q = 0; q < 3; ++q) {
        int c = tid + 256 * q;
        float v = (xv[q] - mu) * rs * w[c] + bb[c];
        if (obf16) ((ushortT*)Y)[(size_t)orow * Cc + c] = f2bf(v);
        else       ((float*)Y)[(size_t)orow * Cc + c] = v;
    }
    if (hasT && tid == 0) yt[orow] = dt * rs * w[Cc] + bb[Cc];
}

// ---------------- MFMA GEMM: C = A[M,K](bf16) @ Bt[N,K](bf16)^T -----------
// EPI: 0 = bias(+rank1) -> bf16 ; 1 = gelu(bias+rank1) -> bf16 ;
//      3 = bias -> fp32 ; 4 = split-K partial fp32 (blockIdx.z chunks)
template <int EPI>
__global__ __launch_bounds__(256)
void gemm_bt(const ushortT* __restrict__ A, int lda,
             const ushortT* __restrict__ Bt, int ldb,
             void* __restrict__ Cm, int ldc, int K,
             const float* __restrict__ bias,
             const float* __restrict__ extraA,
             const float* __restrict__ extraB)
{
    __shared__ __align__(16) ushortT Als[128][32];
    __shared__ __align__(16) ushortT Bls[128][32];
    if (EPI == 4) {
        int koff = blockIdx.z * K;
        A += koff; Bt += koff;
    }
    int tid = threadIdx.x;
    int lane = tid & 63, wid = tid >> 6;
    int wm = wid >> 1, wn = wid & 1;
    int m0 = blockIdx.y * 128, n0 = blockIdx.x * 128;
    f32x4 acc[4][4];
    const f32x4 fz = {0.f, 0.f, 0.f, 0.f};
#pragma unroll
    for (int i = 0; i < 4; ++i)
#pragma unroll
        for (int j = 0; j < 4; ++j) acc[i][j] = fz;

    for (int k0 = 0; k0 < K; k0 += 32) {
#pragma unroll
        for (int is = 0; is < 2; ++is) {
            int ch = is * 256 + tid;
            int m = ch >> 2, kc = ch & 3;
            gll16(A + (size_t)(m0 + m) * lda + k0 + kc * 8, &Als[0][0] + ch * 8);
            gll16(Bt + (size_t)(n0 + m) * ldb + k0 + kc * 8, &Bls[0][0] + ch * 8);
        }
        __syncthreads();
        bf16x8 af[4], bfv[4];
#pragma unroll
        for (int i = 0; i < 4; ++i) {
            int row = wm * 64 + i * 16 + (lane & 15);
            af[i] = *(const bf16x8*)&Als[row][(lane >> 4) * 8];
            int col = wn * 64 + i * 16 + (lane & 15);
            bfv[i] = *(const bf16x8*)&Bls[col][(lane >> 4) * 8];
        }
#pragma unroll
        for (int i = 0; i < 4; ++i)
#pragma unroll
            for (int j = 0; j < 4; ++j)
                acc[i][j] = __builtin_amdgcn_mfma_f32_16x16x32_bf16(af[i], bfv[j], acc[i][j], 0, 0, 0);
        __syncthreads();
    }
#pragma unroll
    for (int i = 0; i < 4; ++i) {
#pragma unroll
        for (int j = 0; j < 4; ++j) {
#pragma unroll
            for (int r = 0; r < 4; ++r) {
                int row = m0 + wm * 64 + i * 16 + (lane >> 4) * 4 + r;
                int col = n0 + wn * 64 + j * 16 + (lane & 15);
                float v = acc[i][j][r];
                if (extraA) v += extraA[row] * extraB[col];
                if (bias) v += bias[col];
                size_t oi = (size_t)row * ldc + col;
                if (EPI == 0) {
                    ((ushortT*)Cm)[oi] = f2bf(v);
                } else if (EPI == 1) {
                    v = 0.5f * v * (1.f + erff(v * 0.70710678118654752440f));
                    ((ushortT*)Cm)[oi] = f2bf(v);
                } else if (EPI == 3) {
                    ((float*)Cm)[oi] = v;
                } else if (EPI == 4) {
                    ((float*)Cm)[(size_t)blockIdx.z * ((size_t)BTc * Cc) + oi] = v;
                }
            }
        }
    }
}

// ---------------- QK^T via MFMA: S = q@k^T / 8 (fp32 out), causal skip ----
__global__ __launch_bounds__(256)
void qk_mfma(const ushortT* __restrict__ qkv, float* __restrict__ S)
{
    int n = blockIdx.z; int b = n / Hc, h = n - b * Hc;
    int m0 = blockIdx.y * 128, n0 = blockIdx.x * 128;
    if (n0 > m0 + 127) return;
    const ushortT* Aq = qkv + (size_t)(b * Tc) * C3 + h * HDc;
    const ushortT* Bk = Aq + Cc;
    __shared__ __align__(16) ushortT Als[128][32];
    __shared__ __align__(16) ushortT Bls[128][32];
    int tid = threadIdx.x;
    int lane = tid & 63, wid = tid >> 6;
    int wm = wid >> 1, wn = wid & 1;
    f32x4 acc[4][4];
    const f32x4 fz = {0.f, 0.f, 0.f, 0.f};
#pragma unroll
    for (int i = 0; i < 4; ++i)
#pragma unroll
        for (int j = 0; j < 4; ++j) acc[i][j] = fz;

    for (int k0 = 0; k0 < HDc; k0 += 32) {
#pragma unroll
        for (int is = 0; is < 2; ++is) {
            int ch = is * 256 + tid;
            int m = ch >> 2, kc = ch & 3;
            gll16(Aq + (size_t)(m0 + m) * C3 + k0 + kc * 8, &Als[0][0] + ch * 8);
            gll16(Bk + (size_t)(n0 + m) * C3 + k0 + kc * 8, &Bls[0][0] + ch * 8);
        }
        __syncthreads();
        bf16x8 af[4], bfv[4];
#pragma unroll
        for (int i = 0; i < 4; ++i) {
            int row = wm * 64 + i * 16 + (lane & 15);
            af[i] = *(const bf16x8*)&Als[row][(lane >> 4) * 8];
            int col = wn * 64 + i * 16 + (lane & 15);
            bfv[i] = *(const bf16x8*)&Bls[col][(lane >> 4) * 8];
        }
#pragma unroll
        for (int i = 0; i < 4; ++i)
#pragma unroll
            for (int j = 0; j < 4; ++j)
                acc[i][j] = __builtin_amdgcn_mfma_f32_16x16x32_bf16(af[i], bfv[j], acc[i][j], 0, 0, 0);
        __syncthreads();
    }
    float* Sb = S + (size_t)n * Tc * Tc;
#pragma unroll
    for (int i = 0; i < 4; ++i)
#pragma unroll
        for (int j = 0; j < 4; ++j)
#pragma unroll
            for (int r = 0; r < 4; ++r) {
                int row = m0 + wm * 64 + i * 16 + (lane >> 4) * 4 + r;
                int col = n0 + wn * 64 + j * 16 + (lane & 15);
                Sb[(size_t)row * Tc + col] = acc[i][j][r] * 0.125f;
            }
}

// ===================== 4-blocks-per-head LDS-resident Sinkhorn ============
// grid = 96 blocks x 512 threads. Block (n, r) owns rows [r*128, r*128+128)
// of head n, resident in LDS (128KB). Row passes are LDS-local; col passes
// exchange 512 partial sums via global + a 4-block counter barrier (6/step).
// V-scale epilogue gathers V straight from qkvb (vtrans kernel eliminated).
__global__ __launch_bounds__(512)
void sinkhead4(const float* __restrict__ S, ushortT* __restrict__ E,
               float* __restrict__ avec, const ushortT* __restrict__ qkvb,
               ushortT* __restrict__ vTs, float* __restrict__ partials,
               unsigned* __restrict__ ctr, unsigned barBase)
{
    int gb = blockIdx.x;
    int n = gb >> 2, r = gb & 3;
    int hb = n / Hc, hh = n - hb * Hc;
    int row0 = r * 128;
    int tid = threadIdx.x;
    int l = tid & 63, w = tid >> 6;          // 8 waves
    __shared__ __align__(16) ushortT Els[128][Tc];   // 128 KB
    __shared__ float a_s[128];
    __shared__ float b_s[Tc];
    const float* Sb = S + (size_t)n * Tc * Tc;
    ushortT* Eg = E + (size_t)n * Tc * Tc;

    // ---- phase 0: causal softmax rows -> E (LDS + global), rowsum -> a1 ----
#pragma unroll 1
    for (int it = 0; it < 16; ++it) {
        int rr = it * 8 + w;                 // 0..127 local row
        int row = row0 + rr;                 // absolute row
        const float* sr = Sb + (size_t)row * Tc + l * 8;
        f32x4 v0 = *(const f32x4*)sr;
        f32x4 v1 = *(const f32x4*)(sr + 4);
        float x[8] = {v0[0], v0[1], v0[2], v0[3], v1[0], v1[1], v1[2], v1[3]};
        float mx = -INFINITY;
#pragma unroll
        for (int e = 0; e < 8; ++e)
            if (l * 8 + e <= row) mx = fmaxf(mx, x[e]);
        mx = waveReduceMaxX(mx);
        float ex[8], se = 0.f;
#pragma unroll
        for (int e = 0; e < 8; ++e) {
            ex[e] = (l * 8 + e <= row) ? __expf(x[e] - mx) : 0.f;
            se += ex[e];
        }
        se = waveReduceSumX(se);
        float inv = 1.f / se;
        us8 pack; float rs = 0.f;
#pragma unroll
        for (int e = 0; e < 8; ++e) {
            float Ee = __expf(-(ex[e] * inv));   // masked: exp(-0)=1 (matches ref)
            rs += Ee;
            pack[e] = f2bf(Ee);
        }
        rs = waveReduceSumX(rs);
        *(us8*)(&Els[rr][l * 8]) = pack;
        *(us8*)(Eg + (size_t)row * Tc + l * 8) = pack;
        if (l == 0) a_s[rr] = INVN / rs;
    }
    __syncthreads();

    float* mypart = partials + (size_t)(n * SB + r) * Tc;
    const float* hpart = partials + (size_t)n * SB * Tc;
    unsigned* myctr = ctr + n * 16;          // 64B-padded per-head counter

    // ---- 11 alternating passes: col(0),row(1),...,col(10) ----
#pragma unroll 1
    for (int p = 0; p < 11; ++p) {
        if ((p & 1) == 0) {
            // col partial over own 128 rows; thread = column
            int j = tid;
            float acc = 0.f;
#pragma unroll 1
            for (int i = 0; i < 128; i += 8) {
                float part = 0.f;
#pragma unroll
                for (int k = 0; k < 8; ++k)
                    part += bf2f(Els[i + k][j]) * a_s[i + k];
                acc += part;
            }
            __hip_atomic_store(&mypart[j], acc, __ATOMIC_RELAXED, __HIP_MEMORY_SCOPE_AGENT);
            __syncthreads();
            if (tid == 0) {
                __threadfence();
                atomicAdd(myctr, 1u);
                unsigned tgt = barBase + (unsigned)(p / 2 + 1) * SB;
                while (__hip_atomic_load(myctr, __ATOMIC_ACQUIRE, __HIP_MEMORY_SCOPE_AGENT) < tgt)
                    __builtin_amdgcn_s_sleep(2);
            }
            __syncthreads();
            float s0 = __hip_atomic_load(&hpart[j], __ATOMIC_RELAXED, __HIP_MEMORY_SCOPE_AGENT);
            float s1 = __hip_atomic_load(&hpart[Tc + j], __ATOMIC_RELAXED, __HIP_MEMORY_SCOPE_AGENT);
            float s2 = __hip_atomic_load(&hpart[2 * Tc + j], __ATOMIC_RELAXED, __HIP_MEMORY_SCOPE_AGENT);
            float s3 = __hip_atomic_load(&hpart[3 * Tc + j], __ATOMIC_RELAXED, __HIP_MEMORY_SCOPE_AGENT);
            b_s[j] = INVN / (s0 + s1 + s2 + s3);
            __syncthreads();
        } else {
            // row pass on own rows: wave per 16 rows, ILP 4
            f32x4 b0 = *(const f32x4*)&b_s[l * 8];
            f32x4 b1 = *(const f32x4*)&b_s[l * 8 + 4];
            float breg[8] = {b0[0], b0[1], b0[2], b0[3], b1[0], b1[1], b1[2], b1[3]};
#pragma unroll 1
            for (int k = 0; k < 16; k += 4) {
                int r0 = w * 16 + k;
                u32x4 q0 = *(const u32x4*)(&Els[r0 + 0][l * 8]);
                u32x4 q1 = *(const u32x4*)(&Els[r0 + 1][l * 8]);
                u32x4 q2 = *(const u32x4*)(&Els[r0 + 2][l * 8]);
                u32x4 q3 = *(const u32x4*)(&Els[r0 + 3][l * 8]);
                float s0 = 0.f, s1 = 0.f, s2 = 0.f, s3 = 0.f;
#pragma unroll
                for (int c = 0; c < 4; ++c) {
                    s0 += bflo(q0[c]) * breg[2 * c] + bfhi(q0[c]) * breg[2 * c + 1];
                    s1 += bflo(q1[c]) * breg[2 * c] + bfhi(q1[c]) * breg[2 * c + 1];
                    s2 += bflo(q2[c]) * breg[2 * c] + bfhi(q2[c]) * breg[2 * c + 1];
                    s3 += bflo(q3[c]) * breg[2 * c] + bfhi(q3[c]) * breg[2 * c + 1];
                }
                s0 = waveReduceSumX(s0);
                s1 = waveReduceSumX(s1);
                s2 = waveReduceSumX(s2);
                s3 = waveReduceSumX(s3);
                if (l == 0) {
                    a_s[r0 + 0] = INVN / s0;
                    a_s[r0 + 1] = INVN / s1;
                    a_s[r0 + 2] = INVN / s2;
                    a_s[r0 + 3] = INVN / s3;
                }
            }
            __syncthreads();
        }
    }

    // ---- vscale own 16 d-rows: vTs[d][t] = v[t][d] * n * b6[t]; write a6 ----
    {
        f32x4 b0 = *(const f32x4*)&b_s[l * 8];
        f32x4 b1 = *(const f32x4*)&b_s[l * 8 + 4];
        float breg[8] = {b0[0], b0[1], b0[2], b0[3], b1[0], b1[1], b1[2], b1[3]};
#pragma unroll
        for (int dd = 0; dd < 2; ++dd) {
            int d = r * 16 + w * 2 + dd;
            const ushortT* vs = qkvb + (size_t)(hb * Tc) * C3 + 2 * Cc + hh * HDc + d;
            us8 o;
#pragma unroll
            for (int e = 0; e < 8; ++e) {
                float vv = bf2f(vs[(size_t)(l * 8 + e) * C3]);
                o[e] = f2bf(vv * 512.f * breg[e]);
            }
            *(us8*)(vTs + ((size_t)n * HDc + d) * Tc + l * 8) = o;
        }
        if (tid < 128) avec[n * Tc + row0 + tid] = a_s[tid];
    }
}

// ---------------- y = a_i * (E @ vTs) via MFMA (bf16 out) -----------------
__global__ __launch_bounds__(256)
void piv_mfma(const ushortT* __restrict__ E, const ushortT* __restrict__ vTs,
              const float* __restrict__ avec, ushortT* __restrict__ y)
{
    int n = blockIdx.y; int b = n / Hc, h = n - b * Hc;
    int m0 = blockIdx.x * 128;
    const ushortT* Ap = E + (size_t)n * Tc * Tc;
    const ushortT* Bv = vTs + (size_t)n * HDc * Tc;
    __shared__ __align__(16) ushortT Als[128][32];
    __shared__ __align__(16) ushortT Bls[64][32];
    int tid = threadIdx.x;
    int lane = tid & 63, wid = tid >> 6;
    int wm = wid >> 1, wn = wid & 1;
    f32x4 acc[4][2];
    const f32x4 fz = {0.f, 0.f, 0.f, 0.f};
#pragma unroll
    for (int i = 0; i < 4; ++i)
#pragma unroll
        for (int j = 0; j < 2; ++j) acc[i][j] = fz;

    for (int k0 = 0; k0 < Tc; k0 += 32) {
#pragma unroll
        for (int is = 0; is < 2; ++is) {
            int ch = is * 256 + tid;
            int m = ch >> 2, kc = ch & 3;
            gll16(Ap + (size_t)(m0 + m) * Tc + k0 + kc * 8, &Als[0][0] + ch * 8);
        }
        {
            int ch = tid;
            int d = ch >> 2, kc = ch & 3;
            gll16(Bv + (size_t)d * Tc + k0 + kc * 8, &Bls[0][0] + ch * 8);
        }
        __syncthreads();
        bf16x8 af[4], bfv[2];
#pragma unroll
        for (int i = 0; i < 4; ++i) {
            int row = wm * 64 + i * 16 + (lane & 15);
            af[i] = *(const bf16x8*)&Als[row][(lane >> 4) * 8];
        }
#pragma unroll
        for (int j = 0; j < 2; ++j) {
            int col = wn * 32 + j * 16 + (lane & 15);
            bfv[j] = *(const bf16x8*)&Bls[col][(lane >> 4) * 8];
        }
#pragma unroll
        for (int i = 0; i < 4; ++i)
#pragma unroll
            for (int j = 0; j < 2; ++j)
                acc[i][j] = __builtin_amdgcn_mfma_f32_16x16x32_bf16(af[i], bfv[j], acc[i][j], 0, 0, 0);
        __syncthreads();
    }
#pragma unroll
    for (int i = 0; i < 4; ++i)
#pragma unroll
        for (int j = 0; j < 2; ++j)
#pragma unroll
            for (int r = 0; r < 4; ++r) {
                int rIn = m0 + wm * 64 + i * 16 + (lane >> 4) * 4 + r;
                float a_r = avec[n * Tc + rIn];
                int row = b * Tc + rIn;
                int col = h * HDc + wn * 32 + j * 16 + (lane & 15);
                y[(size_t)row * Cc + col] = f2bf(acc[i][j][r] * a_r);
            }
}

// ---------------- split-K reduce + Euler: z += h*(sum parts + bias) -------
__global__ __launch_bounds__(256)
void mlp_reduce(const float* __restrict__ parts, const float* __restrict__ bias,
                float* __restrict__ z)
{
    int i4 = (blockIdx.x * 256 + threadIdx.x) * 4;
    const size_t CS = (size_t)BTc * Cc;
    f32x4 a = *(const f32x4*)(parts + i4);
    f32x4 b = *(const f32x4*)(parts + CS + i4);
    f32x4 c = *(const f32x4*)(parts + 2 * CS + i4);
    f32x4 d = *(const f32x4*)(parts + 3 * CS + i4);
    int col = i4 - (i4 / Cc) * Cc;
    f32x4 bb = *(const f32x4*)(bias + col);
    f32x4 zz = *(const f32x4*)(z + i4);
#pragma unroll
    for (int e = 0; e < 4; ++e)
        zz[e] += H_STEP * (a[e] + b[e] + c[e] + d[e] + bb[e]);
    *(f32x4*)(z + i4) = zz;
}

// ---------------- logits: out[b,v] = xf[b,:] . wte[v,:] (fp32, f32x4) -----
// FIX vs R6/R7/R8: the xs loader must cover 384 f32x4 chunks with only 256
// threads — previous `if (tid < 384)` left xs[1024..1535] UNINITIALIZED,
// corrupting every batch-1 logit (the 3-round absmax~2.7 failure).
__global__ __launch_bounds__(256)
void logits_kernel(const float* __restrict__ xf, const float* __restrict__ wte,
                   float* __restrict__ out)
{
    __shared__ __align__(16) float xs[2 * Cc];
    int tid = threadIdx.x;
    for (int i = tid; i < 384; i += 256)
        ((f32x4*)xs)[i] = ((const f32x4*)xf)[i];
    __syncthreads();
    int w = tid >> 6, lane = tid & 63;
    int vrow = blockIdx.x * 4 + w;
    const f32x4* wr = (const f32x4*)(wte + (size_t)vrow * Cc);
    const f32x4* x0 = (const f32x4*)xs;
    const f32x4* x1 = (const f32x4*)(xs + Cc);
    float a0 = 0.f, a1 = 0.f;
#pragma unroll
    for (int it = 0; it < 3; ++it) {
        int k4 = it * 64 + lane;
        f32x4 wv = wr[k4];
        f32x4 p = x0[k4], q = x1[k4];
        a0 += wv[0] * p[0] + wv[1] * p[1] + wv[2] * p[2] + wv[3] * p[3];
        a1 += wv[0] * q[0] + wv[1] * q[1] + wv[2] * q[2] + wv[3] * q[3];
    }
    for (int o = 32; o; o >>= 1) {
        a0 += __shfl_down(a0, o);
        a1 += __shfl_down(a1, o);
    }
    if (lane == 0) {
        out[vrow] = a0;
        out[Vc + vrow] = a1;
    }
}

// ==========================================================================
extern "C" void kernel_launch(void* const* d_in, const int* in_sizes, int n_in,
                              void* d_out, int out_size, void* d_ws, size_t ws_size,
                              hipStream_t stream)
{
    const int*   idx        = (const int*)  d_in[0];
    const float* wte        = (const float*)d_in[1];
    const float* wpe        = (const float*)d_in[2];
    const float* attn_ln_w  = (const float*)d_in[3];
    const float* attn_ln_b  = (const float*)d_in[4];
    const float* c_attn_w   = (const float*)d_in[5];
    const float* c_attn_b   = (const float*)d_in[6];
    const float* c_proj_w   = (const float*)d_in[7];
    const float* c_proj_b   = (const float*)d_in[8];
    const float* mlp_ln_w   = (const float*)d_in[9];
    const float* mlp_ln_b   = (const float*)d_in[10];
    const float* c_fc_w     = (const float*)d_in[11];
    const float* c_fc_b     = (const float*)d_in[12];
    const float* mlp_proj_w = (const float*)d_in[13];
    const float* mlp_proj_b = (const float*)d_in[14];
    const float* lnf_w      = (const float*)d_in[15];
    const float* lnf_b      = (const float*)d_in[16];
    float* out = (float*)d_out;

    // -------- workspace carving (256B aligned) --------
    char* base = (char*)d_ws;
    size_t off = 0;
    auto alloc = [&](size_t bytes) -> void* {
        void* p = base + off;
        off = (off + bytes + 255) & ~(size_t)255;
        return p;
    };
    float*   z     = (float*)  alloc((size_t)BTc * Cc * 4);
    float*   ao    = (float*)  alloc((size_t)BTc * Cc * 4);
    float*   Sbuf  = (float*)  alloc((size_t)NHc * Tc * Tc * 4);  // 24MB; parts/h1 alias
    ushortT* E     = (ushortT*)alloc((size_t)NHc * Tc * Tc * 2);
    ushortT* qkvb  = (ushortT*)alloc((size_t)BTc * C3 * 2);
    ushortT* xlnb  = (ushortT*)alloc((size_t)BTc * Cc * 2);
    ushortT* y     = (ushortT*)alloc((size_t)BTc * Cc * 2);
    ushortT* vTs   = (ushortT*)alloc((size_t)NHc * HDc * Tc * 2);
    float*   xt    = (float*)  alloc(BTc * 4);
    float*   avec  = (float*)  alloc(NHc * Tc * 4);
    float*   part  = (float*)  alloc((size_t)NHc * SB * Tc * 4);
    unsigned* ctr  = (unsigned*)alloc(NHc * 16 * 4);
    float*   xf    = (float*)  alloc(2 * Cc * 4);
    ushortT* WqkvT = (ushortT*)alloc((size_t)C3 * Cc * 2);
    ushortT* WprojT= (ushortT*)alloc((size_t)Cc * Cc * 2);
    ushortT* WfcT  = (ushortT*)alloc((size_t)C4 * Cc * 2);
    ushortT* WmlpT = (ushortT*)alloc((size_t)Cc * C4 * 2);
    // aliases inside Sbuf (S dead once sinkhead4 is done each step)
    float*   parts = (float*)Sbuf;                          // 4 x 3MB fp32
    ushortT* h1    = (ushortT*)((char*)Sbuf + (13u << 20)); // 6MB bf16

    hipMemsetAsync(ctr, 0, NHc * 16 * 4, stream);
    embed_kernel<<<(BTc * Cc + 255) / 256, 256, 0, stream>>>(idx, wte, wpe, z);
    wtrans_kernel<<<dim3(Cc / 32, C3 / 32), 256, 0, stream>>>(c_attn_w,   WqkvT,  Cc, C3);
    wtrans_kernel<<<dim3(Cc / 32, Cc / 32), 256, 0, stream>>>(c_proj_w,   WprojT, Cc, Cc);
    wtrans_kernel<<<dim3(Cc / 32, C4 / 32), 256, 0, stream>>>(c_fc_w,     WfcT,   Cc, C4);
    wtrans_kernel<<<dim3(C4 / 32, Cc / 32), 256, 0, stream>>>(mlp_proj_w, WmlpT,  C4, Cc);

    float t = 0.f;
    for (int step = 0; step < 20; ++step) {
        ln_kernel<<<BTc, 256, 0, stream>>>(z, attn_ln_w, attn_ln_b, xlnb, xt, 1, t, 1, 0, 1);
        gemm_bt<0><<<dim3(C3 / 128, BTc / 128), 256, 0, stream>>>(
            xlnb, Cc, WqkvT, Cc, qkvb, C3, Cc,
            c_attn_b, xt, c_attn_w + (size_t)Cc * C3);
        qk_mfma<<<dim3(Tc / 128, Tc / 128, NHc), 256, 0, stream>>>(qkvb, Sbuf);
        sinkhead4<<<NHc * SB, 512, 0, stream>>>(
            Sbuf, E, avec, qkvb, vTs, part, ctr,
            (unsigned)(step * 6 * SB));
        piv_mfma<<<dim3(Tc / 128, NHc), 256, 0, stream>>>(E, vTs, avec, y);
        gemm_bt<3><<<dim3(Cc / 128, BTc / 128), 256, 0, stream>>>(
            y, Cc, WprojT, Cc, ao, Cc, Cc,
            c_proj_b, nullptr, nullptr);
        ln_kernel<<<BTc, 256, 0, stream>>>(ao, mlp_ln_w, mlp_ln_b, xlnb, xt, 1, t, 1, 0, 1);
        gemm_bt<1><<<dim3(C4 / 128, BTc / 128), 256, 0, stream>>>(
            xlnb, Cc, WfcT, Cc, h1, C4, Cc,
            c_fc_b, xt, c_fc_w + (size_t)Cc * C4);
        gemm_bt<4><<<dim3(Cc / 128, BTc / 128, 4), 256, 0, stream>>>(
            h1, C4, WmlpT, C4, parts, Cc, C4 / 4,
            nullptr, nullptr, nullptr);
        mlp_reduce<<<(BTc * Cc) / 1024, 256, 0, stream>>>(parts, mlp_proj_b, z);
        t += H_STEP;
    }

    ln_kernel<<<2, 256, 0, stream>>>(z, lnf_w, lnf_b, xf, nullptr, 0, 0.f, Tc, Tc - 1, 0);
    logits_kernel<<<Vc / 4, 256, 0, stream>>>(xf, wte, out);
}

// Round 10
// 4192.430 us; speedup vs baseline: 3.7485x; 1.0631x over previous
//
#include <hip/hip_runtime.h>
#include <hip/hip_bf16.h>
#include <math.h>

typedef unsigned short ushortT;
typedef unsigned int uintT;

// Problem constants
#define Bc   2
#define Tc   512
#define Cc   768
#define Hc   12
#define HDc  64
#define Vc   50304
#define BTc  (Bc*Tc)          // 1024
#define NHc  (Bc*Hc)          // 24
#define C3   (3*Cc)           // 2304
#define C4   (4*Cc)           // 3072
#define EPS_LN 1e-5f
#define H_STEP 0.05f
#define INVN (1.0f/512.0f)
#define SB   4                // blocks per head in sinkhorn

typedef float f32x4 __attribute__((ext_vector_type(4)));
typedef __bf16 bf16x8 __attribute__((ext_vector_type(8)));
typedef ushortT us8 __attribute__((ext_vector_type(8)));
typedef uintT u32x4 __attribute__((ext_vector_type(4)));

// ---------------- bf16 helpers --------------------------------------------
__device__ __forceinline__ ushortT f2bf(float f) {
    union { float f; unsigned u; } x; x.f = f;
    unsigned r = (x.u + 0x7fffu + ((x.u >> 16) & 1u)) >> 16;
    return (ushortT)r;
}
__device__ __forceinline__ float bf2f(ushortT b) {
    union { unsigned u; float f; } x; x.u = ((unsigned)b) << 16;
    return x.f;
}
__device__ __forceinline__ float bflo(uintT w) {
    union { unsigned u; float f; } x; x.u = w << 16;
    return x.f;
}
__device__ __forceinline__ float bfhi(uintT w) {
    union { unsigned u; float f; } x; x.u = w & 0xffff0000u;
    return x.f;
}

// async global->LDS, 16 bytes per lane (LDS dest lane-linear: base + lane*16)
__device__ __forceinline__ void gll16(const ushortT* g, ushortT* l) {
    __builtin_amdgcn_global_load_lds(
        (const __attribute__((address_space(1))) unsigned int*)g,
        (__attribute__((address_space(3))) unsigned int*)l,
        16, 0, 0);
}

// ---------------- wave reductions -----------------------------------------
__device__ __forceinline__ float waveReduceSumX(float v) {
    for (int o = 32; o; o >>= 1) v += __shfl_xor(v, o);
    return v;
}
__device__ __forceinline__ float blockReduceSum(float v) {
    __shared__ float sm[4];
    for (int o = 32; o; o >>= 1) v += __shfl_down(v, o);
    __syncthreads();
    if ((threadIdx.x & 63) == 0) sm[threadIdx.x >> 6] = v;
    __syncthreads();
    return sm[0] + sm[1] + sm[2] + sm[3];
}

// ---------------- weight fp32 [K][N] -> bf16 [N][K] transpose -------------
__global__ __launch_bounds__(256)
void wtrans_kernel(const float* __restrict__ W, ushortT* __restrict__ out,
                   int K, int N)
{
    __shared__ float t[32][33];
    int k0 = blockIdx.x * 32, n0 = blockIdx.y * 32;
    int tx = threadIdx.x & 31, ty = threadIdx.x >> 5;
    for (int r = ty; r < 32; r += 8)
        t[r][tx] = W[(size_t)(k0 + r) * N + n0 + tx];
    __syncthreads();
    for (int r = ty; r < 32; r += 8)
        out[(size_t)(n0 + r) * K + k0 + tx] = f2bf(t[tx][r]);
}

// ---------------- embed + attn-LN (t=0): z, xlnb, xt ----------------------
__global__ __launch_bounds__(256)
void embed_ln(const int* __restrict__ idx, const float* __restrict__ wte,
              const float* __restrict__ wpe, float* __restrict__ z,
              const float* __restrict__ lnw, const float* __restrict__ lnb,
              ushortT* __restrict__ xlnb, float* __restrict__ xt)
{
    int row = blockIdx.x, tid = threadIdx.x;
    int tok = idx[row];
    float v[3];
#pragma unroll
    for (int q = 0; q < 3; ++q) {
        int c = tid + 256 * q;
        float val = wte[(size_t)tok * Cc + c] + wpe[(size_t)(row & (Tc - 1)) * Cc + c];
        z[(size_t)row * Cc + c] = val;
        v[q] = val;
    }
    float s = blockReduceSum(v[0] + v[1] + v[2]);
    float mu = s / 769.f;                       // + t(=0)
    float d0 = v[0] - mu, d1 = v[1] - mu, d2 = v[2] - mu;
    float ss = blockReduceSum(d0 * d0 + d1 * d1 + d2 * d2);
    float dt = 0.f - mu;
    float var = (ss + dt * dt) / 769.f;
    float rs = rsqrtf(var + EPS_LN);
#pragma unroll
    for (int q = 0; q < 3; ++q) {
        int c = tid + 256 * q;
        xlnb[(size_t)row * Cc + c] = f2bf((v[q] - mu) * rs * lnw[c] + lnb[c]);
    }
    if (tid == 0) xt[row] = dt * rs * lnw[Cc] + lnb[Cc];
}

// ---------------- LayerNorm over 768 dims (+optional time column) ---------
__global__ __launch_bounds__(256)
void ln_kernel(const float* __restrict__ X, const float* __restrict__ w,
               const float* __restrict__ bb, void* __restrict__ Y,
               float* __restrict__ yt, int hasT, float tval,
               int rowMul, int rowAdd, int obf16)
{
    int orow = blockIdx.x;
    int r = orow * rowMul + rowAdd;
    const float* x = X + (size_t)r * Cc;
    int tid = threadIdx.x;
    float xv[3];
#pragma unroll
    for (int q = 0; q < 3; ++q) xv[q] = x[tid + 256 * q];
    float s = blockReduceSum(xv[0] + xv[1] + xv[2]);
    float cnt = hasT ? 769.f : 768.f;
    float mu = (s + (hasT ? tval : 0.f)) / cnt;
    float d0 = xv[0] - mu, d1 = xv[1] - mu, d2 = xv[2] - mu;
    float ss = blockReduceSum(d0 * d0 + d1 * d1 + d2 * d2);
    float dt = tval - mu;
    float var = (ss + (hasT ? dt * dt : 0.f)) / cnt;
    float rs = rsqrtf(var + EPS_LN);
#pragma unroll
    for (int q = 0; q < 3; ++q) {
        int c = tid + 256 * q;
        float v = (xv[q] - mu) * rs * w[c] + bb[c];
        if (obf16) ((ushortT*)Y)[(size_t)orow * Cc + c] = f2bf(v);
        else       ((float*)Y)[(size_t)orow * Cc + c] = v;
    }
    if (hasT && tid == 0) yt[orow] = dt * rs * w[Cc] + bb[Cc];
}

// ---------------- MFMA GEMM: C = A[M,K](bf16) @ Bt[N,K](bf16)^T -----------
// EPI: 0 = bias(+rank1) -> bf16 ; 1 = gelu(bias+rank1) -> bf16 ;
//      3 = bias -> fp32 ; 4 = split-K partial fp32 (blockIdx.z chunks)
template <int EPI>
__global__ __launch_bounds__(256)
void gemm_bt(const ushortT* __restrict__ A, int lda,
             const ushortT* __restrict__ Bt, int ldb,
             void* __restrict__ Cm, int ldc, int K,
             const float* __restrict__ bias,
             const float* __restrict__ extraA,
             const float* __restrict__ extraB)
{
    __shared__ __align__(16) ushortT Als[128][32];
    __shared__ __align__(16) ushortT Bls[128][32];
    if (EPI == 4) {
        int koff = blockIdx.z * K;
        A += koff; Bt += koff;
    }
    int tid = threadIdx.x;
    int lane = tid & 63, wid = tid >> 6;
    int wm = wid >> 1, wn = wid & 1;
    int m0 = blockIdx.y * 128, n0 = blockIdx.x * 128;
    f32x4 acc[4][4];
    const f32x4 fz = {0.f, 0.f, 0.f, 0.f};
#pragma unroll
    for (int i = 0; i < 4; ++i)
#pragma unroll
        for (int j = 0; j < 4; ++j) acc[i][j] = fz;

    for (int k0 = 0; k0 < K; k0 += 32) {
#pragma unroll
        for (int is = 0; is < 2; ++is) {
            int ch = is * 256 + tid;
            int m = ch >> 2, kc = ch & 3;
            gll16(A + (size_t)(m0 + m) * lda + k0 + kc * 8, &Als[0][0] + ch * 8);
            gll16(Bt + (size_t)(n0 + m) * ldb + k0 + kc * 8, &Bls[0][0] + ch * 8);
        }
        __syncthreads();
        bf16x8 af[4], bfv[4];
#pragma unroll
        for (int i = 0; i < 4; ++i) {
            int row = wm * 64 + i * 16 + (lane & 15);
            af[i] = *(const bf16x8*)&Als[row][(lane >> 4) * 8];
            int col = wn * 64 + i * 16 + (lane & 15);
            bfv[i] = *(const bf16x8*)&Bls[col][(lane >> 4) * 8];
        }
#pragma unroll
        for (int i = 0; i < 4; ++i)
#pragma unroll
            for (int j = 0; j < 4; ++j)
                acc[i][j] = __builtin_amdgcn_mfma_f32_16x16x32_bf16(af[i], bfv[j], acc[i][j], 0, 0, 0);
        __syncthreads();
    }
#pragma unroll
    for (int i = 0; i < 4; ++i) {
#pragma unroll
        for (int j = 0; j < 4; ++j) {
#pragma unroll
            for (int r = 0; r < 4; ++r) {
                int row = m0 + wm * 64 + i * 16 + (lane >> 4) * 4 + r;
                int col = n0 + wn * 64 + j * 16 + (lane & 15);
                float v = acc[i][j][r];
                if (extraA) v += extraA[row] * extraB[col];
                if (bias) v += bias[col];
                size_t oi = (size_t)row * ldc + col;
                if (EPI == 0) {
                    ((ushortT*)Cm)[oi] = f2bf(v);
                } else if (EPI == 1) {
                    v = 0.5f * v * (1.f + erff(v * 0.70710678118654752440f));
                    ((ushortT*)Cm)[oi] = f2bf(v);
                } else if (EPI == 3) {
                    ((float*)Cm)[oi] = v;
                } else if (EPI == 4) {
                    ((float*)Cm)[(size_t)blockIdx.z * ((size_t)BTc * Cc) + oi] = v;
                }
            }
        }
    }
}

// ===================== fused QK + softmax + Sinkhorn + vscale =============
// grid = 96 blocks x 512 threads. Block (n, r) owns rows [r*128, r*128+128).
// Phase QK: q-frags in regs, K staged in XOR-swizzled 16KB LDS, MFMA into
// 32 col-tile acc (only (r+1)*8 tiles computed; rest fully masked -> E=1).
// Softmax in-register (16-lane shfl groups) -> E bf16 in LDS + global.
// Then 11 alternating passes (LDS-local rows; col passes sync 4 blocks via
// per-head counter barrier), finally vTs = v * n*b gathered from qkvb.
__global__ __launch_bounds__(512)
void sinkfused(const ushortT* __restrict__ qkvb, ushortT* __restrict__ E,
               float* __restrict__ avec, ushortT* __restrict__ vTs,
               float* __restrict__ partials, unsigned* __restrict__ ctr,
               unsigned barBase)
{
    int gb = blockIdx.x;
    int n = gb >> 2, r = gb & 3;
    int row0 = r * 128;
    int b = n / Hc, h = n - b * Hc;
    int tid = threadIdx.x;
    int l = tid & 63, w = tid >> 6;              // 8 waves
    __shared__ __align__(16) ushortT Els[128][Tc];   // 128 KB
    __shared__ __align__(16) ushortT Kls[128][64];   // 16 KB (XOR-swizzled)
    __shared__ float a_s[128];
    __shared__ float b_s[Tc];
    ushortT* Eg = E + (size_t)n * Tc * Tc;
    const f32x4 fz = {0.f, 0.f, 0.f, 0.f};

    // ---- phase QK: scores for own 128 rows x (r+1)*128 cols ----
    int qrow = b * Tc + row0 + w * 16 + (l & 15);
    const ushortT* qp = qkvb + (size_t)qrow * C3 + h * HDc + (l >> 4) * 8;
    bf16x8 aq0 = *(const bf16x8*)(qp);
    bf16x8 aq1 = *(const bf16x8*)(qp + 32);

    int kcmax = r + 1;
    f32x4 acc[32];
#pragma unroll
    for (int j = 0; j < 32; ++j) acc[j] = fz;

#pragma unroll
    for (int kc = 0; kc < 4; ++kc) {
        if (kc < kcmax) {
            // stage K rows [kc*128, +128): content (row,c16) at slot row*8 + (c16^(row&7))
            {
                int ch = tid;
                int row = ch >> 3, c16 = (ch & 7) ^ (row & 7);
                gll16(qkvb + (size_t)(b * Tc + kc * 128 + row) * C3 + Cc + h * HDc + c16 * 8,
                      &Kls[0][0] + ch * 8);
                ch = tid + 512;
                row = ch >> 3; c16 = (ch & 7) ^ (row & 7);
                gll16(qkvb + (size_t)(b * Tc + kc * 128 + row) * C3 + Cc + h * HDc + c16 * 8,
                      &Kls[0][0] + ch * 8);
            }
            __syncthreads();
#pragma unroll
            for (int jj = 0; jj < 8; ++jj) {
                int krow = jj * 16 + (l & 15);
                int c16a = (l >> 4);
                int c16b = 4 + (l >> 4);
                bf16x8 bk0 = *(const bf16x8*)(&Kls[0][0] + ((size_t)krow * 8 + (c16a ^ (krow & 7))) * 8);
                bf16x8 bk1 = *(const bf16x8*)(&Kls[0][0] + ((size_t)krow * 8 + (c16b ^ (krow & 7))) * 8);
                acc[kc * 8 + jj] = __builtin_amdgcn_mfma_f32_16x16x32_bf16(aq0, bk0, acc[kc * 8 + jj], 0, 0, 0);
                acc[kc * 8 + jj] = __builtin_amdgcn_mfma_f32_16x16x32_bf16(aq1, bk1, acc[kc * 8 + jj], 0, 0, 0);
            }
            __syncthreads();
        }
    }

    // ---- in-register causal softmax -> E, rowsum -> a1 ----
    int nvalid = kcmax * 8;
    int colbase = (l & 15);
    int rowa[4];
#pragma unroll
    for (int e = 0; e < 4; ++e) rowa[e] = row0 + w * 16 + (l >> 4) * 4 + e;

    float mx[4] = {-INFINITY, -INFINITY, -INFINITY, -INFINITY};
#pragma unroll
    for (int j = 0; j < 32; ++j) {
        if (j < nvalid) {
            int col = j * 16 + colbase;
#pragma unroll
            for (int e = 0; e < 4; ++e)
                if (col <= rowa[e]) mx[e] = fmaxf(mx[e], acc[j][e] * 0.125f);
        }
    }
#pragma unroll
    for (int e = 0; e < 4; ++e)
        for (int o = 1; o < 16; o <<= 1) mx[e] = fmaxf(mx[e], __shfl_xor(mx[e], o));

    float se[4] = {0.f, 0.f, 0.f, 0.f};
#pragma unroll
    for (int j = 0; j < 32; ++j) {
        if (j < nvalid) {
            int col = j * 16 + colbase;
#pragma unroll
            for (int e = 0; e < 4; ++e) {
                float exv = (col <= rowa[e]) ? __expf(acc[j][e] * 0.125f - mx[e]) : 0.f;
                acc[j][e] = exv;
                se[e] += exv;
            }
        }
    }
#pragma unroll
    for (int e = 0; e < 4; ++e)
        for (int o = 1; o < 16; o <<= 1) se[e] += __shfl_xor(se[e], o);
    float inv[4];
#pragma unroll
    for (int e = 0; e < 4; ++e) inv[e] = 1.f / se[e];

    float rsum[4] = {0.f, 0.f, 0.f, 0.f};
#pragma unroll
    for (int j = 0; j < 32; ++j) {
        if (j < nvalid) {
            int col = j * 16 + colbase;
#pragma unroll
            for (int e = 0; e < 4; ++e) {
                float Ee = __expf(-(acc[j][e] * inv[e]));   // masked: exp(-0)=1
                rsum[e] += Ee;
                Els[w * 16 + (l >> 4) * 4 + e][col] = f2bf(Ee);
            }
        }
    }
#pragma unroll
    for (int e = 0; e < 4; ++e) {
        for (int o = 1; o < 16; o <<= 1) rsum[e] += __shfl_xor(rsum[e], o);
        if ((l & 15) == 0)
            a_s[w * 16 + (l >> 4) * 4 + e] = INVN / (rsum[e] + (float)(Tc - nvalid * 16));
    }
    // fill fully-masked tail with ones (per wave: own 16 rows)
    {
        int tailc = 64 - kcmax * 16;              // us8 chunks per row
        if (tailc > 0) {
            us8 ones8;
#pragma unroll
            for (int e = 0; e < 8; ++e) ones8[e] = 0x3F80;
            for (int idx2 = l; idx2 < 16 * tailc; idx2 += 64) {
                int rr = idx2 / tailc, cc = idx2 - rr * tailc;
                *(us8*)&Els[w * 16 + rr][(kcmax * 16 + cc) * 8] = ones8;
            }
        }
    }
    __syncthreads();

    // ---- coalesced copy Els -> Eg (for piv_mfma) ----
#pragma unroll
    for (int ii = 0; ii < 16; ++ii) {
        int flat = ii * 512 + tid;
        int rr = flat >> 6, c = flat & 63;
        *(us8*)(Eg + (((size_t)(row0 + rr)) << 9) + c * 8) = *(const us8*)&Els[rr][c * 8];
    }

    float* mypart = partials + (size_t)(n * SB + r) * Tc;
    const float* hpart = partials + (size_t)n * SB * Tc;
    unsigned* myctr = ctr + n * 16;              // 64B-padded per-head counter

    // ---- 11 alternating passes: col(0),row(1),...,col(10) ----
#pragma unroll 1
    for (int p = 0; p < 11; ++p) {
        if ((p & 1) == 0) {
            // col partial over own 128 rows; thread = column
            int j = tid;
            float accs = 0.f;
#pragma unroll 1
            for (int i = 0; i < 128; i += 8) {
                float part = 0.f;
#pragma unroll
                for (int k = 0; k < 8; ++k)
                    part += bf2f(Els[i + k][j]) * a_s[i + k];
                accs += part;
            }
            __hip_atomic_store(&mypart[j], accs, __ATOMIC_RELAXED, __HIP_MEMORY_SCOPE_AGENT);
            __syncthreads();
            if (tid == 0) {
                __threadfence();
                atomicAdd(myctr, 1u);
                unsigned tgt = barBase + (unsigned)(p / 2 + 1) * SB;
                while (__hip_atomic_load(myctr, __ATOMIC_ACQUIRE, __HIP_MEMORY_SCOPE_AGENT) < tgt)
                    __builtin_amdgcn_s_sleep(2);
            }
            __syncthreads();
            float s0 = __hip_atomic_load(&hpart[j], __ATOMIC_RELAXED, __HIP_MEMORY_SCOPE_AGENT);
            float s1 = __hip_atomic_load(&hpart[Tc + j], __ATOMIC_RELAXED, __HIP_MEMORY_SCOPE_AGENT);
            float s2 = __hip_atomic_load(&hpart[2 * Tc + j], __ATOMIC_RELAXED, __HIP_MEMORY_SCOPE_AGENT);
            float s3 = __hip_atomic_load(&hpart[3 * Tc + j], __ATOMIC_RELAXED, __HIP_MEMORY_SCOPE_AGENT);
            b_s[j] = INVN / (s0 + s1 + s2 + s3);
            __syncthreads();
        } else {
            // row pass on own rows: wave per 16 rows, ILP 4
            f32x4 b0 = *(const f32x4*)&b_s[l * 8];
            f32x4 b1 = *(const f32x4*)&b_s[l * 8 + 4];
            float breg[8] = {b0[0], b0[1], b0[2], b0[3], b1[0], b1[1], b1[2], b1[3]};
#pragma unroll 1
            for (int k = 0; k < 16; k += 4) {
                int r0 = w * 16 + k;
                u32x4 q0 = *(const u32x4*)(&Els[r0 + 0][l * 8]);
                u32x4 q1 = *(const u32x4*)(&Els[r0 + 1][l * 8]);
                u32x4 q2 = *(const u32x4*)(&Els[r0 + 2][l * 8]);
                u32x4 q3 = *(const u32x4*)(&Els[r0 + 3][l * 8]);
                float s0 = 0.f, s1 = 0.f, s2 = 0.f, s3 = 0.f;
#pragma unroll
                for (int c = 0; c < 4; ++c) {
                    s0 += bflo(q0[c]) * breg[2 * c] + bfhi(q0[c]) * breg[2 * c + 1];
                    s1 += bflo(q1[c]) * breg[2 * c] + bfhi(q1[c]) * breg[2 * c + 1];
                    s2 += bflo(q2[c]) * breg[2 * c] + bfhi(q2[c]) * breg[2 * c + 1];
                    s3 += bflo(q3[c]) * breg[2 * c] + bfhi(q3[c]) * breg[2 * c + 1];
                }
                s0 = waveReduceSumX(s0);
                s1 = waveReduceSumX(s1);
                s2 = waveReduceSumX(s2);
                s3 = waveReduceSumX(s3);
                if (l == 0) {
                    a_s[r0 + 0] = INVN / s0;
                    a_s[r0 + 1] = INVN / s1;
                    a_s[r0 + 2] = INVN / s2;
                    a_s[r0 + 3] = INVN / s3;
                }
            }
            __syncthreads();
        }
    }

    // ---- vscale own 16 d-rows: vTs[d][t] = v[t][d] * n * b6[t]; write a6 ----
    {
        f32x4 b0 = *(const f32x4*)&b_s[l * 8];
        f32x4 b1 = *(const f32x4*)&b_s[l * 8 + 4];
        float breg[8] = {b0[0], b0[1], b0[2], b0[3], b1[0], b1[1], b1[2], b1[3]};
#pragma unroll
        for (int dd = 0; dd < 2; ++dd) {
            int d = r * 16 + w * 2 + dd;
            const ushortT* vs = qkvb + (size_t)(b * Tc) * C3 + 2 * Cc + h * HDc + d;
            us8 o;
#pragma unroll
            for (int e = 0; e < 8; ++e) {
                float vv = bf2f(vs[(size_t)(l * 8 + e) * C3]);
                o[e] = f2bf(vv * 512.f * breg[e]);
            }
            *(us8*)(vTs + ((size_t)n * HDc + d) * Tc + l * 8) = o;
        }
        if (tid < 128) avec[n * Tc + row0 + tid] = a_s[tid];
    }
}

// ---------------- y = a_i * (E @ vTs) via MFMA (bf16 out) -----------------
__global__ __launch_bounds__(256)
void piv_mfma(const ushortT* __restrict__ E, const ushortT* __restrict__ vTs,
              const float* __restrict__ avec, ushortT* __restrict__ y)
{
    int n = blockIdx.y; int b = n / Hc, h = n - b * Hc;
    int m0 = blockIdx.x * 128;
    const ushortT* Ap = E + (size_t)n * Tc * Tc;
    const ushortT* Bv = vTs + (size_t)n * HDc * Tc;
    __shared__ __align__(16) ushortT Als[128][32];
    __shared__ __align__(16) ushortT Bls[64][32];
    int tid = threadIdx.x;
    int lane = tid & 63, wid = tid >> 6;
    int wm = wid >> 1, wn = wid & 1;
    f32x4 acc[4][2];
    const f32x4 fz = {0.f, 0.f, 0.f, 0.f};
#pragma unroll
    for (int i = 0; i < 4; ++i)
#pragma unroll
        for (int j = 0; j < 2; ++j) acc[i][j] = fz;

    for (int k0 = 0; k0 < Tc; k0 += 32) {
#pragma unroll
        for (int is = 0; is < 2; ++is) {
            int ch = is * 256 + tid;
            int m = ch >> 2, kc = ch & 3;
            gll16(Ap + (size_t)(m0 + m) * Tc + k0 + kc * 8, &Als[0][0] + ch * 8);
        }
        {
            int ch = tid;
            int d = ch >> 2, kc = ch & 3;
            gll16(Bv + (size_t)d * Tc + k0 + kc * 8, &Bls[0][0] + ch * 8);
        }
        __syncthreads();
        bf16x8 af[4], bfv[2];
#pragma unroll
        for (int i = 0; i < 4; ++i) {
            int row = wm * 64 + i * 16 + (lane & 15);
            af[i] = *(const bf16x8*)&Als[row][(lane >> 4) * 8];
        }
#pragma unroll
        for (int j = 0; j < 2; ++j) {
            int col = wn * 32 + j * 16 + (lane & 15);
            bfv[j] = *(const bf16x8*)&Bls[col][(lane >> 4) * 8];
        }
#pragma unroll
        for (int i = 0; i < 4; ++i)
#pragma unroll
            for (int j = 0; j < 2; ++j)
                acc[i][j] = __builtin_amdgcn_mfma_f32_16x16x32_bf16(af[i], bfv[j], acc[i][j], 0, 0, 0);
        __syncthreads();
    }
#pragma unroll
    for (int i = 0; i < 4; ++i)
#pragma unroll
        for (int j = 0; j < 2; ++j)
#pragma unroll
            for (int r = 0; r < 4; ++r) {
                int rIn = m0 + wm * 64 + i * 16 + (lane >> 4) * 4 + r;
                float a_r = avec[n * Tc + rIn];
                int row = b * Tc + rIn;
                int col = h * HDc + wn * 32 + j * 16 + (lane & 15);
                y[(size_t)row * Cc + col] = f2bf(acc[i][j][r] * a_r);
            }
}

// ------- split-K reduce + Euler + next step's attn-LN (fused) -------------
__global__ __launch_bounds__(256)
void reduce_ln(const float* __restrict__ parts, const float* __restrict__ bias,
               float* __restrict__ z, const float* __restrict__ lnw,
               const float* __restrict__ lnb, ushortT* __restrict__ xlnb,
               float* __restrict__ xt, float tval)
{
    int row = blockIdx.x, tid = threadIdx.x;
    const size_t CS = (size_t)BTc * Cc;
    float v[3];
#pragma unroll
    for (int q = 0; q < 3; ++q) {
        int c = tid + 256 * q;
        size_t idx = (size_t)row * Cc + c;
        float s = parts[idx] + parts[CS + idx] + parts[2 * CS + idx]
                + parts[3 * CS + idx] + bias[c];
        v[q] = z[idx] + H_STEP * s;
        z[idx] = v[q];
    }
    float s = blockReduceSum(v[0] + v[1] + v[2]);
    float mu = (s + tval) / 769.f;
    float d0 = v[0] - mu, d1 = v[1] - mu, d2 = v[2] - mu;
    float ss = blockReduceSum(d0 * d0 + d1 * d1 + d2 * d2);
    float dt = tval - mu;
    float var = (ss + dt * dt) / 769.f;
    float rs = rsqrtf(var + EPS_LN);
#pragma unroll
    for (int q = 0; q < 3; ++q) {
        int c = tid + 256 * q;
        xlnb[(size_t)row * Cc + c] = f2bf((v[q] - mu) * rs * lnw[c] + lnb[c]);
    }
    if (tid == 0) xt[row] = dt * rs * lnw[Cc] + lnb[Cc];
}

// ---------------- logits: out[b,v] = xf[b,:] . wte[v,:] (fp32, f32x4) -----
// Loader covers 384 f32x4 chunks with 256 threads (grid-stride) — the R6/7/8
// `if (tid < 384)` bug left xs[1024..1535] uninitialized.
__global__ __launch_bounds__(256)
void logits_kernel(const float* __restrict__ xf, const float* __restrict__ wte,
                   float* __restrict__ out)
{
    __shared__ __align__(16) float xs[2 * Cc];
    int tid = threadIdx.x;
    for (int i = tid; i < 384; i += 256)
        ((f32x4*)xs)[i] = ((const f32x4*)xf)[i];
    __syncthreads();
    int w = tid >> 6, lane = tid & 63;
    int vrow = blockIdx.x * 4 + w;
    const f32x4* wr = (const f32x4*)(wte + (size_t)vrow * Cc);
    const f32x4* x0 = (const f32x4*)xs;
    const f32x4* x1 = (const f32x4*)(xs + Cc);
    float a0 = 0.f, a1 = 0.f;
#pragma unroll
    for (int it = 0; it < 3; ++it) {
        int k4 = it * 64 + lane;
        f32x4 wv = wr[k4];
        f32x4 p = x0[k4], q = x1[k4];
        a0 += wv[0] * p[0] + wv[1] * p[1] + wv[2] * p[2] + wv[3] * p[3];
        a1 += wv[0] * q[0] + wv[1] * q[1] + wv[2] * q[2] + wv[3] * q[3];
    }
    for (int o = 32; o; o >>= 1) {
        a0 += __shfl_down(a0, o);
        a1 += __shfl_down(a1, o);
    }
    if (lane == 0) {
        out[vrow] = a0;
        out[Vc + vrow] = a1;
    }
}

// ==========================================================================
extern "C" void kernel_launch(void* const* d_in, const int* in_sizes, int n_in,
                              void* d_out, int out_size, void* d_ws, size_t ws_size,
                              hipStream_t stream)
{
    const int*   idx        = (const int*)  d_in[0];
    const float* wte        = (const float*)d_in[1];
    const float* wpe        = (const float*)d_in[2];
    const float* attn_ln_w  = (const float*)d_in[3];
    const float* attn_ln_b  = (const float*)d_in[4];
    const float* c_attn_w   = (const float*)d_in[5];
    const float* c_attn_b   = (const float*)d_in[6];
    const float* c_proj_w   = (const float*)d_in[7];
    const float* c_proj_b   = (const float*)d_in[8];
    const float* mlp_ln_w   = (const float*)d_in[9];
    const float* mlp_ln_b   = (const float*)d_in[10];
    const float* c_fc_w     = (const float*)d_in[11];
    const float* c_fc_b     = (const float*)d_in[12];
    const float* mlp_proj_w = (const float*)d_in[13];
    const float* mlp_proj_b = (const float*)d_in[14];
    const float* lnf_w      = (const float*)d_in[15];
    const float* lnf_b      = (const float*)d_in[16];
    float* out = (float*)d_out;

    // -------- workspace carving (256B aligned) --------
    char* base = (char*)d_ws;
    size_t off = 0;
    auto alloc = [&](size_t bytes) -> void* {
        void* p = base + off;
        off = (off + bytes + 255) & ~(size_t)255;
        return p;
    };
    float*   z     = (float*)  alloc((size_t)BTc * Cc * 4);
    float*   parts = (float*)  alloc((size_t)4 * BTc * Cc * 4);   // split-K partials
    ushortT* E     = (ushortT*)alloc((size_t)NHc * Tc * Tc * 2);
    ushortT* qkvb  = (ushortT*)alloc((size_t)BTc * C3 * 2);
    ushortT* xlnb  = (ushortT*)alloc((size_t)BTc * Cc * 2);
    ushortT* y     = (ushortT*)alloc((size_t)BTc * Cc * 2);
    ushortT* h1    = (ushortT*)alloc((size_t)BTc * C4 * 2);
    ushortT* vTs   = (ushortT*)alloc((size_t)NHc * HDc * Tc * 2);
    float*   ao    = (float*)  alloc((size_t)BTc * Cc * 4);
    float*   xt    = (float*)  alloc(BTc * 4);
    float*   avec  = (float*)  alloc(NHc * Tc * 4);
    float*   partv = (float*)  alloc((size_t)NHc * SB * Tc * 4);
    unsigned* ctr  = (unsigned*)alloc(NHc * 16 * 4);
    float*   xf    = (float*)  alloc(2 * Cc * 4);
    ushortT* WqkvT = (ushortT*)alloc((size_t)C3 * Cc * 2);
    ushortT* WprojT= (ushortT*)alloc((size_t)Cc * Cc * 2);
    ushortT* WfcT  = (ushortT*)alloc((size_t)C4 * Cc * 2);
    ushortT* WmlpT = (ushortT*)alloc((size_t)Cc * C4 * 2);

    hipMemsetAsync(ctr, 0, NHc * 16 * 4, stream);
    embed_ln<<<BTc, 256, 0, stream>>>(idx, wte, wpe, z, attn_ln_w, attn_ln_b, xlnb, xt);
    wtrans_kernel<<<dim3(Cc / 32, C3 / 32), 256, 0, stream>>>(c_attn_w,   WqkvT,  Cc, C3);
    wtrans_kernel<<<dim3(Cc / 32, Cc / 32), 256, 0, stream>>>(c_proj_w,   WprojT, Cc, Cc);
    wtrans_kernel<<<dim3(Cc / 32, C4 / 32), 256, 0, stream>>>(c_fc_w,     WfcT,   Cc, C4);
    wtrans_kernel<<<dim3(C4 / 32, Cc / 32), 256, 0, stream>>>(mlp_proj_w, WmlpT,  C4, Cc);

    float t = 0.f;
    for (int step = 0; step < 20; ++step) {
        gemm_bt<0><<<dim3(C3 / 128, BTc / 128), 256, 0, stream>>>(
            xlnb, Cc, WqkvT, Cc, qkvb, C3, Cc,
            c_attn_b, xt, c_attn_w + (size_t)Cc * C3);
        sinkfused<<<NHc * SB, 512, 0, stream>>>(
            qkvb, E, avec, vTs, partv, ctr, (unsigned)(step * 6 * SB));
        piv_mfma<<<dim3(Tc / 128, NHc), 256, 0, stream>>>(E, vTs, avec, y);
        gemm_bt<3><<<dim3(Cc / 128, BTc / 128), 256, 0, stream>>>(
            y, Cc, WprojT, Cc, ao, Cc, Cc,
            c_proj_b, nullptr, nullptr);
        ln_kernel<<<BTc, 256, 0, stream>>>(ao, mlp_ln_w, mlp_ln_b, xlnb, xt, 1, t, 1, 0, 1);
        gemm_bt<1><<<dim3(C4 / 128, BTc / 128), 256, 0, stream>>>(
            xlnb, Cc, WfcT, Cc, h1, C4, Cc,
            c_fc_b, xt, c_fc_w + (size_t)Cc * C4);
        gemm_bt<4><<<dim3(Cc / 128, BTc / 128, 4), 256, 0, stream>>>(
            h1, C4, WmlpT, C4, parts, Cc, C4 / 4,
            nullptr, nullptr, nullptr);
        t += H_STEP;
        reduce_ln<<<BTc, 256, 0, stream>>>(parts, mlp_proj_b, z,
                                           attn_ln_w, attn_ln_b, xlnb, xt, t);
    }

    ln_kernel<<<2, 256, 0, stream>>>(z, lnf_w, lnf_b, xf, nullptr, 0, 0.f, Tc, Tc - 1, 0);
    logits_kernel<<<Vc / 4, 256, 0, stream>>>(xf, wte, out);
}

// Round 11
// 4088.916 us; speedup vs baseline: 3.8434x; 1.0253x over previous
//
#include <hip/hip_runtime.h>
#include <hip/hip_bf16.h>
#include <math.h>

typedef unsigned short ushortT;
typedef unsigned int uintT;

// Problem constants
#define Bc   2
#define Tc   512
#define Cc   768
#define Hc   12
#define HDc  64
#define Vc   50304
#define BTc  (Bc*Tc)          // 1024
#define NHc  (Bc*Hc)          // 24
#define C3   (3*Cc)           // 2304
#define C4   (4*Cc)           // 3072
#define EPS_LN 1e-5f
#define H_STEP 0.05f
#define INVN (1.0f/512.0f)
#define SB   4                // blocks per head in sinkhorn
#define ELP  (Tc + 8)         // padded Els leading dim (breaks 16-way LDS conflict)

typedef float f32x4 __attribute__((ext_vector_type(4)));
typedef __bf16 bf16x8 __attribute__((ext_vector_type(8)));
typedef ushortT us8 __attribute__((ext_vector_type(8)));
typedef uintT u32x4 __attribute__((ext_vector_type(4)));

// ---------------- bf16 helpers --------------------------------------------
__device__ __forceinline__ ushortT f2bf(float f) {
    union { float f; unsigned u; } x; x.f = f;
    unsigned r = (x.u + 0x7fffu + ((x.u >> 16) & 1u)) >> 16;
    return (ushortT)r;
}
__device__ __forceinline__ float bf2f(ushortT b) {
    union { unsigned u; float f; } x; x.u = ((unsigned)b) << 16;
    return x.f;
}
__device__ __forceinline__ float bflo(uintT w) {
    union { unsigned u; float f; } x; x.u = w << 16;
    return x.f;
}
__device__ __forceinline__ float bfhi(uintT w) {
    union { unsigned u; float f; } x; x.u = w & 0xffff0000u;
    return x.f;
}

// async global->LDS, 16 bytes per lane (LDS dest lane-linear: base + lane*16)
__device__ __forceinline__ void gll16(const ushortT* g, ushortT* l) {
    __builtin_amdgcn_global_load_lds(
        (const __attribute__((address_space(1))) unsigned int*)g,
        (__attribute__((address_space(3))) unsigned int*)l,
        16, 0, 0);
}

// ---------------- wave reductions -----------------------------------------
__device__ __forceinline__ float waveReduceSumX(float v) {
    for (int o = 32; o; o >>= 1) v += __shfl_xor(v, o);
    return v;
}
__device__ __forceinline__ float blockReduceSum(float v) {
    __shared__ float sm[4];
    for (int o = 32; o; o >>= 1) v += __shfl_down(v, o);
    __syncthreads();
    if ((threadIdx.x & 63) == 0) sm[threadIdx.x >> 6] = v;
    __syncthreads();
    return sm[0] + sm[1] + sm[2] + sm[3];
}

// ---------------- weight fp32 [K][N] -> bf16 [N][K] transpose -------------
__global__ __launch_bounds__(256)
void wtrans_kernel(const float* __restrict__ W, ushortT* __restrict__ out,
                   int K, int N)
{
    __shared__ float t[32][33];
    int k0 = blockIdx.x * 32, n0 = blockIdx.y * 32;
    int tx = threadIdx.x & 31, ty = threadIdx.x >> 5;
    for (int r = ty; r < 32; r += 8)
        t[r][tx] = W[(size_t)(k0 + r) * N + n0 + tx];
    __syncthreads();
    for (int r = ty; r < 32; r += 8)
        out[(size_t)(n0 + r) * K + k0 + tx] = f2bf(t[tx][r]);
}

// ---------------- embed + attn-LN (t=0): z, xlnb, xt ----------------------
__global__ __launch_bounds__(256)
void embed_ln(const int* __restrict__ idx, const float* __restrict__ wte,
              const float* __restrict__ wpe, float* __restrict__ z,
              const float* __restrict__ lnw, const float* __restrict__ lnb,
              ushortT* __restrict__ xlnb, float* __restrict__ xt)
{
    int row = blockIdx.x, tid = threadIdx.x;
    int tok = idx[row];
    float v[3];
#pragma unroll
    for (int q = 0; q < 3; ++q) {
        int c = tid + 256 * q;
        float val = wte[(size_t)tok * Cc + c] + wpe[(size_t)(row & (Tc - 1)) * Cc + c];
        z[(size_t)row * Cc + c] = val;
        v[q] = val;
    }
    float s = blockReduceSum(v[0] + v[1] + v[2]);
    float mu = s / 769.f;                       // + t(=0)
    float d0 = v[0] - mu, d1 = v[1] - mu, d2 = v[2] - mu;
    float ss = blockReduceSum(d0 * d0 + d1 * d1 + d2 * d2);
    float dt = 0.f - mu;
    float var = (ss + dt * dt) / 769.f;
    float rs = rsqrtf(var + EPS_LN);
#pragma unroll
    for (int q = 0; q < 3; ++q) {
        int c = tid + 256 * q;
        xlnb[(size_t)row * Cc + c] = f2bf((v[q] - mu) * rs * lnw[c] + lnb[c]);
    }
    if (tid == 0) xt[row] = dt * rs * lnw[Cc] + lnb[Cc];
}

// ---------------- LayerNorm over 768 dims (+optional time column) ---------
__global__ __launch_bounds__(256)
void ln_kernel(const float* __restrict__ X, const float* __restrict__ w,
               const float* __restrict__ bb, void* __restrict__ Y,
               float* __restrict__ yt, int hasT, float tval,
               int rowMul, int rowAdd, int obf16)
{
    int orow = blockIdx.x;
    int r = orow * rowMul + rowAdd;
    const float* x = X + (size_t)r * Cc;
    int tid = threadIdx.x;
    float xv[3];
#pragma unroll
    for (int q = 0; q < 3; ++q) xv[q] = x[tid + 256 * q];
    float s = blockReduceSum(xv[0] + xv[1] + xv[2]);
    float cnt = hasT ? 769.f : 768.f;
    float mu = (s + (hasT ? tval : 0.f)) / cnt;
    float d0 = xv[0] - mu, d1 = xv[1] - mu, d2 = xv[2] - mu;
    float ss = blockReduceSum(d0 * d0 + d1 * d1 + d2 * d2);
    float dt = tval - mu;
    float var = (ss + (hasT ? dt * dt : 0.f)) / cnt;
    float rs = rsqrtf(var + EPS_LN);
#pragma unroll
    for (int q = 0; q < 3; ++q) {
        int c = tid + 256 * q;
        float v = (xv[q] - mu) * rs * w[c] + bb[c];
        if (obf16) ((ushortT*)Y)[(size_t)orow * Cc + c] = f2bf(v);
        else       ((float*)Y)[(size_t)orow * Cc + c] = v;
    }
    if (hasT && tid == 0) yt[orow] = dt * rs * w[Cc] + bb[Cc];
}

// ---------------- MFMA GEMM: C = A[M,K](bf16) @ Bt[N,K](bf16)^T -----------
// EPI: 0 = bias(+rank1) -> bf16 ; 1 = gelu(bias+rank1) -> bf16 ;
//      3 = bias -> fp32 ; 4 = split-K partial fp32 (blockIdx.z chunks)
template <int EPI>
__global__ __launch_bounds__(256)
void gemm_bt(const ushortT* __restrict__ A, int lda,
             const ushortT* __restrict__ Bt, int ldb,
             void* __restrict__ Cm, int ldc, int K,
             const float* __restrict__ bias,
             const float* __restrict__ extraA,
             const float* __restrict__ extraB)
{
    __shared__ __align__(16) ushortT Als[128][32];
    __shared__ __align__(16) ushortT Bls[128][32];
    if (EPI == 4) {
        int koff = blockIdx.z * K;
        A += koff; Bt += koff;
    }
    int tid = threadIdx.x;
    int lane = tid & 63, wid = tid >> 6;
    int wm = wid >> 1, wn = wid & 1;
    int m0 = blockIdx.y * 128, n0 = blockIdx.x * 128;
    f32x4 acc[4][4];
    const f32x4 fz = {0.f, 0.f, 0.f, 0.f};
#pragma unroll
    for (int i = 0; i < 4; ++i)
#pragma unroll
        for (int j = 0; j < 4; ++j) acc[i][j] = fz;

    for (int k0 = 0; k0 < K; k0 += 32) {
#pragma unroll
        for (int is = 0; is < 2; ++is) {
            int ch = is * 256 + tid;
            int m = ch >> 2, kc = ch & 3;
            gll16(A + (size_t)(m0 + m) * lda + k0 + kc * 8, &Als[0][0] + ch * 8);
            gll16(Bt + (size_t)(n0 + m) * ldb + k0 + kc * 8, &Bls[0][0] + ch * 8);
        }
        __syncthreads();
        bf16x8 af[4], bfv[4];
#pragma unroll
        for (int i = 0; i < 4; ++i) {
            int row = wm * 64 + i * 16 + (lane & 15);
            af[i] = *(const bf16x8*)&Als[row][(lane >> 4) * 8];
            int col = wn * 64 + i * 16 + (lane & 15);
            bfv[i] = *(const bf16x8*)&Bls[col][(lane >> 4) * 8];
        }
#pragma unroll
        for (int i = 0; i < 4; ++i)
#pragma unroll
            for (int j = 0; j < 4; ++j)
                acc[i][j] = __builtin_amdgcn_mfma_f32_16x16x32_bf16(af[i], bfv[j], acc[i][j], 0, 0, 0);
        __syncthreads();
    }
#pragma unroll
    for (int i = 0; i < 4; ++i) {
#pragma unroll
        for (int j = 0; j < 4; ++j) {
#pragma unroll
            for (int r = 0; r < 4; ++r) {
                int row = m0 + wm * 64 + i * 16 + (lane >> 4) * 4 + r;
                int col = n0 + wn * 64 + j * 16 + (lane & 15);
                float v = acc[i][j][r];
                if (extraA) v += extraA[row] * extraB[col];
                if (bias) v += bias[col];
                size_t oi = (size_t)row * ldc + col;
                if (EPI == 0) {
                    ((ushortT*)Cm)[oi] = f2bf(v);
                } else if (EPI == 1) {
                    v = 0.5f * v * (1.f + erff(v * 0.70710678118654752440f));
                    ((ushortT*)Cm)[oi] = f2bf(v);
                } else if (EPI == 3) {
                    ((float*)Cm)[oi] = v;
                } else if (EPI == 4) {
                    ((float*)Cm)[(size_t)blockIdx.z * ((size_t)BTc * Cc) + oi] = v;
                }
            }
        }
    }
}

// ===== fused QK + softmax + Sinkhorn + PV (per-head-quarter block) =========
// grid = 96 blocks x 512 threads. Block (n, r) owns rows [r*128, r*128+128).
// QK: q-frags in regs, K staged XOR-swizzled; softmax in-register -> E in
// padded LDS (Els[128][520]); 11 alternating passes (col passes sync 4
// blocks via per-head counter barrier). Finally PV LOCALLY: stage V chunks
// from qkvb scaled by n*b6 transposed into Kls2[64][72], MFMA vs Els rows,
// scale rows by a6, write y. No E/vTs/avec globals, no extra barrier.
__global__ __launch_bounds__(512)
void sinkfused(const ushortT* __restrict__ qkvb, ushortT* __restrict__ y,
               float* __restrict__ partials, unsigned* __restrict__ ctr,
               unsigned barBase)
{
    int gb = blockIdx.x;
    int n = gb >> 2, r = gb & 3;
    int row0 = r * 128;
    int b = n / Hc, h = n - b * Hc;
    int tid = threadIdx.x;
    int l = tid & 63, w = tid >> 6;              // 8 waves
    __shared__ __align__(16) ushortT Els[128][ELP];   // 130 KB (padded)
    __shared__ __align__(16) ushortT Kshare[128 * 64]; // 16 KB (QK Kls / PV Kls2)
    __shared__ float a_s[128];
    __shared__ float b_s[Tc];
    const f32x4 fz = {0.f, 0.f, 0.f, 0.f};

    // ---- phase QK: scores for own 128 rows x (r+1)*128 cols ----
    int qrow = b * Tc + row0 + w * 16 + (l & 15);
    const ushortT* qp = qkvb + (size_t)qrow * C3 + h * HDc + (l >> 4) * 8;
    bf16x8 aq0 = *(const bf16x8*)(qp);
    bf16x8 aq1 = *(const bf16x8*)(qp + 32);

    int kcmax = r + 1;
    f32x4 acc[32];
#pragma unroll
    for (int j = 0; j < 32; ++j) acc[j] = fz;

#pragma unroll
    for (int kc = 0; kc < 4; ++kc) {
        if (kc < kcmax) {
            // stage K rows [kc*128, +128): content (row,c16) at slot row*8 + (c16^(row&7))
            {
                int ch = tid;
                int row = ch >> 3, c16 = (ch & 7) ^ (row & 7);
                gll16(qkvb + (size_t)(b * Tc + kc * 128 + row) * C3 + Cc + h * HDc + c16 * 8,
                      Kshare + ch * 8);
                ch = tid + 512;
                row = ch >> 3; c16 = (ch & 7) ^ (row & 7);
                gll16(qkvb + (size_t)(b * Tc + kc * 128 + row) * C3 + Cc + h * HDc + c16 * 8,
                      Kshare + ch * 8);
            }
            __syncthreads();
#pragma unroll
            for (int jj = 0; jj < 8; ++jj) {
                int krow = jj * 16 + (l & 15);
                int c16a = (l >> 4);
                int c16b = 4 + (l >> 4);
                bf16x8 bk0 = *(const bf16x8*)(Kshare + ((size_t)krow * 8 + (c16a ^ (krow & 7))) * 8);
                bf16x8 bk1 = *(const bf16x8*)(Kshare + ((size_t)krow * 8 + (c16b ^ (krow & 7))) * 8);
                acc[kc * 8 + jj] = __builtin_amdgcn_mfma_f32_16x16x32_bf16(aq0, bk0, acc[kc * 8 + jj], 0, 0, 0);
                acc[kc * 8 + jj] = __builtin_amdgcn_mfma_f32_16x16x32_bf16(aq1, bk1, acc[kc * 8 + jj], 0, 0, 0);
            }
            __syncthreads();
        }
    }

    // ---- in-register causal softmax -> E, rowsum -> a1 ----
    int nvalid = kcmax * 8;
    int colbase = (l & 15);
    int rowa[4];
#pragma unroll
    for (int e = 0; e < 4; ++e) rowa[e] = row0 + w * 16 + (l >> 4) * 4 + e;

    float mx[4] = {-INFINITY, -INFINITY, -INFINITY, -INFINITY};
#pragma unroll
    for (int j = 0; j < 32; ++j) {
        if (j < nvalid) {
            int col = j * 16 + colbase;
#pragma unroll
            for (int e = 0; e < 4; ++e)
                if (col <= rowa[e]) mx[e] = fmaxf(mx[e], acc[j][e] * 0.125f);
        }
    }
#pragma unroll
    for (int e = 0; e < 4; ++e)
        for (int o = 1; o < 16; o <<= 1) mx[e] = fmaxf(mx[e], __shfl_xor(mx[e], o));

    float se[4] = {0.f, 0.f, 0.f, 0.f};
#pragma unroll
    for (int j = 0; j < 32; ++j) {
        if (j < nvalid) {
            int col = j * 16 + colbase;
#pragma unroll
            for (int e = 0; e < 4; ++e) {
                float exv = (col <= rowa[e]) ? __expf(acc[j][e] * 0.125f - mx[e]) : 0.f;
                acc[j][e] = exv;
                se[e] += exv;
            }
        }
    }
#pragma unroll
    for (int e = 0; e < 4; ++e)
        for (int o = 1; o < 16; o <<= 1) se[e] += __shfl_xor(se[e], o);
    float inv[4];
#pragma unroll
    for (int e = 0; e < 4; ++e) inv[e] = 1.f / se[e];

    float rsum[4] = {0.f, 0.f, 0.f, 0.f};
#pragma unroll
    for (int j = 0; j < 32; ++j) {
        if (j < nvalid) {
            int col = j * 16 + colbase;
#pragma unroll
            for (int e = 0; e < 4; ++e) {
                float Ee = __expf(-(acc[j][e] * inv[e]));   // masked: exp(-0)=1
                rsum[e] += Ee;
                Els[w * 16 + (l >> 4) * 4 + e][col] = f2bf(Ee);
            }
        }
    }
#pragma unroll
    for (int e = 0; e < 4; ++e) {
        for (int o = 1; o < 16; o <<= 1) rsum[e] += __shfl_xor(rsum[e], o);
        if ((l & 15) == 0)
            a_s[w * 16 + (l >> 4) * 4 + e] = INVN / (rsum[e] + (float)(Tc - nvalid * 16));
    }
    // fill fully-masked tail with ones (per wave: own 16 rows)
    {
        int tailc = 64 - kcmax * 16;              // us8 chunks per row
        if (tailc > 0) {
            us8 ones8;
#pragma unroll
            for (int e = 0; e < 8; ++e) ones8[e] = 0x3F80;
            for (int idx2 = l; idx2 < 16 * tailc; idx2 += 64) {
                int rr = idx2 / tailc, cc = idx2 - rr * tailc;
                *(us8*)&Els[w * 16 + rr][(kcmax * 16 + cc) * 8] = ones8;
            }
        }
    }
    __syncthreads();

    float* mypart = partials + (size_t)(n * SB + r) * Tc;
    const float* hpart = partials + (size_t)n * SB * Tc;
    unsigned* myctr = ctr + n * 16;              // 64B-padded per-head counter

    // ---- 11 alternating passes: col(0),row(1),...,col(10) ----
#pragma unroll 1
    for (int p = 0; p < 11; ++p) {
        if ((p & 1) == 0) {
            // col partial over own 128 rows; thread = column
            int j = tid;
            float accs = 0.f;
#pragma unroll 1
            for (int i = 0; i < 128; i += 8) {
                float part = 0.f;
#pragma unroll
                for (int k = 0; k < 8; ++k)
                    part += bf2f(Els[i + k][j]) * a_s[i + k];
                accs += part;
            }
            __hip_atomic_store(&mypart[j], accs, __ATOMIC_RELAXED, __HIP_MEMORY_SCOPE_AGENT);
            __syncthreads();
            if (tid == 0) {
                __threadfence();
                atomicAdd(myctr, 1u);
                unsigned tgt = barBase + (unsigned)(p / 2 + 1) * SB;
                while (__hip_atomic_load(myctr, __ATOMIC_ACQUIRE, __HIP_MEMORY_SCOPE_AGENT) < tgt)
                    __builtin_amdgcn_s_sleep(2);
            }
            __syncthreads();
            float s0 = __hip_atomic_load(&hpart[j], __ATOMIC_RELAXED, __HIP_MEMORY_SCOPE_AGENT);
            float s1 = __hip_atomic_load(&hpart[Tc + j], __ATOMIC_RELAXED, __HIP_MEMORY_SCOPE_AGENT);
            float s2 = __hip_atomic_load(&hpart[2 * Tc + j], __ATOMIC_RELAXED, __HIP_MEMORY_SCOPE_AGENT);
            float s3 = __hip_atomic_load(&hpart[3 * Tc + j], __ATOMIC_RELAXED, __HIP_MEMORY_SCOPE_AGENT);
            b_s[j] = INVN / (s0 + s1 + s2 + s3);
            __syncthreads();
        } else {
            // row pass on own rows: wave per 16 rows, ILP 4
            f32x4 b0 = *(const f32x4*)&b_s[l * 8];
            f32x4 b1 = *(const f32x4*)&b_s[l * 8 + 4];
            float breg[8] = {b0[0], b0[1], b0[2], b0[3], b1[0], b1[1], b1[2], b1[3]};
#pragma unroll 1
            for (int k = 0; k < 16; k += 4) {
                int r0 = w * 16 + k;
                u32x4 q0 = *(const u32x4*)(&Els[r0 + 0][l * 8]);
                u32x4 q1 = *(const u32x4*)(&Els[r0 + 1][l * 8]);
                u32x4 q2 = *(const u32x4*)(&Els[r0 + 2][l * 8]);
                u32x4 q3 = *(const u32x4*)(&Els[r0 + 3][l * 8]);
                float s0 = 0.f, s1 = 0.f, s2 = 0.f, s3 = 0.f;
#pragma unroll
                for (int c = 0; c < 4; ++c) {
                    s0 += bflo(q0[c]) * breg[2 * c] + bfhi(q0[c]) * breg[2 * c + 1];
                    s1 += bflo(q1[c]) * breg[2 * c] + bfhi(q1[c]) * breg[2 * c + 1];
                    s2 += bflo(q2[c]) * breg[2 * c] + bfhi(q2[c]) * breg[2 * c + 1];
                    s3 += bflo(q3[c]) * breg[2 * c] + bfhi(q3[c]) * breg[2 * c + 1];
                }
                s0 = waveReduceSumX(s0);
                s1 = waveReduceSumX(s1);
                s2 = waveReduceSumX(s2);
                s3 = waveReduceSumX(s3);
                if (l == 0) {
                    a_s[r0 + 0] = INVN / s0;
                    a_s[r0 + 1] = INVN / s1;
                    a_s[r0 + 2] = INVN / s2;
                    a_s[r0 + 3] = INVN / s3;
                }
            }
            __syncthreads();
        }
    }

    // ---- PV (local): y[row0..row0+128) = a6 ⊙ (E_own @ (n·b6 ⊙ V)) -------
    {
        ushortT* Kls2 = Kshare;                  // [64][72] bf16 (144B stride)
        int wm = w >> 1, wn = w & 1;             // 4 row-groups x 2 d-groups
        f32x4 acc2[2][2];
#pragma unroll
        for (int i = 0; i < 2; ++i)
#pragma unroll
            for (int j = 0; j < 2; ++j) acc2[i][j] = fz;
        const ushortT* vbase = qkvb + (size_t)(b * Tc) * C3 + 2 * Cc + h * HDc;

#pragma unroll 1
        for (int k0 = 0; k0 < Tc; k0 += 64) {
            // stage chunk: 64 t x 64 d, scaled by n*b6[t], transposed
            {
                int tt = tid >> 3, dblk = tid & 7;
                us8 vv = *(const us8*)(vbase + (size_t)(k0 + tt) * C3 + dblk * 8);
                float bs = 512.f * b_s[k0 + tt];
#pragma unroll
                for (int e = 0; e < 8; ++e)
                    Kls2[(dblk * 8 + e) * 72 + tt] = f2bf(bf2f(vv[e]) * bs);
            }
            __syncthreads();
#pragma unroll
            for (int kk = 0; kk < 64; kk += 32) {
                bf16x8 af[2], bv[2];
#pragma unroll
                for (int i = 0; i < 2; ++i)
                    af[i] = *(const bf16x8*)&Els[wm * 32 + i * 16 + (l & 15)][k0 + kk + (l >> 4) * 8];
#pragma unroll
                for (int j = 0; j < 2; ++j)
                    bv[j] = *(const bf16x8*)(Kls2 + (size_t)(wn * 32 + j * 16 + (l & 15)) * 72 + kk + (l >> 4) * 8);
#pragma unroll
                for (int i = 0; i < 2; ++i)
#pragma unroll
                    for (int j = 0; j < 2; ++j)
                        acc2[i][j] = __builtin_amdgcn_mfma_f32_16x16x32_bf16(af[i], bv[j], acc2[i][j], 0, 0, 0);
            }
            __syncthreads();
        }
#pragma unroll
        for (int i = 0; i < 2; ++i)
#pragma unroll
            for (int j = 0; j < 2; ++j)
#pragma unroll
                for (int rr = 0; rr < 4; ++rr) {
                    int lrow = wm * 32 + i * 16 + (l >> 4) * 4 + rr;
                    float a_r = a_s[lrow];
                    int grow = b * Tc + row0 + lrow;
                    int gcol = h * HDc + wn * 32 + j * 16 + (l & 15);
                    y[(size_t)grow * Cc + gcol] = f2bf(acc2[i][j][rr] * a_r);
                }
    }
}

// ------- split-K reduce + Euler + next step's attn-LN (fused) -------------
__global__ __launch_bounds__(256)
void reduce_ln(const float* __restrict__ parts, const float* __restrict__ bias,
               float* __restrict__ z, const float* __restrict__ lnw,
               const float* __restrict__ lnb, ushortT* __restrict__ xlnb,
               float* __restrict__ xt, float tval)
{
    int row = blockIdx.x, tid = threadIdx.x;
    const size_t CS = (size_t)BTc * Cc;
    float v[3];
#pragma unroll
    for (int q = 0; q < 3; ++q) {
        int c = tid + 256 * q;
        size_t idx = (size_t)row * Cc + c;
        float s = parts[idx] + parts[CS + idx] + parts[2 * CS + idx]
                + parts[3 * CS + idx] + bias[c];
        v[q] = z[idx] + H_STEP * s;
        z[idx] = v[q];
    }
    float s = blockReduceSum(v[0] + v[1] + v[2]);
    float mu = (s + tval) / 769.f;
    float d0 = v[0] - mu, d1 = v[1] - mu, d2 = v[2] - mu;
    float ss = blockReduceSum(d0 * d0 + d1 * d1 + d2 * d2);
    float dt = tval - mu;
    float var = (ss + dt * dt) / 769.f;
    float rs = rsqrtf(var + EPS_LN);
#pragma unroll
    for (int q = 0; q < 3; ++q) {
        int c = tid + 256 * q;
        xlnb[(size_t)row * Cc + c] = f2bf((v[q] - mu) * rs * lnw[c] + lnb[c]);
    }
    if (tid == 0) xt[row] = dt * rs * lnw[Cc] + lnb[Cc];
}

// ---------------- logits: out[b,v] = xf[b,:] . wte[v,:] (fp32, f32x4) -----
// Loader covers 384 f32x4 chunks with 256 threads (grid-stride).
__global__ __launch_bounds__(256)
void logits_kernel(const float* __restrict__ xf, const float* __restrict__ wte,
                   float* __restrict__ out)
{
    __shared__ __align__(16) float xs[2 * Cc];
    int tid = threadIdx.x;
    for (int i = tid; i < 384; i += 256)
        ((f32x4*)xs)[i] = ((const f32x4*)xf)[i];
    __syncthreads();
    int w = tid >> 6, lane = tid & 63;
    int vrow = blockIdx.x * 4 + w;
    const f32x4* wr = (const f32x4*)(wte + (size_t)vrow * Cc);
    const f32x4* x0 = (const f32x4*)xs;
    const f32x4* x1 = (const f32x4*)(xs + Cc);
    float a0 = 0.f, a1 = 0.f;
#pragma unroll
    for (int it = 0; it < 3; ++it) {
        int k4 = it * 64 + lane;
        f32x4 wv = wr[k4];
        f32x4 p = x0[k4], q = x1[k4];
        a0 += wv[0] * p[0] + wv[1] * p[1] + wv[2] * p[2] + wv[3] * p[3];
        a1 += wv[0] * q[0] + wv[1] * q[1] + wv[2] * q[2] + wv[3] * q[3];
    }
    for (int o = 32; o; o >>= 1) {
        a0 += __shfl_down(a0, o);
        a1 += __shfl_down(a1, o);
    }
    if (lane == 0) {
        out[vrow] = a0;
        out[Vc + vrow] = a1;
    }
}

// ==========================================================================
extern "C" void kernel_launch(void* const* d_in, const int* in_sizes, int n_in,
                              void* d_out, int out_size, void* d_ws, size_t ws_size,
                              hipStream_t stream)
{
    const int*   idx        = (const int*)  d_in[0];
    const float* wte        = (const float*)d_in[1];
    const float* wpe        = (const float*)d_in[2];
    const float* attn_ln_w  = (const float*)d_in[3];
    const float* attn_ln_b  = (const float*)d_in[4];
    const float* c_attn_w   = (const float*)d_in[5];
    const float* c_attn_b   = (const float*)d_in[6];
    const float* c_proj_w   = (const float*)d_in[7];
    const float* c_proj_b   = (const float*)d_in[8];
    const float* mlp_ln_w   = (const float*)d_in[9];
    const float* mlp_ln_b   = (const float*)d_in[10];
    const float* c_fc_w     = (const float*)d_in[11];
    const float* c_fc_b     = (const float*)d_in[12];
    const float* mlp_proj_w = (const float*)d_in[13];
    const float* mlp_proj_b = (const float*)d_in[14];
    const float* lnf_w      = (const float*)d_in[15];
    const float* lnf_b      = (const float*)d_in[16];
    float* out = (float*)d_out;

    // -------- workspace carving (256B aligned) --------
    char* base = (char*)d_ws;
    size_t off = 0;
    auto alloc = [&](size_t bytes) -> void* {
        void* p = base + off;
        off = (off + bytes + 255) & ~(size_t)255;
        return p;
    };
    float*   z     = (float*)  alloc((size_t)BTc * Cc * 4);
    float*   parts = (float*)  alloc((size_t)4 * BTc * Cc * 4);   // split-K partials
    ushortT* qkvb  = (ushortT*)alloc((size_t)BTc * C3 * 2);
    ushortT* xlnb  = (ushortT*)alloc((size_t)BTc * Cc * 2);
    ushortT* y     = (ushortT*)alloc((size_t)BTc * Cc * 2);
    ushortT* h1    = (ushortT*)alloc((size_t)BTc * C4 * 2);
    float*   ao    = (float*)  alloc((size_t)BTc * Cc * 4);
    float*   xt    = (float*)  alloc(BTc * 4);
    float*   partv = (float*)  alloc((size_t)NHc * SB * Tc * 4);
    unsigned* ctr  = (unsigned*)alloc(NHc * 16 * 4);
    float*   xf    = (float*)  alloc(2 * Cc * 4);
    ushortT* WqkvT = (ushortT*)alloc((size_t)C3 * Cc * 2);
    ushortT* WprojT= (ushortT*)alloc((size_t)Cc * Cc * 2);
    ushortT* WfcT  = (ushortT*)alloc((size_t)C4 * Cc * 2);
    ushortT* WmlpT = (ushortT*)alloc((size_t)Cc * C4 * 2);

    hipMemsetAsync(ctr, 0, NHc * 16 * 4, stream);
    embed_ln<<<BTc, 256, 0, stream>>>(idx, wte, wpe, z, attn_ln_w, attn_ln_b, xlnb, xt);
    wtrans_kernel<<<dim3(Cc / 32, C3 / 32), 256, 0, stream>>>(c_attn_w,   WqkvT,  Cc, C3);
    wtrans_kernel<<<dim3(Cc / 32, Cc / 32), 256, 0, stream>>>(c_proj_w,   WprojT, Cc, Cc);
    wtrans_kernel<<<dim3(Cc / 32, C4 / 32), 256, 0, stream>>>(c_fc_w,     WfcT,   Cc, C4);
    wtrans_kernel<<<dim3(C4 / 32, Cc / 32), 256, 0, stream>>>(mlp_proj_w, WmlpT,  C4, Cc);

    float t = 0.f;
    for (int step = 0; step < 20; ++step) {
        gemm_bt<0><<<dim3(C3 / 128, BTc / 128), 256, 0, stream>>>(
            xlnb, Cc, WqkvT, Cc, qkvb, C3, Cc,
            c_attn_b, xt, c_attn_w + (size_t)Cc * C3);
        sinkfused<<<NHc * SB, 512, 0, stream>>>(
            qkvb, y, partv, ctr, (unsigned)(step * 6 * SB));
        gemm_bt<3><<<dim3(Cc / 128, BTc / 128), 256, 0, stream>>>(
            y, Cc, WprojT, Cc, ao, Cc, Cc,
            c_proj_b, nullptr, nullptr);
        ln_kernel<<<BTc, 256, 0, stream>>>(ao, mlp_ln_w, mlp_ln_b, xlnb, xt, 1, t, 1, 0, 1);
        gemm_bt<1><<<dim3(C4 / 128, BTc / 128), 256, 0, stream>>>(
            xlnb, Cc, WfcT, Cc, h1, C4, Cc,
            c_fc_b, xt, c_fc_w + (size_t)Cc * C4);
        gemm_bt<4><<<dim3(Cc / 128, BTc / 128, 4), 256, 0, stream>>>(
            h1, C4, WmlpT, C4, parts, Cc, C4 / 4,
            nullptr, nullptr, nullptr);
        t += H_STEP;
        reduce_ln<<<BTc, 256, 0, stream>>>(parts, mlp_proj_b, z,
                                           attn_ln_w, attn_ln_b, xlnb, xt, t);
    }

    ln_kernel<<<2, 256, 0, stream>>>(z, lnf_w, lnf_b, xf, nullptr, 0, 0.f, Tc, Tc - 1, 0);
    logits_kernel<<<Vc / 4, 256, 0, stream>>>(xf, wte, out);
}

// Round 12
// 4019.777 us; speedup vs baseline: 3.9095x; 1.0172x over previous
//
#include <hip/hip_runtime.h>
#include <hip/hip_bf16.h>
#include <math.h>

typedef unsigned short ushortT;
typedef unsigned int uintT;

// Problem constants
#define Bc   2
#define Tc   512
#define Cc   768
#define Hc   12
#define HDc  64
#define Vc   50304
#define BTc  (Bc*Tc)          // 1024
#define NHc  (Bc*Hc)          // 24
#define C3   (3*Cc)           // 2304
#define C4   (4*Cc)           // 3072
#define EPS_LN 1e-5f
#define H_STEP 0.05f
#define INVN (1.0f/512.0f)
#define SB   4                // blocks per head in sinkhorn
#define ELP  (Tc + 8)         // padded Els leading dim (breaks 16-way LDS conflict)

typedef float f32x4 __attribute__((ext_vector_type(4)));
typedef __bf16 bf16x8 __attribute__((ext_vector_type(8)));
typedef ushortT us8 __attribute__((ext_vector_type(8)));
typedef uintT u32x4 __attribute__((ext_vector_type(4)));

// ---------------- bf16 helpers --------------------------------------------
__device__ __forceinline__ ushortT f2bf(float f) {
    union { float f; unsigned u; } x; x.f = f;
    unsigned r = (x.u + 0x7fffu + ((x.u >> 16) & 1u)) >> 16;
    return (ushortT)r;
}
__device__ __forceinline__ float bf2f(ushortT b) {
    union { unsigned u; float f; } x; x.u = ((unsigned)b) << 16;
    return x.f;
}
__device__ __forceinline__ float bflo(uintT w) {
    union { unsigned u; float f; } x; x.u = w << 16;
    return x.f;
}
__device__ __forceinline__ float bfhi(uintT w) {
    union { unsigned u; float f; } x; x.u = w & 0xffff0000u;
    return x.f;
}

// async global->LDS, 16 bytes per lane (LDS dest lane-linear: base + lane*16)
__device__ __forceinline__ void gll16(const ushortT* g, ushortT* l) {
    __builtin_amdgcn_global_load_lds(
        (const __attribute__((address_space(1))) unsigned int*)g,
        (__attribute__((address_space(3))) unsigned int*)l,
        16, 0, 0);
}

// ---------------- wave reductions -----------------------------------------
__device__ __forceinline__ float waveReduceSumX(float v) {
    for (int o = 32; o; o >>= 1) v += __shfl_xor(v, o);
    return v;
}
__device__ __forceinline__ float blockReduceSum(float v) {
    __shared__ float sm[4];
    for (int o = 32; o; o >>= 1) v += __shfl_down(v, o);
    __syncthreads();
    if ((threadIdx.x & 63) == 0) sm[threadIdx.x >> 6] = v;
    __syncthreads();
    return sm[0] + sm[1] + sm[2] + sm[3];
}

// ---------------- weight fp32 [K][N] -> bf16 [N][K] transpose -------------
__global__ __launch_bounds__(256)
void wtrans_kernel(const float* __restrict__ W, ushortT* __restrict__ out,
                   int K, int N)
{
    __shared__ float t[32][33];
    int k0 = blockIdx.x * 32, n0 = blockIdx.y * 32;
    int tx = threadIdx.x & 31, ty = threadIdx.x >> 5;
    for (int r = ty; r < 32; r += 8)
        t[r][tx] = W[(size_t)(k0 + r) * N + n0 + tx];
    __syncthreads();
    for (int r = ty; r < 32; r += 8)
        out[(size_t)(n0 + r) * K + k0 + tx] = f2bf(t[tx][r]);
}

// ---------------- embed + attn-LN (t=0): z, xlnb, xt ----------------------
__global__ __launch_bounds__(256)
void embed_ln(const int* __restrict__ idx, const float* __restrict__ wte,
              const float* __restrict__ wpe, float* __restrict__ z,
              const float* __restrict__ lnw, const float* __restrict__ lnb,
              ushortT* __restrict__ xlnb, float* __restrict__ xt)
{
    int row = blockIdx.x, tid = threadIdx.x;
    int tok = idx[row];
    float v[3];
#pragma unroll
    for (int q = 0; q < 3; ++q) {
        int c = tid + 256 * q;
        float val = wte[(size_t)tok * Cc + c] + wpe[(size_t)(row & (Tc - 1)) * Cc + c];
        z[(size_t)row * Cc + c] = val;
        v[q] = val;
    }
    float s = blockReduceSum(v[0] + v[1] + v[2]);
    float mu = s / 769.f;                       // + t(=0)
    float d0 = v[0] - mu, d1 = v[1] - mu, d2 = v[2] - mu;
    float ss = blockReduceSum(d0 * d0 + d1 * d1 + d2 * d2);
    float dt = 0.f - mu;
    float var = (ss + dt * dt) / 769.f;
    float rs = rsqrtf(var + EPS_LN);
#pragma unroll
    for (int q = 0; q < 3; ++q) {
        int c = tid + 256 * q;
        xlnb[(size_t)row * Cc + c] = f2bf((v[q] - mu) * rs * lnw[c] + lnb[c]);
    }
    if (tid == 0) xt[row] = dt * rs * lnw[Cc] + lnb[Cc];
}

// ---------------- LayerNorm over 768 dims (+optional time column) ---------
__global__ __launch_bounds__(256)
void ln_kernel(const float* __restrict__ X, const float* __restrict__ w,
               const float* __restrict__ bb, void* __restrict__ Y,
               float* __restrict__ yt, int hasT, float tval,
               int rowMul, int rowAdd, int obf16)
{
    int orow = blockIdx.x;
    int r = orow * rowMul + rowAdd;
    const float* x = X + (size_t)r * Cc;
    int tid = threadIdx.x;
    float xv[3];
#pragma unroll
    for (int q = 0; q < 3; ++q) xv[q] = x[tid + 256 * q];
    float s = blockReduceSum(xv[0] + xv[1] + xv[2]);
    float cnt = hasT ? 769.f : 768.f;
    float mu = (s + (hasT ? tval : 0.f)) / cnt;
    float d0 = xv[0] - mu, d1 = xv[1] - mu, d2 = xv[2] - mu;
    float ss = blockReduceSum(d0 * d0 + d1 * d1 + d2 * d2);
    float dt = tval - mu;
    float var = (ss + (hasT ? dt * dt : 0.f)) / cnt;
    float rs = rsqrtf(var + EPS_LN);
#pragma unroll
    for (int q = 0; q < 3; ++q) {
        int c = tid + 256 * q;
        float v = (xv[q] - mu) * rs * w[c] + bb[c];
        if (obf16) ((ushortT*)Y)[(size_t)orow * Cc + c] = f2bf(v);
        else       ((float*)Y)[(size_t)orow * Cc + c] = v;
    }
    if (hasT && tid == 0) yt[orow] = dt * rs * w[Cc] + bb[Cc];
}

// ---------------- MFMA GEMM: C = A[M,K](bf16) @ Bt[N,K](bf16)^T -----------
// EPI: 0 = bias(+rank1) -> bf16 ; 1 = gelu(bias+rank1) -> bf16 ;
//      3 = bias -> fp32 ; 4 = split-K partial fp32 (blockIdx.z chunks)
template <int EPI>
__global__ __launch_bounds__(256)
void gemm_bt(const ushortT* __restrict__ A, int lda,
             const ushortT* __restrict__ Bt, int ldb,
             void* __restrict__ Cm, int ldc, int K,
             const float* __restrict__ bias,
             const float* __restrict__ extraA,
             const float* __restrict__ extraB)
{
    __shared__ __align__(16) ushortT Als[128][32];
    __shared__ __align__(16) ushortT Bls[128][32];
    if (EPI == 4) {
        int koff = blockIdx.z * K;
        A += koff; Bt += koff;
    }
    int tid = threadIdx.x;
    int lane = tid & 63, wid = tid >> 6;
    int wm = wid >> 1, wn = wid & 1;
    int m0 = blockIdx.y * 128, n0 = blockIdx.x * 128;
    f32x4 acc[4][4];
    const f32x4 fz = {0.f, 0.f, 0.f, 0.f};
#pragma unroll
    for (int i = 0; i < 4; ++i)
#pragma unroll
        for (int j = 0; j < 4; ++j) acc[i][j] = fz;

    for (int k0 = 0; k0 < K; k0 += 32) {
#pragma unroll
        for (int is = 0; is < 2; ++is) {
            int ch = is * 256 + tid;
            int m = ch >> 2, kc = ch & 3;
            gll16(A + (size_t)(m0 + m) * lda + k0 + kc * 8, &Als[0][0] + ch * 8);
            gll16(Bt + (size_t)(n0 + m) * ldb + k0 + kc * 8, &Bls[0][0] + ch * 8);
        }
        __syncthreads();
        bf16x8 af[4], bfv[4];
#pragma unroll
        for (int i = 0; i < 4; ++i) {
            int row = wm * 64 + i * 16 + (lane & 15);
            af[i] = *(const bf16x8*)&Als[row][(lane >> 4) * 8];
            int col = wn * 64 + i * 16 + (lane & 15);
            bfv[i] = *(const bf16x8*)&Bls[col][(lane >> 4) * 8];
        }
#pragma unroll
        for (int i = 0; i < 4; ++i)
#pragma unroll
            for (int j = 0; j < 4; ++j)
                acc[i][j] = __builtin_amdgcn_mfma_f32_16x16x32_bf16(af[i], bfv[j], acc[i][j], 0, 0, 0);
        __syncthreads();
    }
#pragma unroll
    for (int i = 0; i < 4; ++i) {
#pragma unroll
        for (int j = 0; j < 4; ++j) {
#pragma unroll
            for (int r = 0; r < 4; ++r) {
                int row = m0 + wm * 64 + i * 16 + (lane >> 4) * 4 + r;
                int col = n0 + wn * 64 + j * 16 + (lane & 15);
                float v = acc[i][j][r];
                if (extraA) v += extraA[row] * extraB[col];
                if (bias) v += bias[col];
                size_t oi = (size_t)row * ldc + col;
                if (EPI == 0) {
                    ((ushortT*)Cm)[oi] = f2bf(v);
                } else if (EPI == 1) {
                    v = 0.5f * v * (1.f + erff(v * 0.70710678118654752440f));
                    ((ushortT*)Cm)[oi] = f2bf(v);
                } else if (EPI == 3) {
                    ((float*)Cm)[oi] = v;
                } else if (EPI == 4) {
                    ((float*)Cm)[(size_t)blockIdx.z * ((size_t)BTc * Cc) + oi] = v;
                }
            }
        }
    }
}

// ===== fused QK + softmax + Sinkhorn + PV (per-head-quarter block) =========
// grid = 96 blocks x 512 threads. Block (n, r) owns rows [r*128, r*128+128).
// QK: q-frags in regs, K staged XOR-swizzled; softmax in-register -> E in
// padded LDS (Els[128][520]); 11 alternating passes (col passes VECTORIZED:
// 16x us8 per thread + 8-slice LDS-scratch reduce in Kshare; 4-block counter
// barrier). PV locally: stage V chunks scaled by n*b6 transposed into
// Kls2[64][72], MFMA vs Els rows, scale by a6, write y.
__global__ __launch_bounds__(512)
void sinkfused(const ushortT* __restrict__ qkvb, ushortT* __restrict__ y,
               float* __restrict__ partials, unsigned* __restrict__ ctr,
               unsigned barBase)
{
    int gb = blockIdx.x;
    int n = gb >> 2, r = gb & 3;
    int row0 = r * 128;
    int b = n / Hc, h = n - b * Hc;
    int tid = threadIdx.x;
    int l = tid & 63, w = tid >> 6;              // 8 waves
    __shared__ __align__(16) ushortT Els[128][ELP];   // 130 KB (padded)
    __shared__ __align__(16) ushortT Kshare[128 * 64]; // 16 KB (QK K / col scratch / PV V)
    __shared__ float a_s[128];
    __shared__ float b_s[Tc];
    const f32x4 fz = {0.f, 0.f, 0.f, 0.f};

    // ---- phase QK: scores for own 128 rows x (r+1)*128 cols ----
    int qrow = b * Tc + row0 + w * 16 + (l & 15);
    const ushortT* qp = qkvb + (size_t)qrow * C3 + h * HDc + (l >> 4) * 8;
    bf16x8 aq0 = *(const bf16x8*)(qp);
    bf16x8 aq1 = *(const bf16x8*)(qp + 32);

    int kcmax = r + 1;
    f32x4 acc[32];
#pragma unroll
    for (int j = 0; j < 32; ++j) acc[j] = fz;

#pragma unroll
    for (int kc = 0; kc < 4; ++kc) {
        if (kc < kcmax) {
            // stage K rows [kc*128, +128): content (row,c16) at slot row*8 + (c16^(row&7))
            {
                int ch = tid;
                int row = ch >> 3, c16 = (ch & 7) ^ (row & 7);
                gll16(qkvb + (size_t)(b * Tc + kc * 128 + row) * C3 + Cc + h * HDc + c16 * 8,
                      Kshare + ch * 8);
                ch = tid + 512;
                row = ch >> 3; c16 = (ch & 7) ^ (row & 7);
                gll16(qkvb + (size_t)(b * Tc + kc * 128 + row) * C3 + Cc + h * HDc + c16 * 8,
                      Kshare + ch * 8);
            }
            __syncthreads();
#pragma unroll
            for (int jj = 0; jj < 8; ++jj) {
                int krow = jj * 16 + (l & 15);
                int c16a = (l >> 4);
                int c16b = 4 + (l >> 4);
                bf16x8 bk0 = *(const bf16x8*)(Kshare + ((size_t)krow * 8 + (c16a ^ (krow & 7))) * 8);
                bf16x8 bk1 = *(const bf16x8*)(Kshare + ((size_t)krow * 8 + (c16b ^ (krow & 7))) * 8);
                acc[kc * 8 + jj] = __builtin_amdgcn_mfma_f32_16x16x32_bf16(aq0, bk0, acc[kc * 8 + jj], 0, 0, 0);
                acc[kc * 8 + jj] = __builtin_amdgcn_mfma_f32_16x16x32_bf16(aq1, bk1, acc[kc * 8 + jj], 0, 0, 0);
            }
            __syncthreads();
        }
    }

    // ---- in-register causal softmax -> E, rowsum -> a1 ----
    int nvalid = kcmax * 8;
    int colbase = (l & 15);
    int rowa[4];
#pragma unroll
    for (int e = 0; e < 4; ++e) rowa[e] = row0 + w * 16 + (l >> 4) * 4 + e;

    float mx[4] = {-INFINITY, -INFINITY, -INFINITY, -INFINITY};
#pragma unroll
    for (int j = 0; j < 32; ++j) {
        if (j < nvalid) {
            int col = j * 16 + colbase;
#pragma unroll
            for (int e = 0; e < 4; ++e)
                if (col <= rowa[e]) mx[e] = fmaxf(mx[e], acc[j][e] * 0.125f);
        }
    }
#pragma unroll
    for (int e = 0; e < 4; ++e)
        for (int o = 1; o < 16; o <<= 1) mx[e] = fmaxf(mx[e], __shfl_xor(mx[e], o));

    float se[4] = {0.f, 0.f, 0.f, 0.f};
#pragma unroll
    for (int j = 0; j < 32; ++j) {
        if (j < nvalid) {
            int col = j * 16 + colbase;
#pragma unroll
            for (int e = 0; e < 4; ++e) {
                float exv = (col <= rowa[e]) ? __expf(acc[j][e] * 0.125f - mx[e]) : 0.f;
                acc[j][e] = exv;
                se[e] += exv;
            }
        }
    }
#pragma unroll
    for (int e = 0; e < 4; ++e)
        for (int o = 1; o < 16; o <<= 1) se[e] += __shfl_xor(se[e], o);
    float inv[4];
#pragma unroll
    for (int e = 0; e < 4; ++e) inv[e] = 1.f / se[e];

    float rsum[4] = {0.f, 0.f, 0.f, 0.f};
#pragma unroll
    for (int j = 0; j < 32; ++j) {
        if (j < nvalid) {
            int col = j * 16 + colbase;
#pragma unroll
            for (int e = 0; e < 4; ++e) {
                float Ee = __expf(-(acc[j][e] * inv[e]));   // masked: exp(-0)=1
                rsum[e] += Ee;
                Els[w * 16 + (l >> 4) * 4 + e][col] = f2bf(Ee);
            }
        }
    }
#pragma unroll
    for (int e = 0; e < 4; ++e) {
        for (int o = 1; o < 16; o <<= 1) rsum[e] += __shfl_xor(rsum[e], o);
        if ((l & 15) == 0)
            a_s[w * 16 + (l >> 4) * 4 + e] = INVN / (rsum[e] + (float)(Tc - nvalid * 16));
    }
    // fill fully-masked tail with ones (per wave: own 16 rows)
    {
        int tailc = 64 - kcmax * 16;              // us8 chunks per row
        if (tailc > 0) {
            us8 ones8;
#pragma unroll
            for (int e = 0; e < 8; ++e) ones8[e] = 0x3F80;
            for (int idx2 = l; idx2 < 16 * tailc; idx2 += 64) {
                int rr = idx2 / tailc, cc = idx2 - rr * tailc;
                *(us8*)&Els[w * 16 + rr][(kcmax * 16 + cc) * 8] = ones8;
            }
        }
    }
    __syncthreads();

    float* mypart = partials + (size_t)(n * SB + r) * Tc;
    const float* hpart = partials + (size_t)n * SB * Tc;
    unsigned* myctr = ctr + n * 16;              // 64B-padded per-head counter
    float* scr = (float*)Kshare;                 // 8 x 512 fp32 col-pass scratch

    // ---- 11 alternating passes: col(0),row(1),...,col(10) ----
#pragma unroll 1
    for (int p = 0; p < 11; ++p) {
        if ((p & 1) == 0) {
            // col partial over own 128 rows — VECTORIZED:
            // thread (sl,cg) reads 16 rows x 8 cols via us8, partials to scr.
            int cg = tid & 63, sl = tid >> 6;
            float ac[8] = {0.f, 0.f, 0.f, 0.f, 0.f, 0.f, 0.f, 0.f};
#pragma unroll
            for (int i = 0; i < 16; ++i) {
                int row = sl * 16 + i;
                us8 ev = *(const us8*)&Els[row][cg * 8];
                float fa = a_s[row];
#pragma unroll
                for (int e = 0; e < 8; ++e)
                    ac[e] += bf2f(ev[e]) * fa;
            }
            f32x4 lo = {ac[0], ac[1], ac[2], ac[3]};
            f32x4 hi = {ac[4], ac[5], ac[6], ac[7]};
            *(f32x4*)&scr[sl * 512 + cg * 8] = lo;
            *(f32x4*)&scr[sl * 512 + cg * 8 + 4] = hi;
            __syncthreads();
            int j = tid;
            float accs = 0.f;
#pragma unroll
            for (int s2 = 0; s2 < 8; ++s2) accs += scr[s2 * 512 + j];
            __hip_atomic_store(&mypart[j], accs, __ATOMIC_RELAXED, __HIP_MEMORY_SCOPE_AGENT);
            __syncthreads();
            if (tid == 0) {
                __threadfence();
                atomicAdd(myctr, 1u);
                unsigned tgt = barBase + (unsigned)(p / 2 + 1) * SB;
                while (__hip_atomic_load(myctr, __ATOMIC_ACQUIRE, __HIP_MEMORY_SCOPE_AGENT) < tgt)
                    __builtin_amdgcn_s_sleep(2);
            }
            __syncthreads();
            float s0 = __hip_atomic_load(&hpart[j], __ATOMIC_RELAXED, __HIP_MEMORY_SCOPE_AGENT);
            float s1 = __hip_atomic_load(&hpart[Tc + j], __ATOMIC_RELAXED, __HIP_MEMORY_SCOPE_AGENT);
            float s2 = __hip_atomic_load(&hpart[2 * Tc + j], __ATOMIC_RELAXED, __HIP_MEMORY_SCOPE_AGENT);
            float s3 = __hip_atomic_load(&hpart[3 * Tc + j], __ATOMIC_RELAXED, __HIP_MEMORY_SCOPE_AGENT);
            b_s[j] = INVN / (s0 + s1 + s2 + s3);
            __syncthreads();
        } else {
            // row pass on own rows: wave per 16 rows, ILP 4
            f32x4 b0 = *(const f32x4*)&b_s[l * 8];
            f32x4 b1 = *(const f32x4*)&b_s[l * 8 + 4];
            float breg[8] = {b0[0], b0[1], b0[2], b0[3], b1[0], b1[1], b1[2], b1[3]};
#pragma unroll 1
            for (int k = 0; k < 16; k += 4) {
                int r0 = w * 16 + k;
                u32x4 q0 = *(const u32x4*)(&Els[r0 + 0][l * 8]);
                u32x4 q1 = *(const u32x4*)(&Els[r0 + 1][l * 8]);
                u32x4 q2 = *(const u32x4*)(&Els[r0 + 2][l * 8]);
                u32x4 q3 = *(const u32x4*)(&Els[r0 + 3][l * 8]);
                float s0 = 0.f, s1 = 0.f, s2 = 0.f, s3 = 0.f;
#pragma unroll
                for (int c = 0; c < 4; ++c) {
                    s0 += bflo(q0[c]) * breg[2 * c] + bfhi(q0[c]) * breg[2 * c + 1];
                    s1 += bflo(q1[c]) * breg[2 * c] + bfhi(q1[c]) * breg[2 * c + 1];
                    s2 += bflo(q2[c]) * breg[2 * c] + bfhi(q2[c]) * breg[2 * c + 1];
                    s3 += bflo(q3[c]) * breg[2 * c] + bfhi(q3[c]) * breg[2 * c + 1];
                }
                s0 = waveReduceSumX(s0);
                s1 = waveReduceSumX(s1);
                s2 = waveReduceSumX(s2);
                s3 = waveReduceSumX(s3);
                if (l == 0) {
                    a_s[r0 + 0] = INVN / s0;
                    a_s[r0 + 1] = INVN / s1;
                    a_s[r0 + 2] = INVN / s2;
                    a_s[r0 + 3] = INVN / s3;
                }
            }
            __syncthreads();
        }
    }

    // ---- PV (local): y[row0..row0+128) = a6 ⊙ (E_own @ (n·b6 ⊙ V)) -------
    {
        ushortT* Kls2 = Kshare;                  // [64][72] bf16 (144B stride)
        int wm = w >> 1, wn = w & 1;             // 4 row-groups x 2 d-groups
        f32x4 acc2[2][2];
#pragma unroll
        for (int i = 0; i < 2; ++i)
#pragma unroll
            for (int j = 0; j < 2; ++j) acc2[i][j] = fz;
        const ushortT* vbase = qkvb + (size_t)(b * Tc) * C3 + 2 * Cc + h * HDc;

#pragma unroll 1
        for (int k0 = 0; k0 < Tc; k0 += 64) {
            // stage chunk: 64 t x 64 d, scaled by n*b6[t], transposed
            {
                int tt = tid >> 3, dblk = tid & 7;
                us8 vv = *(const us8*)(vbase + (size_t)(k0 + tt) * C3 + dblk * 8);
                float bs = 512.f * b_s[k0 + tt];
#pragma unroll
                for (int e = 0; e < 8; ++e)
                    Kls2[(dblk * 8 + e) * 72 + tt] = f2bf(bf2f(vv[e]) * bs);
            }
            __syncthreads();
#pragma unroll
            for (int kk = 0; kk < 64; kk += 32) {
                bf16x8 af[2], bv[2];
#pragma unroll
                for (int i = 0; i < 2; ++i)
                    af[i] = *(const bf16x8*)&Els[wm * 32 + i * 16 + (l & 15)][k0 + kk + (l >> 4) * 8];
#pragma unroll
                for (int j = 0; j < 2; ++j)
                    bv[j] = *(const bf16x8*)(Kls2 + (size_t)(wn * 32 + j * 16 + (l & 15)) * 72 + kk + (l >> 4) * 8);
#pragma unroll
                for (int i = 0; i < 2; ++i)
#pragma unroll
                    for (int j = 0; j < 2; ++j)
                        acc2[i][j] = __builtin_amdgcn_mfma_f32_16x16x32_bf16(af[i], bv[j], acc2[i][j], 0, 0, 0);
            }
            __syncthreads();
        }
#pragma unroll
        for (int i = 0; i < 2; ++i)
#pragma unroll
            for (int j = 0; j < 2; ++j)
#pragma unroll
                for (int rr = 0; rr < 4; ++rr) {
                    int lrow = wm * 32 + i * 16 + (l >> 4) * 4 + rr;
                    float a_r = a_s[lrow];
                    int grow = b * Tc + row0 + lrow;
                    int gcol = h * HDc + wn * 32 + j * 16 + (l & 15);
                    y[(size_t)grow * Cc + gcol] = f2bf(acc2[i][j][rr] * a_r);
                }
    }
}

// ------- split-K reduce + Euler + next step's attn-LN (fused) -------------
__global__ __launch_bounds__(256)
void reduce_ln(const float* __restrict__ parts, const float* __restrict__ bias,
               float* __restrict__ z, const float* __restrict__ lnw,
               const float* __restrict__ lnb, ushortT* __restrict__ xlnb,
               float* __restrict__ xt, float tval)
{
    int row = blockIdx.x, tid = threadIdx.x;
    const size_t CS = (size_t)BTc * Cc;
    float v[3];
#pragma unroll
    for (int q = 0; q < 3; ++q) {
        int c = tid + 256 * q;
        size_t idx = (size_t)row * Cc + c;
        float s = parts[idx] + parts[CS + idx] + parts[2 * CS + idx]
                + parts[3 * CS + idx] + bias[c];
        v[q] = z[idx] + H_STEP * s;
        z[idx] = v[q];
    }
    float s = blockReduceSum(v[0] + v[1] + v[2]);
    float mu = (s + tval) / 769.f;
    float d0 = v[0] - mu, d1 = v[1] - mu, d2 = v[2] - mu;
    float ss = blockReduceSum(d0 * d0 + d1 * d1 + d2 * d2);
    float dt = tval - mu;
    float var = (ss + dt * dt) / 769.f;
    float rs = rsqrtf(var + EPS_LN);
#pragma unroll
    for (int q = 0; q < 3; ++q) {
        int c = tid + 256 * q;
        xlnb[(size_t)row * Cc + c] = f2bf((v[q] - mu) * rs * lnw[c] + lnb[c]);
    }
    if (tid == 0) xt[row] = dt * rs * lnw[Cc] + lnb[Cc];
}

// ---------------- logits: out[b,v] = xf[b,:] . wte[v,:] (fp32, f32x4) -----
// Loader covers 384 f32x4 chunks with 256 threads (grid-stride).
__global__ __launch_bounds__(256)
void logits_kernel(const float* __restrict__ xf, const float* __restrict__ wte,
                   float* __restrict__ out)
{
    __shared__ __align__(16) float xs[2 * Cc];
    int tid = threadIdx.x;
    for (int i = tid; i < 384; i += 256)
        ((f32x4*)xs)[i] = ((const f32x4*)xf)[i];
    __syncthreads();
    int w = tid >> 6, lane = tid & 63;
    int vrow = blockIdx.x * 4 + w;
    const f32x4* wr = (const f32x4*)(wte + (size_t)vrow * Cc);
    const f32x4* x0 = (const f32x4*)xs;
    const f32x4* x1 = (const f32x4*)(xs + Cc);
    float a0 = 0.f, a1 = 0.f;
#pragma unroll
    for (int it = 0; it < 3; ++it) {
        int k4 = it * 64 + lane;
        f32x4 wv = wr[k4];
        f32x4 p = x0[k4], q = x1[k4];
        a0 += wv[0] * p[0] + wv[1] * p[1] + wv[2] * p[2] + wv[3] * p[3];
        a1 += wv[0] * q[0] + wv[1] * q[1] + wv[2] * q[2] + wv[3] * q[3];
    }
    for (int o = 32; o; o >>= 1) {
        a0 += __shfl_down(a0, o);
        a1 += __shfl_down(a1, o);
    }
    if (lane == 0) {
        out[vrow] = a0;
        out[Vc + vrow] = a1;
    }
}

// ==========================================================================
extern "C" void kernel_launch(void* const* d_in, const int* in_sizes, int n_in,
                              void* d_out, int out_size, void* d_ws, size_t ws_size,
                              hipStream_t stream)
{
    const int*   idx        = (const int*)  d_in[0];
    const float* wte        = (const float*)d_in[1];
    const float* wpe        = (const float*)d_in[2];
    const float* attn_ln_w  = (const float*)d_in[3];
    const float* attn_ln_b  = (const float*)d_in[4];
    const float* c_attn_w   = (const float*)d_in[5];
    const float* c_attn_b   = (const float*)d_in[6];
    const float* c_proj_w   = (const float*)d_in[7];
    const float* c_proj_b   = (const float*)d_in[8];
    const float* mlp_ln_w   = (const float*)d_in[9];
    const float* mlp_ln_b   = (const float*)d_in[10];
    const float* c_fc_w     = (const float*)d_in[11];
    const float* c_fc_b     = (const float*)d_in[12];
    const float* mlp_proj_w = (const float*)d_in[13];
    const float* mlp_proj_b = (const float*)d_in[14];
    const float* lnf_w      = (const float*)d_in[15];
    const float* lnf_b      = (const float*)d_in[16];
    float* out = (float*)d_out;

    // -------- workspace carving (256B aligned) --------
    char* base = (char*)d_ws;
    size_t off = 0;
    auto alloc = [&](size_t bytes) -> void* {
        void* p = base + off;
        off = (off + bytes + 255) & ~(size_t)255;
        return p;
    };
    float*   z     = (float*)  alloc((size_t)BTc * Cc * 4);
    float*   parts = (float*)  alloc((size_t)4 * BTc * Cc * 4);   // split-K partials
    ushortT* qkvb  = (ushortT*)alloc((size_t)BTc * C3 * 2);
    ushortT* xlnb  = (ushortT*)alloc((size_t)BTc * Cc * 2);
    ushortT* y     = (ushortT*)alloc((size_t)BTc * Cc * 2);
    ushortT* h1    = (ushortT*)alloc((size_t)BTc * C4 * 2);
    float*   ao    = (float*)  alloc((size_t)BTc * Cc * 4);
    float*   xt    = (float*)  alloc(BTc * 4);
    float*   partv = (float*)  alloc((size_t)NHc * SB * Tc * 4);
    unsigned* ctr  = (unsigned*)alloc(NHc * 16 * 4);
    float*   xf    = (float*)  alloc(2 * Cc * 4);
    ushortT* WqkvT = (ushortT*)alloc((size_t)C3 * Cc * 2);
    ushortT* WprojT= (ushortT*)alloc((size_t)Cc * Cc * 2);
    ushortT* WfcT  = (ushortT*)alloc((size_t)C4 * Cc * 2);
    ushortT* WmlpT = (ushortT*)alloc((size_t)Cc * C4 * 2);

    hipMemsetAsync(ctr, 0, NHc * 16 * 4, stream);
    embed_ln<<<BTc, 256, 0, stream>>>(idx, wte, wpe, z, attn_ln_w, attn_ln_b, xlnb, xt);
    wtrans_kernel<<<dim3(Cc / 32, C3 / 32), 256, 0, stream>>>(c_attn_w,   WqkvT,  Cc, C3);
    wtrans_kernel<<<dim3(Cc / 32, Cc / 32), 256, 0, stream>>>(c_proj_w,   WprojT, Cc, Cc);
    wtrans_kernel<<<dim3(Cc / 32, C4 / 32), 256, 0, stream>>>(c_fc_w,     WfcT,   Cc, C4);
    wtrans_kernel<<<dim3(C4 / 32, Cc / 32), 256, 0, stream>>>(mlp_proj_w, WmlpT,  C4, Cc);

    float t = 0.f;
    for (int step = 0; step < 20; ++step) {
        gemm_bt<0><<<dim3(C3 / 128, BTc / 128), 256, 0, stream>>>(
            xlnb, Cc, WqkvT, Cc, qkvb, C3, Cc,
            c_attn_b, xt, c_attn_w + (size_t)Cc * C3);
        sinkfused<<<NHc * SB, 512, 0, stream>>>(
            qkvb, y, partv, ctr, (unsigned)(step * 6 * SB));
        gemm_bt<3><<<dim3(Cc / 128, BTc / 128), 256, 0, stream>>>(
            y, Cc, WprojT, Cc, ao, Cc, Cc,
            c_proj_b, nullptr, nullptr);
        ln_kernel<<<BTc, 256, 0, stream>>>(ao, mlp_ln_w, mlp_ln_b, xlnb, xt, 1, t, 1, 0, 1);
        gemm_bt<1><<<dim3(C4 / 128, BTc / 128), 256, 0, stream>>>(
            xlnb, Cc, WfcT, Cc, h1, C4, Cc,
            c_fc_b, xt, c_fc_w + (size_t)Cc * C4);
        gemm_bt<4><<<dim3(Cc / 128, BTc / 128, 4), 256, 0, stream>>>(
            h1, C4, WmlpT, C4, parts, Cc, C4 / 4,
            nullptr, nullptr, nullptr);
        t += H_STEP;
        reduce_ln<<<BTc, 256, 0, stream>>>(parts, mlp_proj_b, z,
                                           attn_ln_w, attn_ln_b, xlnb, xt, t);
    }

    ln_kernel<<<2, 256, 0, stream>>>(z, lnf_w, lnf_b, xf, nullptr, 0, 0.f, Tc, Tc - 1, 0);
    logits_kernel<<<Vc / 4, 256, 0, stream>>>(xf, wte, out);
}